// Round 7
// baseline (986.963 us; speedup 1.0000x reference)
//
#include <hip/hip_runtime.h>
#include <math.h>

#define BATCH 16384
#define EPSQ 1e-8f

// ---------------- ws layout (32-bit units) ----------------
// float scalars: [0] absmax_in, [1,2] conv1 max/negmax, [3,4] conv2, [5,6] fc1,
//                [7,8] fc2, [9] s_w1 [10] s_w2 [11] s_w3 [12] s_w4 [13] s_w5
#define OFF_SCAL 0
#define OFF_WPK1 16      // 180 u32  : conv1 sign-packs [6][3][5]{w0123,w4pack}
#define OFF_WPK2 196     // 960 u32  : conv2 sign-packs [16][6][5]{...}
#define OFF_FQ1  1156    // 12000 u32: fc1 signs [120][100]
#define OFF_FQ2  13156   // 2688 u32 : fc2 signs [84][32] (k>=30 zero)
#define OFF_FQ3  15844   // 240 u32  : fc3 signs [10][24] (k>=21 zero)
#define OFF_OUT1 16384   // B*1176 fp32 pooled conv1 preact
#define N_OUT1   (BATCH*1176)
#define OFF_OUT2 (OFF_OUT1+N_OUT1)   // B*400 fp32 pooled conv2 preact
#define N_OUT2   (BATCH*400)
#define OFF_P3   (OFF_OUT2+N_OUT2)   // B*120 fc1 preact
#define N_P3     (BATCH*120)
#define OFF_P4   (OFF_P3+N_P3)       // B*84 fc2 preact

__device__ inline int sdot4(unsigned int a, unsigned int b, int c) {
    return __builtin_amdgcn_sdot4((int)a, (int)b, c, false);
}

__device__ inline void atomicMaxF(float* addr, float val) {
    unsigned int* ua = (unsigned int*)addr;
    unsigned int old = *ua;
    while (__uint_as_float(old) < val) {
        unsigned int assumed = old;
        old = atomicCAS(ua, assumed, __float_as_uint(val));
        if (old == assumed) break;
    }
}

__device__ inline float waveMax(float v) {
    #pragma unroll
    for (int off = 32; off > 0; off >>= 1)
        v = fmaxf(v, __shfl_down(v, off, 64));
    return v;
}

__device__ inline void blockAtomicMax2(float vmax, float vnmax, float* gmax, float* gnmax) {
    __shared__ float sm[4], sn[4];
    float a = waveMax(vmax), b = waveMax(vnmax);
    int tid = threadIdx.x;
    if ((tid & 63) == 0) { sm[tid >> 6] = a; sn[tid >> 6] = b; }
    __syncthreads();
    if (tid == 0) {
        float m = fmaxf(fmaxf(sm[0], sm[1]), fmaxf(sm[2], sm[3]));
        float n = fmaxf(fmaxf(sn[0], sn[1]), fmaxf(sn[2], sn[3]));
        atomicMaxF(gmax, m);
        atomicMaxF(gnmax, n);
    }
}

__device__ inline void waveAtomicMax2(float vmax, float vnmax, float* gmax, float* gnmax) {
    float a = waveMax(vmax), b = waveMax(vnmax);
    if ((threadIdx.x & 63) == 0) { atomicMaxF(gmax, a); atomicMaxF(gnmax, b); }
}

// int8 fake-quant pieces (IEEE div matches jnp.round(x/s) bins)
__device__ inline float fq_elem(float x, float s) {
    float q = fminf(fmaxf(rintf(x / s), -128.0f), 127.0f);
    return q * s;
}

// qrelu returning INTEGER code r in [0,127] (value = r*s2)
__device__ inline int qrelu_code(float x, float s1, float s2) {
    float q = fq_elem(x, s1);
    q = fmaxf(q, 0.0f);
    return (int)fminf(fmaxf(rintf(q / s2), -128.0f), 127.0f);
}

__device__ inline void get_qrelu_scales(const float* scal, int slot, float& s1, float& s2) {
    float maxa = scal[slot], negm = scal[slot + 1];
    float absm = fmaxf(maxa, negm);
    s1 = fmaxf(absm / 127.0f, EPSQ);
    float qm = fminf(fmaxf(rintf(maxa / s1), -128.0f), 127.0f) * s1;
    s2 = fmaxf(fmaxf(qm, 0.0f) / 127.0f, EPSQ);
}

__device__ inline unsigned int sgn8(float w) { return (w >= 0.0f) ? 0x01u : 0xFFu; }

// bytes k..k+3 from word pair (static k after unroll)
__device__ inline unsigned int u32at(const unsigned int* wv, int wi, int k) {
    return (k == 0) ? wv[wi]
        : __builtin_amdgcn_perm(wv[wi + 1], wv[wi], 0x03020100u + 0x01010101u * (unsigned)k);
}

// ---------------- prep: scalars + sign-pack all weights ----------------
__global__ __launch_bounds__(256) void prep_kernel(const float* __restrict__ w1,
        const float* __restrict__ w2, const float* __restrict__ fw1,
        const float* __restrict__ fw2, const float* __restrict__ fw3,
        float* __restrict__ wsf) {
    int blk = blockIdx.x, tid = threadIdx.x;
    unsigned int* wsu = (unsigned int*)wsf;
    if (blk == 0) {
        if (tid == 0) wsf[0] = 0.0f;
        else if (tid <= 8) wsf[tid] = -INFINITY;
        return;
    }
    const float* src = nullptr; int N = 0;
    if (blk == 1)      { src = w1;  N = 450; }
    else if (blk == 2) { src = w2;  N = 2400; }
    else if (blk == 3) { src = fw1; N = 48000; }
    else if (blk == 4) { src = fw2; N = 10080; }
    else               { src = fw3; N = 840; }
    __shared__ float red[256];
    float partial = 0.0f;
    for (int i = tid; i < N; i += 256) partial += fabsf(src[i]);
    red[tid] = partial;
    __syncthreads();
    for (int s = 128; s > 0; s >>= 1) {
        if (tid < s) red[tid] += red[tid + s];
        __syncthreads();
    }
    if (tid == 0) wsf[8 + blk] = red[0] / (float)N;   // ws[9..13]

    if (blk == 1) {
        for (int t = tid; t < 90; t += 256) {         // (c,ci,ky)
            const float* wp = w1 + t * 5;
            wsu[OFF_WPK1 + 2*t] = sgn8(wp[0]) | (sgn8(wp[1])<<8) | (sgn8(wp[2])<<16) | (sgn8(wp[3])<<24);
            wsu[OFF_WPK1 + 2*t + 1] = sgn8(wp[4]) << 24;
        }
    } else if (blk == 2) {
        for (int t = tid; t < 480; t += 256) {
            const float* wp = w2 + t * 5;
            wsu[OFF_WPK2 + 2*t] = sgn8(wp[0]) | (sgn8(wp[1])<<8) | (sgn8(wp[2])<<16) | (sgn8(wp[3])<<24);
            wsu[OFF_WPK2 + 2*t + 1] = sgn8(wp[4]) << 24;
        }
    } else if (blk == 3) {
        for (int i = tid; i < 12000; i += 256) {
            int j = i / 100, k = i % 100;
            const float* wp = fw1 + j * 400 + k * 4;
            wsu[OFF_FQ1 + i] = sgn8(wp[0]) | (sgn8(wp[1])<<8) | (sgn8(wp[2])<<16) | (sgn8(wp[3])<<24);
        }
    } else if (blk == 4) {
        for (int i = tid; i < 2688; i += 256) {
            int j = i >> 5, k = i & 31;
            unsigned int u = 0;
            if (k < 30) {
                const float* wp = fw2 + j * 120 + k * 4;
                u = sgn8(wp[0]) | (sgn8(wp[1])<<8) | (sgn8(wp[2])<<16) | (sgn8(wp[3])<<24);
            }
            wsu[OFF_FQ2 + i] = u;
        }
    } else {
        for (int i = tid; i < 240; i += 256) {
            int j = i / 24, k = i % 24;
            unsigned int u = 0;
            if (k < 21) {
                const float* wp = fw3 + j * 84 + k * 4;
                u = sgn8(wp[0]) | (sgn8(wp[1])<<8) | (sgn8(wp[2])<<16) | (sgn8(wp[3])<<24);
            }
            wsu[OFF_FQ3 + i] = u;
        }
    }
}

// ---------------- input abs-max ----------------
__global__ __launch_bounds__(256) void absmax_kernel(const float4* __restrict__ x, int n4,
                                                     float* __restrict__ gmax) {
    float m = 0.0f;
    int stride = gridDim.x * 256;
    for (int i = blockIdx.x * 256 + threadIdx.x; i < n4; i += stride) {
        float4 v = x[i];
        m = fmaxf(m, fmaxf(fmaxf(fabsf(v.x), fabsf(v.y)), fmaxf(fabsf(v.z), fabsf(v.w))));
    }
    m = waveMax(m);
    if ((threadIdx.x & 63) == 0) atomicMaxF(gmax, m);
}

// ---------------- conv1: 3 img/block, i8 codes in LDS, batched-load dot4 conv ------
#define C1_ROWP 48
#define C1_CIS  (32*C1_ROWP)
#define C1_IMGS (3*C1_CIS)

// PH=0: outputs x=0..13, window bytes 0..19  -> load uint4@0  + u32@16, wv={A,B}, no shift
// PH=1: outputs x=14..27, window bytes 12..31 -> load u32@12 + uint4@16, wv={B,A}, shift+2
template<int PH>
__device__ __forceinline__ void c1_phase(const unsigned char* ib, const unsigned int* wcp,
                                         int* ip, int& gmax, int& gmin) {
    int a0[14], a1[14];
    #pragma unroll
    for (int i = 0; i < 14; i++) { a0[i] = 0; a1[i] = 0; }
    #pragma unroll 1
    for (int ci = 0; ci < 3; ci++) {
        // ---- batched row loads: all 12 ds_reads issue before compute ----
        uint4 A[6]; unsigned int Bv[6];
        const unsigned char* cb = ib + ci * C1_CIS;
        #pragma unroll
        for (int r = 0; r < 6; r++) {
            const unsigned char* rb = cb + r * C1_ROWP;
            if (PH == 0) {
                A[r]  = *(const uint4*)(rb);
                Bv[r] = *(const unsigned int*)(rb + 16);
            } else {
                Bv[r] = *(const unsigned int*)(rb + 12);
                A[r]  = *(const uint4*)(rb + 16);
            }
        }
        const unsigned int* wkp = wcp + ci * 10;
        unsigned int wk0[5], wk4[5];
        #pragma unroll
        for (int ky = 0; ky < 5; ky++) { wk0[ky] = wkp[2*ky]; wk4[ky] = wkp[2*ky+1]; }
        #pragma unroll
        for (int r6 = 0; r6 < 6; r6++) {
            unsigned int wq[5];
            if (PH == 0) {
                wq[0] = A[r6].x; wq[1] = A[r6].y; wq[2] = A[r6].z; wq[3] = A[r6].w; wq[4] = Bv[r6];
            } else {
                // window bytes 14.. : shift the {Bv,A} pair by +2 bytes (static perms)
                wq[0] = __builtin_amdgcn_perm(A[r6].x, Bv[r6],  0x05040302u);
                wq[1] = __builtin_amdgcn_perm(A[r6].y, A[r6].x, 0x05040302u);
                wq[2] = __builtin_amdgcn_perm(A[r6].z, A[r6].y, 0x05040302u);
                wq[3] = __builtin_amdgcn_perm(A[r6].w, A[r6].z, 0x05040302u);
                wq[4] = __builtin_amdgcn_perm(A[r6].w, A[r6].w, 0x00000302u); // low2 = A.w b2,b3
            }
            unsigned int up[15];
            #pragma unroll
            for (int i = 0; i < 15; i++) up[i] = u32at(wq, i >> 2, i & 3);
            if (r6 <= 4) {
                unsigned int w0 = wk0[r6], w4 = wk4[r6];
                #pragma unroll
                for (int i = 0; i < 14; i++) {
                    a0[i] = sdot4(up[i], w0, a0[i]);
                    a0[i] = sdot4(up[i+1], w4, a0[i]);
                }
            }
            if (r6 >= 1) {
                unsigned int w0 = wk0[r6-1], w4 = wk4[r6-1];
                #pragma unroll
                for (int i = 0; i < 14; i++) {
                    a1[i] = sdot4(up[i], w0, a1[i]);
                    a1[i] = sdot4(up[i+1], w4, a1[i]);
                }
            }
        }
    }
    #pragma unroll
    for (int i = 0; i < 14; i++) {
        gmax = max(gmax, max(a0[i], a1[i]));
        gmin = min(gmin, min(a0[i], a1[i]));
    }
    #pragma unroll
    for (int p = 0; p < 7; p++)
        ip[p] = max(max(a0[2*p], a0[2*p+1]), max(a1[2*p], a1[2*p+1]));
}

__global__ __launch_bounds__(256) void conv1_kernel(const float* __restrict__ x,
        const float* __restrict__ b1, float* __restrict__ wsf) {
    __shared__ unsigned char xq[3 * C1_IMGS];
    __shared__ unsigned int wpk[180];
    __shared__ float bsm[6];
    unsigned int* wsu = (unsigned int*)wsf;
    float* scal = wsf;
    float* out1 = wsf + OFF_OUT1;
    int tid = threadIdx.x;
    int b0 = blockIdx.x * 3;
    int nimg = min(3, BATCH - b0);
    float s0 = fmaxf(scal[0] / 127.0f, EPSQ);
    float seff = s0 * scal[9];

    const float4* xb = (const float4*)(x + (size_t)b0 * 3072);
    for (int i = tid; i < nimg * 768; i += 256) {
        float4 v = xb[i];
        int q0 = (int)fminf(fmaxf(rintf(v.x / s0), -128.f), 127.f);
        int q1 = (int)fminf(fmaxf(rintf(v.y / s0), -128.f), 127.f);
        int q2 = (int)fminf(fmaxf(rintf(v.z / s0), -128.f), 127.f);
        int q3 = (int)fminf(fmaxf(rintf(v.w / s0), -128.f), 127.f);
        unsigned int u = (q0 & 255) | ((q1 & 255) << 8) | ((q2 & 255) << 16)
                       | ((unsigned)(q3 & 255) << 24);
        int idx = i * 4;
        int img = idx / 3072, rem = idx % 3072;
        int ci = rem >> 10, r2 = rem & 1023;
        int row = r2 >> 5, col = r2 & 31;
        *(unsigned int*)&xq[img * C1_IMGS + ci * C1_CIS + row * C1_ROWP + col] = u;
    }
    for (int i = tid; i < 180; i += 256) wpk[i] = wsu[OFF_WPK1 + i];
    if (tid < 6) bsm[tid] = b1[tid];
    __syncthreads();

    float vmax = -INFINITY, vnmax = -INFINITY;
    if (tid < nimg * 84) {
        int img = tid / 84, r = tid % 84;
        int c = r / 14, py = r % 14;
        const unsigned char* ib = &xq[img * C1_IMGS + (2 * py) * C1_ROWP];
        const unsigned int* wcp = &wpk[c * 30];
        int ip0[7], ip1[7];
        int gmax = -2000000000, gmin = 2000000000;
        c1_phase<0>(ib, wcp, ip0, gmax, gmin);
        c1_phase<1>(ib, wcp, ip1, gmax, gmin);
        float bias = bsm[c];
        float* dst = &out1[(size_t)(b0 + img) * 1176 + c * 196 + py * 14];
        #pragma unroll
        for (int p = 0; p < 7; p++) {
            dst[p]     = fmaf(seff, (float)ip0[p], bias);
            dst[7 + p] = fmaf(seff, (float)ip1[p], bias);
        }
        vmax  = fmaf(seff, (float)gmax, bias);
        vnmax = -fmaf(seff, (float)gmin, bias);
    }
    blockAtomicMax2(vmax, vnmax, scal + 1, scal + 2);
}

// ---------------- conv2: 3 img/block, i8 codes, batched-load dot4 ----------------
#define C2_ROWP 16
#define C2_CIS  (14*C2_ROWP)
#define C2_IMGS (6*C2_CIS)

__global__ __launch_bounds__(256) void conv2_kernel(const float* __restrict__ b2,
                                                    float* __restrict__ wsf) {
    __shared__ unsigned char act[3 * C2_IMGS];
    __shared__ unsigned int wpk[960];
    __shared__ float bsm[16];
    unsigned int* wsu = (unsigned int*)wsf;
    float* scal = wsf;
    const float* out1 = wsf + OFF_OUT1;
    float* out2 = wsf + OFF_OUT2;
    int tid = threadIdx.x;
    int b0 = blockIdx.x * 3;
    int nimg = min(3, BATCH - b0);
    float s1, s2;
    get_qrelu_scales(scal, 1, s1, s2);
    float seff = s2 * scal[10];

    for (int i = tid; i < nimg * 588; i += 256) {
        int img = i / 588, rem = i % 588;
        int e = rem * 2;
        int ci = e / 196, r2 = e % 196;
        int row = r2 / 14, col = r2 % 14;
        float2 v = *(const float2*)&out1[(size_t)(b0 + img) * 1176 + e];
        int r0 = qrelu_code(v.x, s1, s2);
        int r1 = qrelu_code(v.y, s1, s2);
        *(unsigned short*)&act[img * C2_IMGS + ci * C2_CIS + row * C2_ROWP + col] =
            (unsigned short)(r0 | (r1 << 8));
    }
    for (int i = tid; i < 960; i += 256) wpk[i] = wsu[OFF_WPK2 + i];
    if (tid < 16) bsm[tid] = b2[tid];
    __syncthreads();

    float vmax = -INFINITY, vnmax = -INFINITY;
    if (tid < nimg * 80) {
        int img = tid / 80, r = tid % 80;
        int c = r / 5, py = r % 5;
        const unsigned char* ib = &act[img * C2_IMGS + (2 * py) * C2_ROWP];
        int a0[10], a1[10];
        #pragma unroll
        for (int i = 0; i < 10; i++) { a0[i] = 0; a1[i] = 0; }
        #pragma unroll 1
        for (int cig = 0; cig < 3; cig++) {       // 2 input channels per group
            // ---- batched loads: 12 ds_read_b128 issue before compute ----
            uint4 R[2][6];
            #pragma unroll
            for (int g = 0; g < 2; g++)
                #pragma unroll
                for (int r6 = 0; r6 < 6; r6++)
                    R[g][r6] = *(const uint4*)(ib + (2*cig + g) * C2_CIS + r6 * C2_ROWP);
            #pragma unroll
            for (int g = 0; g < 2; g++) {
                int ci = 2*cig + g;
                const unsigned int* wkp = &wpk[(c * 6 + ci) * 10];
                unsigned int wk0[5], wk4[5];
                #pragma unroll
                for (int ky = 0; ky < 5; ky++) { wk0[ky] = wkp[2*ky]; wk4[ky] = wkp[2*ky+1]; }
                #pragma unroll
                for (int r6 = 0; r6 < 6; r6++) {
                    unsigned int wv[4] = { R[g][r6].x, R[g][r6].y, R[g][r6].z, R[g][r6].w };
                    unsigned int up[11];
                    #pragma unroll
                    for (int i = 0; i < 11; i++) up[i] = u32at(wv, i >> 2, i & 3);
                    if (r6 <= 4) {
                        unsigned int w0 = wk0[r6], w4 = wk4[r6];
                        #pragma unroll
                        for (int i = 0; i < 10; i++) {
                            a0[i] = sdot4(up[i], w0, a0[i]);
                            a0[i] = sdot4(up[i+1], w4, a0[i]);
                        }
                    }
                    if (r6 >= 1) {
                        unsigned int w0 = wk0[r6-1], w4 = wk4[r6-1];
                        #pragma unroll
                        for (int i = 0; i < 10; i++) {
                            a1[i] = sdot4(up[i], w0, a1[i]);
                            a1[i] = sdot4(up[i+1], w4, a1[i]);
                        }
                    }
                }
            }
        }
        int gmax = -2000000000, gmin = 2000000000;
        #pragma unroll
        for (int i = 0; i < 10; i++) {
            gmax = max(gmax, max(a0[i], a1[i]));
            gmin = min(gmin, min(a0[i], a1[i]));
        }
        float bias = bsm[c];
        float* dst = &out2[(size_t)(b0 + img) * 400 + c * 25 + py * 5];
        #pragma unroll
        for (int p = 0; p < 5; p++) {
            int ip = max(max(a0[2*p], a0[2*p+1]), max(a1[2*p], a1[2*p+1]));
            dst[p] = fmaf(seff, (float)ip, bias);
        }
        vmax  = fmaf(seff, (float)gmax, bias);
        vnmax = -fmaf(seff, (float)gmin, bias);
    }
    blockAtomicMax2(vmax, vnmax, scal + 3, scal + 4);
}

// ---------------- fc1: [B,400]->[B,120], dot4, 8 rows/block ----------------
__global__ __launch_bounds__(128) void fc1_kernel(const float* __restrict__ fb1,
                                                  float* __restrict__ wsf) {
    __shared__ unsigned int xs[8][100];
    unsigned int* wsu = (unsigned int*)wsf;
    float* scal = wsf;
    const float* p2 = wsf + OFF_OUT2;
    float* p3 = wsf + OFF_P3;
    int tid = threadIdx.x;
    size_t row0 = (size_t)blockIdx.x * 8;
    float s1, s2;
    get_qrelu_scales(scal, 3, s1, s2);
    float seff = s2 * scal[11];
    const float4* src = (const float4*)(p2 + row0 * 400);
    for (int i = tid; i < 800; i += 128) {
        float4 v = src[i];
        int c0 = qrelu_code(v.x, s1, s2), c1 = qrelu_code(v.y, s1, s2);
        int c2 = qrelu_code(v.z, s1, s2), c3 = qrelu_code(v.w, s1, s2);
        xs[i / 100][i % 100] = c0 | (c1 << 8) | (c2 << 16) | ((unsigned)c3 << 24);
    }
    __syncthreads();
    float vmax = -INFINITY, vnmax = -INFINITY;
    if (tid < 120) {
        int j = tid;
        int acc[8];
        #pragma unroll
        for (int r = 0; r < 8; r++) acc[r] = 0;
        const uint4* wrow = (const uint4*)&wsu[OFF_FQ1 + j * 100];
        for (int kg = 0; kg < 25; kg++) {
            uint4 wv = wrow[kg];
            #pragma unroll
            for (int r = 0; r < 8; r++) {
                uint4 xv = *(const uint4*)&xs[r][kg * 4];
                acc[r] = sdot4(xv.x, wv.x, acc[r]);
                acc[r] = sdot4(xv.y, wv.y, acc[r]);
                acc[r] = sdot4(xv.z, wv.z, acc[r]);
                acc[r] = sdot4(xv.w, wv.w, acc[r]);
            }
        }
        float bias = fb1[j];
        #pragma unroll
        for (int r = 0; r < 8; r++) {
            float pv = fmaf(seff, (float)acc[r], bias);
            p3[(row0 + r) * 120 + j] = pv;
            vmax = fmaxf(vmax, pv); vnmax = fmaxf(vnmax, -pv);
        }
    }
    waveAtomicMax2(vmax, vnmax, scal + 5, scal + 6);
}

// ---------------- fc2: [B,120]->[B,84], dot4, 8 rows/block ----------------
__global__ __launch_bounds__(128) void fc2_kernel(const float* __restrict__ fb2,
                                                  float* __restrict__ wsf) {
    __shared__ unsigned int xs[8][32];
    unsigned int* wsu = (unsigned int*)wsf;
    float* scal = wsf;
    const float* p3 = wsf + OFF_P3;
    float* p4 = wsf + OFF_P4;
    int tid = threadIdx.x;
    size_t row0 = (size_t)blockIdx.x * 8;
    float s1, s2;
    get_qrelu_scales(scal, 5, s1, s2);
    float seff = s2 * scal[12];
    const float4* src = (const float4*)(p3 + row0 * 120);
    for (int i = tid; i < 240; i += 128) {
        float4 v = src[i];
        int c0 = qrelu_code(v.x, s1, s2), c1 = qrelu_code(v.y, s1, s2);
        int c2 = qrelu_code(v.z, s1, s2), c3 = qrelu_code(v.w, s1, s2);
        xs[i / 30][i % 30] = c0 | (c1 << 8) | (c2 << 16) | ((unsigned)c3 << 24);
    }
    if (tid < 16) xs[tid >> 1][30 + (tid & 1)] = 0;
    __syncthreads();
    float vmax = -INFINITY, vnmax = -INFINITY;
    if (tid < 84) {
        int j = tid;
        int acc[8];
        #pragma unroll
        for (int r = 0; r < 8; r++) acc[r] = 0;
        const uint4* wrow = (const uint4*)&wsu[OFF_FQ2 + j * 32];
        #pragma unroll
        for (int kg = 0; kg < 8; kg++) {
            uint4 wv = wrow[kg];
            #pragma unroll
            for (int r = 0; r < 8; r++) {
                uint4 xv = *(const uint4*)&xs[r][kg * 4];
                acc[r] = sdot4(xv.x, wv.x, acc[r]);
                acc[r] = sdot4(xv.y, wv.y, acc[r]);
                acc[r] = sdot4(xv.z, wv.z, acc[r]);
                acc[r] = sdot4(xv.w, wv.w, acc[r]);
            }
        }
        float bias = fb2[j];
        #pragma unroll
        for (int r = 0; r < 8; r++) {
            float pv = fmaf(seff, (float)acc[r], bias);
            p4[(row0 + r) * 84 + j] = pv;
            vmax = fmaxf(vmax, pv); vnmax = fmaxf(vnmax, -pv);
        }
    }
    waveAtomicMax2(vmax, vnmax, scal + 7, scal + 8);
}

// ---------------- fc3: [B,84]->[B,10], dot4, 1 row/thread ----------------
__global__ __launch_bounds__(256) void fc3_kernel(const float* __restrict__ fb3,
                                                  float* __restrict__ out,
                                                  float* __restrict__ wsf) {
    __shared__ unsigned int wsm[240];
    __shared__ float bs[10];
    unsigned int* wsu = (unsigned int*)wsf;
    float* scal = wsf;
    const float* p4 = wsf + OFF_P4;
    int tid = threadIdx.x;
    for (int i = tid; i < 240; i += 256) wsm[i] = wsu[OFF_FQ3 + i];
    if (tid < 10) bs[tid] = fb3[tid];
    __syncthreads();
    float s1, s2;
    get_qrelu_scales(scal, 7, s1, s2);
    float seff = s2 * scal[13];
    size_t row = (size_t)blockIdx.x * 256 + tid;
    unsigned int xr[24];
    const float4* src = (const float4*)(p4 + row * 84);
    #pragma unroll
    for (int k = 0; k < 21; k++) {
        float4 v = src[k];
        int c0 = qrelu_code(v.x, s1, s2), c1 = qrelu_code(v.y, s1, s2);
        int c2 = qrelu_code(v.z, s1, s2), c3 = qrelu_code(v.w, s1, s2);
        xr[k] = c0 | (c1 << 8) | (c2 << 16) | ((unsigned)c3 << 24);
    }
    xr[21] = 0; xr[22] = 0; xr[23] = 0;
    #pragma unroll
    for (int j = 0; j < 10; j++) {
        int acc = 0;
        #pragma unroll
        for (int k = 0; k < 24; k++) acc = sdot4(xr[k], wsm[j * 24 + k], acc);
        out[row * 10 + j] = fmaf(seff, (float)acc, bs[j]);
    }
}

extern "C" void kernel_launch(void* const* d_in, const int* in_sizes, int n_in,
                              void* d_out, int out_size, void* d_ws, size_t ws_size,
                              hipStream_t stream) {
    const float* input = (const float*)d_in[0];
    const float* w1  = (const float*)d_in[1];
    const float* b1  = (const float*)d_in[2];
    const float* w2  = (const float*)d_in[3];
    const float* b2  = (const float*)d_in[4];
    const float* fw1 = (const float*)d_in[5];
    const float* fb1 = (const float*)d_in[6];
    const float* fw2 = (const float*)d_in[7];
    const float* fb2 = (const float*)d_in[8];
    const float* fw3 = (const float*)d_in[9];
    const float* fb3 = (const float*)d_in[10];
    float* ws  = (float*)d_ws;
    float* out = (float*)d_out;

    prep_kernel<<<6, 256, 0, stream>>>(w1, w2, fw1, fw2, fw3, ws);
    absmax_kernel<<<2048, 256, 0, stream>>>((const float4*)input,
                                            (int)((size_t)BATCH * 3072 / 4), ws);
    conv1_kernel<<<(BATCH + 2) / 3, 256, 0, stream>>>(input, b1, ws);
    conv2_kernel<<<(BATCH + 2) / 3, 256, 0, stream>>>(b2, ws);
    fc1_kernel<<<BATCH / 8, 128, 0, stream>>>(fb1, ws);
    fc2_kernel<<<BATCH / 8, 128, 0, stream>>>(fb2, ws);
    fc3_kernel<<<BATCH / 256, 256, 0, stream>>>(fb3, out, ws);
}

// Round 8
// 823.764 us; speedup vs baseline: 1.1981x; 1.1981x over previous
//
#include <hip/hip_runtime.h>
#include <math.h>

#define BATCH 16384
#define EPSQ 1e-8f

// ---------------- ws layout (32-bit units) ----------------
// scal (uint keys, order-preserving float map): [0] absmax_in, [1,2] conv1 max/negmax,
//   [3,4] conv2, [5,6] fc1, [7,8] fc2.  float: [9] s_w1 [10] s_w2 [11] s_w3 [12] s_w4 [13] s_w5
#define OFF_SCAL 0
#define OFF_WPK1 16      // 180 u32  : conv1 sign-packs [6][3][5]{w0123,w4pack}
#define OFF_WPK2 196     // 960 u32  : conv2 sign-packs [16][6][5]{...}
#define OFF_FQ1  1156    // 12000 u32: fc1 signs [120][100]
#define OFF_FQ2  13156   // 2688 u32 : fc2 signs [84][32] (k>=30 zero)
#define OFF_FQ3  15844   // 240 u32  : fc3 signs [10][24] (k>=21 zero)
#define OFF_OUT1 16384   // B*1176 fp32 pooled conv1 preact
#define N_OUT1   (BATCH*1176)
#define OFF_OUT2 (OFF_OUT1+N_OUT1)   // B*400 fp32 pooled conv2 preact
#define N_OUT2   (BATCH*400)
#define OFF_P3   (OFF_OUT2+N_OUT2)   // B*120 fc1 preact
#define N_P3     (BATCH*120)
#define OFF_P4   (OFF_P3+N_P3)       // B*84 fc2 preact

__device__ inline int sdot4(unsigned int a, unsigned int b, int c) {
    return __builtin_amdgcn_sdot4((int)a, (int)b, c, false);
}

// order-preserving float<->uint map (exact, bijective, monotone for non-NaN)
__device__ inline unsigned int fkey(float f) {
    unsigned int u = __float_as_uint(f);
    return (u & 0x80000000u) ? ~u : (u | 0x80000000u);
}
__device__ inline float fdec(unsigned int k) {
    unsigned int u = (k & 0x80000000u) ? (k ^ 0x80000000u) : ~k;
    return __uint_as_float(u);
}
#define KEY_ZERO   0x80000000u   // fkey(0.0f)
#define KEY_NEGINF 0x007FFFFFu   // fkey(-inf)

__device__ inline float waveMax(float v) {
    #pragma unroll
    for (int off = 32; off > 0; off >>= 1)
        v = fmaxf(v, __shfl_down(v, off, 64));
    return v;
}

// 256-thread block: reduce then ONE fire-and-forget HW atomic per scalar (no CAS loop)
__device__ inline void blockAtomicMax2(float vmax, float vnmax,
                                       unsigned int* gmax, unsigned int* gnmax) {
    __shared__ float sm[4], sn[4];
    float a = waveMax(vmax), b = waveMax(vnmax);
    int tid = threadIdx.x;
    if ((tid & 63) == 0) { sm[tid >> 6] = a; sn[tid >> 6] = b; }
    __syncthreads();
    if (tid == 0) {
        atomicMax(gmax, fkey(fmaxf(fmaxf(sm[0], sm[1]), fmaxf(sm[2], sm[3]))));
        atomicMax(gnmax, fkey(fmaxf(fmaxf(sn[0], sn[1]), fmaxf(sn[2], sn[3]))));
    }
}

// 128-thread block (2 waves) variant
__device__ inline void block2AtomicMax2(float vmax, float vnmax,
                                        unsigned int* gmax, unsigned int* gnmax) {
    __shared__ float sm[2], sn[2];
    float a = waveMax(vmax), b = waveMax(vnmax);
    int tid = threadIdx.x;
    if ((tid & 63) == 0) { sm[tid >> 6] = a; sn[tid >> 6] = b; }
    __syncthreads();
    if (tid == 0) {
        atomicMax(gmax, fkey(fmaxf(sm[0], sm[1])));
        atomicMax(gnmax, fkey(fmaxf(sn[0], sn[1])));
    }
}

// int8 fake-quant pieces (IEEE div matches jnp.round(x/s) bins)
__device__ inline float fq_elem(float x, float s) {
    float q = fminf(fmaxf(rintf(x / s), -128.0f), 127.0f);
    return q * s;
}

// qrelu returning INTEGER code r in [0,127] (value = r*s2)
__device__ inline int qrelu_code(float x, float s1, float s2) {
    float q = fq_elem(x, s1);
    q = fmaxf(q, 0.0f);
    return (int)fminf(fmaxf(rintf(q / s2), -128.0f), 127.0f);
}

__device__ inline void get_qrelu_scales(const unsigned int* scalu, int slot,
                                        float& s1, float& s2) {
    float maxa = fdec(scalu[slot]), negm = fdec(scalu[slot + 1]);
    float absm = fmaxf(maxa, negm);
    s1 = fmaxf(absm / 127.0f, EPSQ);
    float qm = fminf(fmaxf(rintf(maxa / s1), -128.0f), 127.0f) * s1;
    s2 = fmaxf(fmaxf(qm, 0.0f) / 127.0f, EPSQ);
}

__device__ inline unsigned int sgn8(float w) { return (w >= 0.0f) ? 0x01u : 0xFFu; }

// bytes k..k+3 from word pair (static k after unroll)
__device__ inline unsigned int u32at(const unsigned int* wv, int wi, int k) {
    return (k == 0) ? wv[wi]
        : __builtin_amdgcn_perm(wv[wi + 1], wv[wi], 0x03020100u + 0x01010101u * (unsigned)k);
}

// ---------------- prep: scalars + sign-pack all weights ----------------
__global__ __launch_bounds__(256) void prep_kernel(const float* __restrict__ w1,
        const float* __restrict__ w2, const float* __restrict__ fw1,
        const float* __restrict__ fw2, const float* __restrict__ fw3,
        float* __restrict__ wsf) {
    int blk = blockIdx.x, tid = threadIdx.x;
    unsigned int* wsu = (unsigned int*)wsf;
    if (blk == 0) {
        if (tid == 0) wsu[0] = KEY_ZERO;
        else if (tid <= 8) wsu[tid] = KEY_NEGINF;
        return;
    }
    const float* src = nullptr; int N = 0;
    if (blk == 1)      { src = w1;  N = 450; }
    else if (blk == 2) { src = w2;  N = 2400; }
    else if (blk == 3) { src = fw1; N = 48000; }
    else if (blk == 4) { src = fw2; N = 10080; }
    else               { src = fw3; N = 840; }
    __shared__ float red[256];
    float partial = 0.0f;
    for (int i = tid; i < N; i += 256) partial += fabsf(src[i]);
    red[tid] = partial;
    __syncthreads();
    for (int s = 128; s > 0; s >>= 1) {
        if (tid < s) red[tid] += red[tid + s];
        __syncthreads();
    }
    if (tid == 0) wsf[8 + blk] = red[0] / (float)N;   // ws[9..13] plain float

    if (blk == 1) {
        for (int t = tid; t < 90; t += 256) {         // (c,ci,ky)
            const float* wp = w1 + t * 5;
            wsu[OFF_WPK1 + 2*t] = sgn8(wp[0]) | (sgn8(wp[1])<<8) | (sgn8(wp[2])<<16) | (sgn8(wp[3])<<24);
            wsu[OFF_WPK1 + 2*t + 1] = sgn8(wp[4]) << 24;
        }
    } else if (blk == 2) {
        for (int t = tid; t < 480; t += 256) {
            const float* wp = w2 + t * 5;
            wsu[OFF_WPK2 + 2*t] = sgn8(wp[0]) | (sgn8(wp[1])<<8) | (sgn8(wp[2])<<16) | (sgn8(wp[3])<<24);
            wsu[OFF_WPK2 + 2*t + 1] = sgn8(wp[4]) << 24;
        }
    } else if (blk == 3) {
        for (int i = tid; i < 12000; i += 256) {
            int j = i / 100, k = i % 100;
            const float* wp = fw1 + j * 400 + k * 4;
            wsu[OFF_FQ1 + i] = sgn8(wp[0]) | (sgn8(wp[1])<<8) | (sgn8(wp[2])<<16) | (sgn8(wp[3])<<24);
        }
    } else if (blk == 4) {
        for (int i = tid; i < 2688; i += 256) {
            int j = i >> 5, k = i & 31;
            unsigned int u = 0;
            if (k < 30) {
                const float* wp = fw2 + j * 120 + k * 4;
                u = sgn8(wp[0]) | (sgn8(wp[1])<<8) | (sgn8(wp[2])<<16) | (sgn8(wp[3])<<24);
            }
            wsu[OFF_FQ2 + i] = u;
        }
    } else {
        for (int i = tid; i < 240; i += 256) {
            int j = i / 24, k = i % 24;
            unsigned int u = 0;
            if (k < 21) {
                const float* wp = fw3 + j * 84 + k * 4;
                u = sgn8(wp[0]) | (sgn8(wp[1])<<8) | (sgn8(wp[2])<<16) | (sgn8(wp[3])<<24);
            }
            wsu[OFF_FQ3 + i] = u;
        }
    }
}

// ---------------- input abs-max (1 fire-and-forget atomic per block) ----------------
__global__ __launch_bounds__(256) void absmax_kernel(const float4* __restrict__ x, int n4,
                                                     unsigned int* __restrict__ gkey) {
    float m = 0.0f;
    int stride = gridDim.x * 256;
    for (int i = blockIdx.x * 256 + threadIdx.x; i < n4; i += stride) {
        float4 v = x[i];
        m = fmaxf(m, fmaxf(fmaxf(fabsf(v.x), fabsf(v.y)), fmaxf(fabsf(v.z), fabsf(v.w))));
    }
    __shared__ float sm[4];
    m = waveMax(m);
    int tid = threadIdx.x;
    if ((tid & 63) == 0) sm[tid >> 6] = m;
    __syncthreads();
    if (tid == 0)
        atomicMax(gkey, fkey(fmaxf(fmaxf(sm[0], sm[1]), fmaxf(sm[2], sm[3]))));
}

// ---------------- conv1: 3 img/block, i8 codes in LDS, batched-load dot4 conv ------
#define C1_ROWP 48
#define C1_CIS  (32*C1_ROWP)
#define C1_IMGS (3*C1_CIS)

template<int PH>
__device__ __forceinline__ void c1_phase(const unsigned char* ib, const unsigned int* wcp,
                                         int* ip, int& gmax, int& gmin) {
    int a0[14], a1[14];
    #pragma unroll
    for (int i = 0; i < 14; i++) { a0[i] = 0; a1[i] = 0; }
    #pragma unroll 1
    for (int ci = 0; ci < 3; ci++) {
        uint4 A[6]; unsigned int Bv[6];
        const unsigned char* cb = ib + ci * C1_CIS;
        #pragma unroll
        for (int r = 0; r < 6; r++) {
            const unsigned char* rb = cb + r * C1_ROWP;
            if (PH == 0) {
                A[r]  = *(const uint4*)(rb);
                Bv[r] = *(const unsigned int*)(rb + 16);
            } else {
                Bv[r] = *(const unsigned int*)(rb + 12);
                A[r]  = *(const uint4*)(rb + 16);
            }
        }
        const unsigned int* wkp = wcp + ci * 10;
        unsigned int wk0[5], wk4[5];
        #pragma unroll
        for (int ky = 0; ky < 5; ky++) { wk0[ky] = wkp[2*ky]; wk4[ky] = wkp[2*ky+1]; }
        #pragma unroll
        for (int r6 = 0; r6 < 6; r6++) {
            unsigned int wq[5];
            if (PH == 0) {
                wq[0] = A[r6].x; wq[1] = A[r6].y; wq[2] = A[r6].z; wq[3] = A[r6].w; wq[4] = Bv[r6];
            } else {
                wq[0] = __builtin_amdgcn_perm(A[r6].x, Bv[r6],  0x05040302u);
                wq[1] = __builtin_amdgcn_perm(A[r6].y, A[r6].x, 0x05040302u);
                wq[2] = __builtin_amdgcn_perm(A[r6].z, A[r6].y, 0x05040302u);
                wq[3] = __builtin_amdgcn_perm(A[r6].w, A[r6].z, 0x05040302u);
                wq[4] = __builtin_amdgcn_perm(A[r6].w, A[r6].w, 0x00000302u);
            }
            unsigned int up[15];
            #pragma unroll
            for (int i = 0; i < 15; i++) up[i] = u32at(wq, i >> 2, i & 3);
            if (r6 <= 4) {
                unsigned int w0 = wk0[r6], w4 = wk4[r6];
                #pragma unroll
                for (int i = 0; i < 14; i++) {
                    a0[i] = sdot4(up[i], w0, a0[i]);
                    a0[i] = sdot4(up[i+1], w4, a0[i]);
                }
            }
            if (r6 >= 1) {
                unsigned int w0 = wk0[r6-1], w4 = wk4[r6-1];
                #pragma unroll
                for (int i = 0; i < 14; i++) {
                    a1[i] = sdot4(up[i], w0, a1[i]);
                    a1[i] = sdot4(up[i+1], w4, a1[i]);
                }
            }
        }
    }
    #pragma unroll
    for (int i = 0; i < 14; i++) {
        gmax = max(gmax, max(a0[i], a1[i]));
        gmin = min(gmin, min(a0[i], a1[i]));
    }
    #pragma unroll
    for (int p = 0; p < 7; p++)
        ip[p] = max(max(a0[2*p], a0[2*p+1]), max(a1[2*p], a1[2*p+1]));
}

__global__ __launch_bounds__(256) void conv1_kernel(const float* __restrict__ x,
        const float* __restrict__ b1, float* __restrict__ wsf) {
    __shared__ unsigned char xq[3 * C1_IMGS];
    __shared__ unsigned int wpk[180];
    __shared__ float bsm[6];
    unsigned int* wsu = (unsigned int*)wsf;
    float* out1 = wsf + OFF_OUT1;
    int tid = threadIdx.x;
    int b0 = blockIdx.x * 3;
    int nimg = min(3, BATCH - b0);
    float s0 = fmaxf(fdec(wsu[0]) / 127.0f, EPSQ);
    float seff = s0 * wsf[9];

    const float4* xb = (const float4*)(x + (size_t)b0 * 3072);
    for (int i = tid; i < nimg * 768; i += 256) {
        float4 v = xb[i];
        int q0 = (int)fminf(fmaxf(rintf(v.x / s0), -128.f), 127.f);
        int q1 = (int)fminf(fmaxf(rintf(v.y / s0), -128.f), 127.f);
        int q2 = (int)fminf(fmaxf(rintf(v.z / s0), -128.f), 127.f);
        int q3 = (int)fminf(fmaxf(rintf(v.w / s0), -128.f), 127.f);
        unsigned int u = (q0 & 255) | ((q1 & 255) << 8) | ((q2 & 255) << 16)
                       | ((unsigned)(q3 & 255) << 24);
        int idx = i * 4;
        int img = idx / 3072, rem = idx % 3072;
        int ci = rem >> 10, r2 = rem & 1023;
        int row = r2 >> 5, col = r2 & 31;
        *(unsigned int*)&xq[img * C1_IMGS + ci * C1_CIS + row * C1_ROWP + col] = u;
    }
    for (int i = tid; i < 180; i += 256) wpk[i] = wsu[OFF_WPK1 + i];
    if (tid < 6) bsm[tid] = b1[tid];
    __syncthreads();

    float vmax = -INFINITY, vnmax = -INFINITY;
    if (tid < nimg * 84) {
        int img = tid / 84, r = tid % 84;
        int c = r / 14, py = r % 14;
        const unsigned char* ib = &xq[img * C1_IMGS + (2 * py) * C1_ROWP];
        const unsigned int* wcp = &wpk[c * 30];
        int ip0[7], ip1[7];
        int gmax = -2000000000, gmin = 2000000000;
        c1_phase<0>(ib, wcp, ip0, gmax, gmin);
        c1_phase<1>(ib, wcp, ip1, gmax, gmin);
        float bias = bsm[c];
        float* dst = &out1[(size_t)(b0 + img) * 1176 + c * 196 + py * 14];
        #pragma unroll
        for (int p = 0; p < 7; p++) {
            dst[p]     = fmaf(seff, (float)ip0[p], bias);
            dst[7 + p] = fmaf(seff, (float)ip1[p], bias);
        }
        vmax  = fmaf(seff, (float)gmax, bias);
        vnmax = -fmaf(seff, (float)gmin, bias);
    }
    blockAtomicMax2(vmax, vnmax, wsu + 1, wsu + 2);
}

// ---------------- conv2: 3 img/block, i8 codes, batched-load dot4 ----------------
#define C2_ROWP 16
#define C2_CIS  (14*C2_ROWP)
#define C2_IMGS (6*C2_CIS)

__global__ __launch_bounds__(256) void conv2_kernel(const float* __restrict__ b2,
                                                    float* __restrict__ wsf) {
    __shared__ unsigned char act[3 * C2_IMGS];
    __shared__ unsigned int wpk[960];
    __shared__ float bsm[16];
    unsigned int* wsu = (unsigned int*)wsf;
    const float* out1 = wsf + OFF_OUT1;
    float* out2 = wsf + OFF_OUT2;
    int tid = threadIdx.x;
    int b0 = blockIdx.x * 3;
    int nimg = min(3, BATCH - b0);
    float s1, s2;
    get_qrelu_scales(wsu, 1, s1, s2);
    float seff = s2 * wsf[10];

    for (int i = tid; i < nimg * 588; i += 256) {
        int img = i / 588, rem = i % 588;
        int e = rem * 2;
        int ci = e / 196, r2 = e % 196;
        int row = r2 / 14, col = r2 % 14;
        float2 v = *(const float2*)&out1[(size_t)(b0 + img) * 1176 + e];
        int r0 = qrelu_code(v.x, s1, s2);
        int r1 = qrelu_code(v.y, s1, s2);
        *(unsigned short*)&act[img * C2_IMGS + ci * C2_CIS + row * C2_ROWP + col] =
            (unsigned short)(r0 | (r1 << 8));
    }
    for (int i = tid; i < 960; i += 256) wpk[i] = wsu[OFF_WPK2 + i];
    if (tid < 16) bsm[tid] = b2[tid];
    __syncthreads();

    float vmax = -INFINITY, vnmax = -INFINITY;
    if (tid < nimg * 80) {
        int img = tid / 80, r = tid % 80;
        int c = r / 5, py = r % 5;
        const unsigned char* ib = &act[img * C2_IMGS + (2 * py) * C2_ROWP];
        int a0[10], a1[10];
        #pragma unroll
        for (int i = 0; i < 10; i++) { a0[i] = 0; a1[i] = 0; }
        #pragma unroll 1
        for (int cig = 0; cig < 3; cig++) {
            uint4 R[2][6];
            #pragma unroll
            for (int g = 0; g < 2; g++)
                #pragma unroll
                for (int r6 = 0; r6 < 6; r6++)
                    R[g][r6] = *(const uint4*)(ib + (2*cig + g) * C2_CIS + r6 * C2_ROWP);
            #pragma unroll
            for (int g = 0; g < 2; g++) {
                int ci = 2*cig + g;
                const unsigned int* wkp = &wpk[(c * 6 + ci) * 10];
                unsigned int wk0[5], wk4[5];
                #pragma unroll
                for (int ky = 0; ky < 5; ky++) { wk0[ky] = wkp[2*ky]; wk4[ky] = wkp[2*ky+1]; }
                #pragma unroll
                for (int r6 = 0; r6 < 6; r6++) {
                    unsigned int wv[4] = { R[g][r6].x, R[g][r6].y, R[g][r6].z, R[g][r6].w };
                    unsigned int up[11];
                    #pragma unroll
                    for (int i = 0; i < 11; i++) up[i] = u32at(wv, i >> 2, i & 3);
                    if (r6 <= 4) {
                        unsigned int w0 = wk0[r6], w4 = wk4[r6];
                        #pragma unroll
                        for (int i = 0; i < 10; i++) {
                            a0[i] = sdot4(up[i], w0, a0[i]);
                            a0[i] = sdot4(up[i+1], w4, a0[i]);
                        }
                    }
                    if (r6 >= 1) {
                        unsigned int w0 = wk0[r6-1], w4 = wk4[r6-1];
                        #pragma unroll
                        for (int i = 0; i < 10; i++) {
                            a1[i] = sdot4(up[i], w0, a1[i]);
                            a1[i] = sdot4(up[i+1], w4, a1[i]);
                        }
                    }
                }
            }
        }
        int gmax = -2000000000, gmin = 2000000000;
        #pragma unroll
        for (int i = 0; i < 10; i++) {
            gmax = max(gmax, max(a0[i], a1[i]));
            gmin = min(gmin, min(a0[i], a1[i]));
        }
        float bias = bsm[c];
        float* dst = &out2[(size_t)(b0 + img) * 400 + c * 25 + py * 5];
        #pragma unroll
        for (int p = 0; p < 5; p++) {
            int ip = max(max(a0[2*p], a0[2*p+1]), max(a1[2*p], a1[2*p+1]));
            dst[p] = fmaf(seff, (float)ip, bias);
        }
        vmax  = fmaf(seff, (float)gmax, bias);
        vnmax = -fmaf(seff, (float)gmin, bias);
    }
    blockAtomicMax2(vmax, vnmax, wsu + 3, wsu + 4);
}

// ---------------- fc1: [B,400]->[B,120], dot4, 8 rows/block ----------------
__global__ __launch_bounds__(128) void fc1_kernel(const float* __restrict__ fb1,
                                                  float* __restrict__ wsf) {
    __shared__ unsigned int xs[8][100];
    unsigned int* wsu = (unsigned int*)wsf;
    const float* p2 = wsf + OFF_OUT2;
    float* p3 = wsf + OFF_P3;
    int tid = threadIdx.x;
    size_t row0 = (size_t)blockIdx.x * 8;
    float s1, s2;
    get_qrelu_scales(wsu, 3, s1, s2);
    float seff = s2 * wsf[11];
    const float4* src = (const float4*)(p2 + row0 * 400);
    for (int i = tid; i < 800; i += 128) {
        float4 v = src[i];
        int c0 = qrelu_code(v.x, s1, s2), c1 = qrelu_code(v.y, s1, s2);
        int c2 = qrelu_code(v.z, s1, s2), c3 = qrelu_code(v.w, s1, s2);
        xs[i / 100][i % 100] = c0 | (c1 << 8) | (c2 << 16) | ((unsigned)c3 << 24);
    }
    __syncthreads();
    float vmax = -INFINITY, vnmax = -INFINITY;
    if (tid < 120) {
        int j = tid;
        int acc[8];
        #pragma unroll
        for (int r = 0; r < 8; r++) acc[r] = 0;
        const uint4* wrow = (const uint4*)&wsu[OFF_FQ1 + j * 100];
        for (int kg = 0; kg < 25; kg++) {
            uint4 wv = wrow[kg];
            #pragma unroll
            for (int r = 0; r < 8; r++) {
                uint4 xv = *(const uint4*)&xs[r][kg * 4];
                acc[r] = sdot4(xv.x, wv.x, acc[r]);
                acc[r] = sdot4(xv.y, wv.y, acc[r]);
                acc[r] = sdot4(xv.z, wv.z, acc[r]);
                acc[r] = sdot4(xv.w, wv.w, acc[r]);
            }
        }
        float bias = fb1[j];
        #pragma unroll
        for (int r = 0; r < 8; r++) {
            float pv = fmaf(seff, (float)acc[r], bias);
            p3[(row0 + r) * 120 + j] = pv;
            vmax = fmaxf(vmax, pv); vnmax = fmaxf(vnmax, -pv);
        }
    }
    block2AtomicMax2(vmax, vnmax, wsu + 5, wsu + 6);
}

// ---------------- fc2: [B,120]->[B,84], dot4, 8 rows/block ----------------
__global__ __launch_bounds__(128) void fc2_kernel(const float* __restrict__ fb2,
                                                  float* __restrict__ wsf) {
    __shared__ unsigned int xs[8][32];
    unsigned int* wsu = (unsigned int*)wsf;
    const float* p3 = wsf + OFF_P3;
    float* p4 = wsf + OFF_P4;
    int tid = threadIdx.x;
    size_t row0 = (size_t)blockIdx.x * 8;
    float s1, s2;
    get_qrelu_scales(wsu, 5, s1, s2);
    float seff = s2 * wsf[12];
    const float4* src = (const float4*)(p3 + row0 * 120);
    for (int i = tid; i < 240; i += 128) {
        float4 v = src[i];
        int c0 = qrelu_code(v.x, s1, s2), c1 = qrelu_code(v.y, s1, s2);
        int c2 = qrelu_code(v.z, s1, s2), c3 = qrelu_code(v.w, s1, s2);
        xs[i / 30][i % 30] = c0 | (c1 << 8) | (c2 << 16) | ((unsigned)c3 << 24);
    }
    if (tid < 16) xs[tid >> 1][30 + (tid & 1)] = 0;
    __syncthreads();
    float vmax = -INFINITY, vnmax = -INFINITY;
    if (tid < 84) {
        int j = tid;
        int acc[8];
        #pragma unroll
        for (int r = 0; r < 8; r++) acc[r] = 0;
        const uint4* wrow = (const uint4*)&wsu[OFF_FQ2 + j * 32];
        #pragma unroll
        for (int kg = 0; kg < 8; kg++) {
            uint4 wv = wrow[kg];
            #pragma unroll
            for (int r = 0; r < 8; r++) {
                uint4 xv = *(const uint4*)&xs[r][kg * 4];
                acc[r] = sdot4(xv.x, wv.x, acc[r]);
                acc[r] = sdot4(xv.y, wv.y, acc[r]);
                acc[r] = sdot4(xv.z, wv.z, acc[r]);
                acc[r] = sdot4(xv.w, wv.w, acc[r]);
            }
        }
        float bias = fb2[j];
        #pragma unroll
        for (int r = 0; r < 8; r++) {
            float pv = fmaf(seff, (float)acc[r], bias);
            p4[(row0 + r) * 84 + j] = pv;
            vmax = fmaxf(vmax, pv); vnmax = fmaxf(vnmax, -pv);
        }
    }
    block2AtomicMax2(vmax, vnmax, wsu + 7, wsu + 8);
}

// ---------------- fc3: [B,84]->[B,10], dot4, 1 row/thread ----------------
__global__ __launch_bounds__(256) void fc3_kernel(const float* __restrict__ fb3,
                                                  float* __restrict__ out,
                                                  float* __restrict__ wsf) {
    __shared__ unsigned int wsm[240];
    __shared__ float bs[10];
    unsigned int* wsu = (unsigned int*)wsf;
    const float* p4 = wsf + OFF_P4;
    int tid = threadIdx.x;
    for (int i = tid; i < 240; i += 256) wsm[i] = wsu[OFF_FQ3 + i];
    if (tid < 10) bs[tid] = fb3[tid];
    __syncthreads();
    float s1, s2;
    get_qrelu_scales(wsu, 7, s1, s2);
    float seff = s2 * wsf[13];
    size_t row = (size_t)blockIdx.x * 256 + tid;
    unsigned int xr[24];
    const float4* src = (const float4*)(p4 + row * 84);
    #pragma unroll
    for (int k = 0; k < 21; k++) {
        float4 v = src[k];
        int c0 = qrelu_code(v.x, s1, s2), c1 = qrelu_code(v.y, s1, s2);
        int c2 = qrelu_code(v.z, s1, s2), c3 = qrelu_code(v.w, s1, s2);
        xr[k] = c0 | (c1 << 8) | (c2 << 16) | ((unsigned)c3 << 24);
    }
    xr[21] = 0; xr[22] = 0; xr[23] = 0;
    #pragma unroll
    for (int j = 0; j < 10; j++) {
        int acc = 0;
        #pragma unroll
        for (int k = 0; k < 24; k++) acc = sdot4(xr[k], wsm[j * 24 + k], acc);
        out[row * 10 + j] = fmaf(seff, (float)acc, bs[j]);
    }
}

extern "C" void kernel_launch(void* const* d_in, const int* in_sizes, int n_in,
                              void* d_out, int out_size, void* d_ws, size_t ws_size,
                              hipStream_t stream) {
    const float* input = (const float*)d_in[0];
    const float* w1  = (const float*)d_in[1];
    const float* b1  = (const float*)d_in[2];
    const float* w2  = (const float*)d_in[3];
    const float* b2  = (const float*)d_in[4];
    const float* fw1 = (const float*)d_in[5];
    const float* fb1 = (const float*)d_in[6];
    const float* fw2 = (const float*)d_in[7];
    const float* fb2 = (const float*)d_in[8];
    const float* fw3 = (const float*)d_in[9];
    const float* fb3 = (const float*)d_in[10];
    float* ws  = (float*)d_ws;
    float* out = (float*)d_out;

    prep_kernel<<<6, 256, 0, stream>>>(w1, w2, fw1, fw2, fw3, ws);
    absmax_kernel<<<2048, 256, 0, stream>>>((const float4*)input,
                                            (int)((size_t)BATCH * 3072 / 4),
                                            (unsigned int*)ws);
    conv1_kernel<<<(BATCH + 2) / 3, 256, 0, stream>>>(input, b1, ws);
    conv2_kernel<<<(BATCH + 2) / 3, 256, 0, stream>>>(b2, ws);
    fc1_kernel<<<BATCH / 8, 128, 0, stream>>>(fb1, ws);
    fc2_kernel<<<BATCH / 8, 128, 0, stream>>>(fb2, ws);
    fc3_kernel<<<BATCH / 256, 256, 0, stream>>>(fb3, out, ws);
}

// Round 9
// 761.678 us; speedup vs baseline: 1.2958x; 1.0815x over previous
//
#include <hip/hip_runtime.h>
#include <math.h>

#define BATCH 16384
#define EPSQ 1e-8f

// ---------------- ws layout (32-bit units) ----------------
// scal (uint keys, order-preserving float map): [0] absmax_in, [1,2] conv1 max/negmax,
//   [3,4] conv2, [5,6] fc1, [7,8] fc2.  float: [9] s_w1 [10] s_w2 [11] s_w3 [12] s_w4 [13] s_w5
#define OFF_SCAL 0
#define OFF_WPK1 16      // 180 u32  : conv1 sign-packs [6][3][5]{w0123,w4pack}
#define OFF_WPK2 196     // 960 u32  : conv2 sign-packs [16][6][5]{...}
#define OFF_FQ1  1156    // 12000 u32: fc1 signs [120][100]
#define OFF_FQ2  13156   // 2688 u32 : fc2 signs [84][32] (k>=30 zero)
#define OFF_FQ3  15844   // 240 u32  : fc3 signs [10][24] (k>=21 zero)
#define OFF_OUT1 16384   // B*1176 fp32 pooled conv1 preact
#define N_OUT1   (BATCH*1176)
#define OFF_OUT2 (OFF_OUT1+N_OUT1)   // B*400 fp32 pooled conv2 preact
#define N_OUT2   (BATCH*400)
#define OFF_P3   (OFF_OUT2+N_OUT2)   // B*120 fc1 preact
#define N_P3     (BATCH*120)
#define OFF_P4   (OFF_P3+N_P3)       // B*84 fc2 preact

__device__ inline int sdot4(unsigned int a, unsigned int b, int c) {
    return __builtin_amdgcn_sdot4((int)a, (int)b, c, false);
}

// order-preserving float<->uint map (exact, bijective, monotone for non-NaN)
__device__ inline unsigned int fkey(float f) {
    unsigned int u = __float_as_uint(f);
    return (u & 0x80000000u) ? ~u : (u | 0x80000000u);
}
__device__ inline float fdec(unsigned int k) {
    unsigned int u = (k & 0x80000000u) ? (k ^ 0x80000000u) : ~k;
    return __uint_as_float(u);
}
#define KEY_ZERO   0x80000000u   // fkey(0.0f)
#define KEY_NEGINF 0x007FFFFFu   // fkey(-inf)

__device__ inline float waveMax(float v) {
    #pragma unroll
    for (int off = 32; off > 0; off >>= 1)
        v = fmaxf(v, __shfl_down(v, off, 64));
    return v;
}

// 256-thread block: reduce then ONE fire-and-forget HW atomic per scalar
__device__ inline void blockAtomicMax2(float vmax, float vnmax,
                                       unsigned int* gmax, unsigned int* gnmax) {
    __shared__ float sm[4], sn[4];
    float a = waveMax(vmax), b = waveMax(vnmax);
    int tid = threadIdx.x;
    if ((tid & 63) == 0) { sm[tid >> 6] = a; sn[tid >> 6] = b; }
    __syncthreads();
    if (tid == 0) {
        atomicMax(gmax, fkey(fmaxf(fmaxf(sm[0], sm[1]), fmaxf(sm[2], sm[3]))));
        atomicMax(gnmax, fkey(fmaxf(fmaxf(sn[0], sn[1]), fmaxf(sn[2], sn[3]))));
    }
}

// 128-thread block (2 waves) variant
__device__ inline void block2AtomicMax2(float vmax, float vnmax,
                                        unsigned int* gmax, unsigned int* gnmax) {
    __shared__ float sm[2], sn[2];
    float a = waveMax(vmax), b = waveMax(vnmax);
    int tid = threadIdx.x;
    if ((tid & 63) == 0) { sm[tid >> 6] = a; sn[tid >> 6] = b; }
    __syncthreads();
    if (tid == 0) {
        atomicMax(gmax, fkey(fmaxf(sm[0], sm[1])));
        atomicMax(gnmax, fkey(fmaxf(sn[0], sn[1])));
    }
}

// int8 fake-quant pieces (IEEE div matches jnp.round(x/s) bins)
__device__ inline float fq_elem(float x, float s) {
    float q = fminf(fmaxf(rintf(x / s), -128.0f), 127.0f);
    return q * s;
}

// qrelu returning INTEGER code r in [0,127] (value = r*s2)
__device__ inline int qrelu_code(float x, float s1, float s2) {
    float q = fq_elem(x, s1);
    q = fmaxf(q, 0.0f);
    return (int)fminf(fmaxf(rintf(q / s2), -128.0f), 127.0f);
}

__device__ inline void get_qrelu_scales(const unsigned int* scalu, int slot,
                                        float& s1, float& s2) {
    float maxa = fdec(scalu[slot]), negm = fdec(scalu[slot + 1]);
    float absm = fmaxf(maxa, negm);
    s1 = fmaxf(absm / 127.0f, EPSQ);
    float qm = fminf(fmaxf(rintf(maxa / s1), -128.0f), 127.0f) * s1;
    s2 = fmaxf(fmaxf(qm, 0.0f) / 127.0f, EPSQ);
}

__device__ inline unsigned int sgn8(float w) { return (w >= 0.0f) ? 0x01u : 0xFFu; }

// bytes k..k+3 from word pair (static k after unroll)
__device__ inline unsigned int u32at(const unsigned int* wv, int wi, int k) {
    return (k == 0) ? wv[wi]
        : __builtin_amdgcn_perm(wv[wi + 1], wv[wi], 0x03020100u + 0x01010101u * (unsigned)k);
}

// ---------------- prep: scalars + sign-pack all weights ----------------
__global__ __launch_bounds__(256) void prep_kernel(const float* __restrict__ w1,
        const float* __restrict__ w2, const float* __restrict__ fw1,
        const float* __restrict__ fw2, const float* __restrict__ fw3,
        float* __restrict__ wsf) {
    int blk = blockIdx.x, tid = threadIdx.x;
    unsigned int* wsu = (unsigned int*)wsf;
    if (blk == 0) {
        if (tid == 0) wsu[0] = KEY_ZERO;
        else if (tid <= 8) wsu[tid] = KEY_NEGINF;
        return;
    }
    const float* src = nullptr; int N = 0;
    if (blk == 1)      { src = w1;  N = 450; }
    else if (blk == 2) { src = w2;  N = 2400; }
    else if (blk == 3) { src = fw1; N = 48000; }
    else if (blk == 4) { src = fw2; N = 10080; }
    else               { src = fw3; N = 840; }
    __shared__ float red[256];
    float partial = 0.0f;
    for (int i = tid; i < N; i += 256) partial += fabsf(src[i]);
    red[tid] = partial;
    __syncthreads();
    for (int s = 128; s > 0; s >>= 1) {
        if (tid < s) red[tid] += red[tid + s];
        __syncthreads();
    }
    if (tid == 0) wsf[8 + blk] = red[0] / (float)N;   // ws[9..13] plain float

    if (blk == 1) {
        for (int t = tid; t < 90; t += 256) {         // (c,ci,ky)
            const float* wp = w1 + t * 5;
            wsu[OFF_WPK1 + 2*t] = sgn8(wp[0]) | (sgn8(wp[1])<<8) | (sgn8(wp[2])<<16) | (sgn8(wp[3])<<24);
            wsu[OFF_WPK1 + 2*t + 1] = sgn8(wp[4]) << 24;
        }
    } else if (blk == 2) {
        for (int t = tid; t < 480; t += 256) {
            const float* wp = w2 + t * 5;
            wsu[OFF_WPK2 + 2*t] = sgn8(wp[0]) | (sgn8(wp[1])<<8) | (sgn8(wp[2])<<16) | (sgn8(wp[3])<<24);
            wsu[OFF_WPK2 + 2*t + 1] = sgn8(wp[4]) << 24;
        }
    } else if (blk == 3) {
        for (int i = tid; i < 12000; i += 256) {
            int j = i / 100, k = i % 100;
            const float* wp = fw1 + j * 400 + k * 4;
            wsu[OFF_FQ1 + i] = sgn8(wp[0]) | (sgn8(wp[1])<<8) | (sgn8(wp[2])<<16) | (sgn8(wp[3])<<24);
        }
    } else if (blk == 4) {
        for (int i = tid; i < 2688; i += 256) {
            int j = i >> 5, k = i & 31;
            unsigned int u = 0;
            if (k < 30) {
                const float* wp = fw2 + j * 120 + k * 4;
                u = sgn8(wp[0]) | (sgn8(wp[1])<<8) | (sgn8(wp[2])<<16) | (sgn8(wp[3])<<24);
            }
            wsu[OFF_FQ2 + i] = u;
        }
    } else {
        for (int i = tid; i < 240; i += 256) {
            int j = i / 24, k = i % 24;
            unsigned int u = 0;
            if (k < 21) {
                const float* wp = fw3 + j * 84 + k * 4;
                u = sgn8(wp[0]) | (sgn8(wp[1])<<8) | (sgn8(wp[2])<<16) | (sgn8(wp[3])<<24);
            }
            wsu[OFF_FQ3 + i] = u;
        }
    }
}

// ---------------- input abs-max (1 fire-and-forget atomic per block) ----------------
__global__ __launch_bounds__(256) void absmax_kernel(const float4* __restrict__ x, int n4,
                                                     unsigned int* __restrict__ gkey) {
    float m = 0.0f;
    int stride = gridDim.x * 256;
    for (int i = blockIdx.x * 256 + threadIdx.x; i < n4; i += stride) {
        float4 v = x[i];
        m = fmaxf(m, fmaxf(fmaxf(fabsf(v.x), fabsf(v.y)), fmaxf(fabsf(v.z), fabsf(v.w))));
    }
    __shared__ float sm[4];
    m = waveMax(m);
    int tid = threadIdx.x;
    if ((tid & 63) == 0) sm[tid >> 6] = m;
    __syncthreads();
    if (tid == 0)
        atomicMax(gkey, fkey(fmaxf(fmaxf(sm[0], sm[1]), fmaxf(sm[2], sm[3]))));
}

// ---------------- conv1: 3 img/block, i8 codes in LDS, batched-load dot4 conv ------
#define C1_ROWP 48
#define C1_CIS  (32*C1_ROWP)
#define C1_IMGS (3*C1_CIS)

template<int PH>
__device__ __forceinline__ void c1_phase(const unsigned char* ib, const unsigned int* wcp,
                                         int* ip, int& gmax, int& gmin) {
    int a0[14], a1[14];
    #pragma unroll
    for (int i = 0; i < 14; i++) { a0[i] = 0; a1[i] = 0; }
    #pragma unroll 1
    for (int ci = 0; ci < 3; ci++) {
        uint4 A[6]; unsigned int Bv[6];
        const unsigned char* cb = ib + ci * C1_CIS;
        #pragma unroll
        for (int r = 0; r < 6; r++) {
            const unsigned char* rb = cb + r * C1_ROWP;
            if (PH == 0) {
                A[r]  = *(const uint4*)(rb);
                Bv[r] = *(const unsigned int*)(rb + 16);
            } else {
                Bv[r] = *(const unsigned int*)(rb + 12);
                A[r]  = *(const uint4*)(rb + 16);
            }
        }
        const unsigned int* wkp = wcp + ci * 10;
        unsigned int wk0[5], wk4[5];
        #pragma unroll
        for (int ky = 0; ky < 5; ky++) { wk0[ky] = wkp[2*ky]; wk4[ky] = wkp[2*ky+1]; }
        #pragma unroll
        for (int r6 = 0; r6 < 6; r6++) {
            unsigned int wq[5];
            if (PH == 0) {
                wq[0] = A[r6].x; wq[1] = A[r6].y; wq[2] = A[r6].z; wq[3] = A[r6].w; wq[4] = Bv[r6];
            } else {
                wq[0] = __builtin_amdgcn_perm(A[r6].x, Bv[r6],  0x05040302u);
                wq[1] = __builtin_amdgcn_perm(A[r6].y, A[r6].x, 0x05040302u);
                wq[2] = __builtin_amdgcn_perm(A[r6].z, A[r6].y, 0x05040302u);
                wq[3] = __builtin_amdgcn_perm(A[r6].w, A[r6].z, 0x05040302u);
                wq[4] = __builtin_amdgcn_perm(A[r6].w, A[r6].w, 0x00000302u);
            }
            unsigned int up[15];
            #pragma unroll
            for (int i = 0; i < 15; i++) up[i] = u32at(wq, i >> 2, i & 3);
            if (r6 <= 4) {
                unsigned int w0 = wk0[r6], w4 = wk4[r6];
                #pragma unroll
                for (int i = 0; i < 14; i++) {
                    a0[i] = sdot4(up[i], w0, a0[i]);
                    a0[i] = sdot4(up[i+1], w4, a0[i]);
                }
            }
            if (r6 >= 1) {
                unsigned int w0 = wk0[r6-1], w4 = wk4[r6-1];
                #pragma unroll
                for (int i = 0; i < 14; i++) {
                    a1[i] = sdot4(up[i], w0, a1[i]);
                    a1[i] = sdot4(up[i+1], w4, a1[i]);
                }
            }
        }
    }
    #pragma unroll
    for (int i = 0; i < 14; i++) {
        gmax = max(gmax, max(a0[i], a1[i]));
        gmin = min(gmin, min(a0[i], a1[i]));
    }
    #pragma unroll
    for (int p = 0; p < 7; p++)
        ip[p] = max(max(a0[2*p], a0[2*p+1]), max(a1[2*p], a1[2*p+1]));
}

__global__ __launch_bounds__(256) void conv1_kernel(const float* __restrict__ x,
        const float* __restrict__ b1, float* __restrict__ wsf) {
    // smem is xq (i8 codes, 13824 B) during compute, then fp32 out-staging (14112 B)
    __shared__ __align__(16) unsigned char smem[14112];
    __shared__ unsigned int wpk[180];
    __shared__ float bsm[6];
    unsigned char* xq = smem;
    unsigned int* wsu = (unsigned int*)wsf;
    float* out1 = wsf + OFF_OUT1;
    int tid = threadIdx.x;
    int b0 = blockIdx.x * 3;
    int nimg = min(3, BATCH - b0);
    float s0 = fmaxf(fdec(wsu[0]) / 127.0f, EPSQ);
    float seff = s0 * wsf[9];

    const float4* xb = (const float4*)(x + (size_t)b0 * 3072);
    for (int i = tid; i < nimg * 768; i += 256) {
        float4 v = xb[i];
        int q0 = (int)fminf(fmaxf(rintf(v.x / s0), -128.f), 127.f);
        int q1 = (int)fminf(fmaxf(rintf(v.y / s0), -128.f), 127.f);
        int q2 = (int)fminf(fmaxf(rintf(v.z / s0), -128.f), 127.f);
        int q3 = (int)fminf(fmaxf(rintf(v.w / s0), -128.f), 127.f);
        unsigned int u = (q0 & 255) | ((q1 & 255) << 8) | ((q2 & 255) << 16)
                       | ((unsigned)(q3 & 255) << 24);
        int idx = i * 4;
        int img = idx / 3072, rem = idx % 3072;
        int ci = rem >> 10, r2 = rem & 1023;
        int row = r2 >> 5, col = r2 & 31;
        *(unsigned int*)&xq[img * C1_IMGS + ci * C1_CIS + row * C1_ROWP + col] = u;
    }
    for (int i = tid; i < 180; i += 256) wpk[i] = wsu[OFF_WPK1 + i];
    if (tid < 6) bsm[tid] = b1[tid];
    __syncthreads();

    float vmax = -INFINITY, vnmax = -INFINITY;
    int img = 0, c = 0, py = 0;
    int ip0[7], ip1[7];
    float bias = 0.0f;
    bool active = (tid < nimg * 84);
    if (active) {
        int r = tid % 84;
        img = tid / 84; c = r / 14; py = r % 14;
        const unsigned char* ib = &xq[img * C1_IMGS + (2 * py) * C1_ROWP];
        const unsigned int* wcp = &wpk[c * 30];
        int gmax = -2000000000, gmin = 2000000000;
        c1_phase<0>(ib, wcp, ip0, gmax, gmin);
        c1_phase<1>(ib, wcp, ip1, gmax, gmin);
        bias = bsm[c];
        vmax  = fmaf(seff, (float)gmax, bias);
        vnmax = -fmaf(seff, (float)gmin, bias);
    }
    // ---- coalesced output: stage in LDS (alias xq, now dead), flush as float4 ----
    __syncthreads();
    if (active) {
        float* pb = (float*)smem;
        int base = img * 1176 + (c * 14 + py) * 14;
        #pragma unroll
        for (int p = 0; p < 7; p++) {
            pb[base + p]     = fmaf(seff, (float)ip0[p], bias);
            pb[base + 7 + p] = fmaf(seff, (float)ip1[p], bias);
        }
    }
    __syncthreads();
    {
        const float4* pb4 = (const float4*)smem;
        float4* d4 = (float4*)(out1 + (size_t)b0 * 1176);
        for (int i = tid; i < nimg * 294; i += 256) d4[i] = pb4[i];
    }
    blockAtomicMax2(vmax, vnmax, wsu + 1, wsu + 2);
}

// ---------------- conv2: 3 img/block, i8 codes, batched-load dot4 ----------------
#define C2_ROWP 16
#define C2_CIS  (14*C2_ROWP)
#define C2_IMGS (6*C2_CIS)

__global__ __launch_bounds__(256) void conv2_kernel(const float* __restrict__ b2,
                                                    float* __restrict__ wsf) {
    __shared__ unsigned char act[3 * C2_IMGS];
    __shared__ unsigned int wpk[960];
    __shared__ float bsm[16];
    __shared__ __align__(16) float pbuf[1200];
    unsigned int* wsu = (unsigned int*)wsf;
    const float* out1 = wsf + OFF_OUT1;
    float* out2 = wsf + OFF_OUT2;
    int tid = threadIdx.x;
    int b0 = blockIdx.x * 3;
    int nimg = min(3, BATCH - b0);
    float s1, s2;
    get_qrelu_scales(wsu, 1, s1, s2);
    float seff = s2 * wsf[10];

    for (int i = tid; i < nimg * 588; i += 256) {
        int img = i / 588, rem = i % 588;
        int e = rem * 2;
        int ci = e / 196, r2 = e % 196;
        int row = r2 / 14, col = r2 % 14;
        float2 v = *(const float2*)&out1[(size_t)(b0 + img) * 1176 + e];
        int r0 = qrelu_code(v.x, s1, s2);
        int r1 = qrelu_code(v.y, s1, s2);
        *(unsigned short*)&act[img * C2_IMGS + ci * C2_CIS + row * C2_ROWP + col] =
            (unsigned short)(r0 | (r1 << 8));
    }
    for (int i = tid; i < 960; i += 256) wpk[i] = wsu[OFF_WPK2 + i];
    if (tid < 16) bsm[tid] = b2[tid];
    __syncthreads();

    float vmax = -INFINITY, vnmax = -INFINITY;
    if (tid < nimg * 80) {
        int img = tid / 80, r = tid % 80;
        int c = r / 5, py = r % 5;
        const unsigned char* ib = &act[img * C2_IMGS + (2 * py) * C2_ROWP];
        int a0[10], a1[10];
        #pragma unroll
        for (int i = 0; i < 10; i++) { a0[i] = 0; a1[i] = 0; }
        #pragma unroll 1
        for (int cig = 0; cig < 3; cig++) {
            uint4 R[2][6];
            #pragma unroll
            for (int g = 0; g < 2; g++)
                #pragma unroll
                for (int r6 = 0; r6 < 6; r6++)
                    R[g][r6] = *(const uint4*)(ib + (2*cig + g) * C2_CIS + r6 * C2_ROWP);
            #pragma unroll
            for (int g = 0; g < 2; g++) {
                int ci = 2*cig + g;
                const unsigned int* wkp = &wpk[(c * 6 + ci) * 10];
                unsigned int wk0[5], wk4[5];
                #pragma unroll
                for (int ky = 0; ky < 5; ky++) { wk0[ky] = wkp[2*ky]; wk4[ky] = wkp[2*ky+1]; }
                #pragma unroll
                for (int r6 = 0; r6 < 6; r6++) {
                    unsigned int wv[4] = { R[g][r6].x, R[g][r6].y, R[g][r6].z, R[g][r6].w };
                    unsigned int up[11];
                    #pragma unroll
                    for (int i = 0; i < 11; i++) up[i] = u32at(wv, i >> 2, i & 3);
                    if (r6 <= 4) {
                        unsigned int w0 = wk0[r6], w4 = wk4[r6];
                        #pragma unroll
                        for (int i = 0; i < 10; i++) {
                            a0[i] = sdot4(up[i], w0, a0[i]);
                            a0[i] = sdot4(up[i+1], w4, a0[i]);
                        }
                    }
                    if (r6 >= 1) {
                        unsigned int w0 = wk0[r6-1], w4 = wk4[r6-1];
                        #pragma unroll
                        for (int i = 0; i < 10; i++) {
                            a1[i] = sdot4(up[i], w0, a1[i]);
                            a1[i] = sdot4(up[i+1], w4, a1[i]);
                        }
                    }
                }
            }
        }
        int gmax = -2000000000, gmin = 2000000000;
        #pragma unroll
        for (int i = 0; i < 10; i++) {
            gmax = max(gmax, max(a0[i], a1[i]));
            gmin = min(gmin, min(a0[i], a1[i]));
        }
        float bias = bsm[c];
        int base = img * 400 + c * 25 + py * 5;
        #pragma unroll
        for (int p = 0; p < 5; p++) {
            int ip = max(max(a0[2*p], a0[2*p+1]), max(a1[2*p], a1[2*p+1]));
            pbuf[base + p] = fmaf(seff, (float)ip, bias);
        }
        vmax  = fmaf(seff, (float)gmax, bias);
        vnmax = -fmaf(seff, (float)gmin, bias);
    }
    __syncthreads();
    {
        const float4* pb4 = (const float4*)pbuf;
        float4* d4 = (float4*)(out2 + (size_t)b0 * 400);
        for (int i = tid; i < nimg * 100; i += 256) d4[i] = pb4[i];
    }
    blockAtomicMax2(vmax, vnmax, wsu + 3, wsu + 4);
}

// ---------------- fc1: [B,400]->[B,120], dot4, 8 rows/block ----------------
__global__ __launch_bounds__(128) void fc1_kernel(const float* __restrict__ fb1,
                                                  float* __restrict__ wsf) {
    __shared__ unsigned int xs[8][100];
    __shared__ __align__(16) float pb[960];
    unsigned int* wsu = (unsigned int*)wsf;
    const float* p2 = wsf + OFF_OUT2;
    float* p3 = wsf + OFF_P3;
    int tid = threadIdx.x;
    size_t row0 = (size_t)blockIdx.x * 8;
    float s1, s2;
    get_qrelu_scales(wsu, 3, s1, s2);
    float seff = s2 * wsf[11];
    const float4* src = (const float4*)(p2 + row0 * 400);
    for (int i = tid; i < 800; i += 128) {
        float4 v = src[i];
        int c0 = qrelu_code(v.x, s1, s2), c1 = qrelu_code(v.y, s1, s2);
        int c2 = qrelu_code(v.z, s1, s2), c3 = qrelu_code(v.w, s1, s2);
        xs[i / 100][i % 100] = c0 | (c1 << 8) | (c2 << 16) | ((unsigned)c3 << 24);
    }
    __syncthreads();
    float vmax = -INFINITY, vnmax = -INFINITY;
    if (tid < 120) {
        int j = tid;
        int acc[8];
        #pragma unroll
        for (int r = 0; r < 8; r++) acc[r] = 0;
        const uint4* wrow = (const uint4*)&wsu[OFF_FQ1 + j * 100];
        for (int kg = 0; kg < 25; kg++) {
            uint4 wv = wrow[kg];
            #pragma unroll
            for (int r = 0; r < 8; r++) {
                uint4 xv = *(const uint4*)&xs[r][kg * 4];
                acc[r] = sdot4(xv.x, wv.x, acc[r]);
                acc[r] = sdot4(xv.y, wv.y, acc[r]);
                acc[r] = sdot4(xv.z, wv.z, acc[r]);
                acc[r] = sdot4(xv.w, wv.w, acc[r]);
            }
        }
        float bias = fb1[j];
        #pragma unroll
        for (int r = 0; r < 8; r++) {
            float pv = fmaf(seff, (float)acc[r], bias);
            pb[r * 120 + j] = pv;
            vmax = fmaxf(vmax, pv); vnmax = fmaxf(vnmax, -pv);
        }
    }
    __syncthreads();
    {
        const float4* pb4 = (const float4*)pb;
        float4* d4 = (float4*)(p3 + row0 * 120);
        for (int i = tid; i < 240; i += 128) d4[i] = pb4[i];
    }
    block2AtomicMax2(vmax, vnmax, wsu + 5, wsu + 6);
}

// ---------------- fc2: [B,120]->[B,84], dot4, 8 rows/block ----------------
__global__ __launch_bounds__(128) void fc2_kernel(const float* __restrict__ fb2,
                                                  float* __restrict__ wsf) {
    __shared__ unsigned int xs[8][32];
    __shared__ __align__(16) float pb[672];
    unsigned int* wsu = (unsigned int*)wsf;
    const float* p3 = wsf + OFF_P3;
    float* p4 = wsf + OFF_P4;
    int tid = threadIdx.x;
    size_t row0 = (size_t)blockIdx.x * 8;
    float s1, s2;
    get_qrelu_scales(wsu, 5, s1, s2);
    float seff = s2 * wsf[12];
    const float4* src = (const float4*)(p3 + row0 * 120);
    for (int i = tid; i < 240; i += 128) {
        float4 v = src[i];
        int c0 = qrelu_code(v.x, s1, s2), c1 = qrelu_code(v.y, s1, s2);
        int c2 = qrelu_code(v.z, s1, s2), c3 = qrelu_code(v.w, s1, s2);
        xs[i / 30][i % 30] = c0 | (c1 << 8) | (c2 << 16) | ((unsigned)c3 << 24);
    }
    if (tid < 16) xs[tid >> 1][30 + (tid & 1)] = 0;
    __syncthreads();
    float vmax = -INFINITY, vnmax = -INFINITY;
    if (tid < 84) {
        int j = tid;
        int acc[8];
        #pragma unroll
        for (int r = 0; r < 8; r++) acc[r] = 0;
        const uint4* wrow = (const uint4*)&wsu[OFF_FQ2 + j * 32];
        #pragma unroll
        for (int kg = 0; kg < 8; kg++) {
            uint4 wv = wrow[kg];
            #pragma unroll
            for (int r = 0; r < 8; r++) {
                uint4 xv = *(const uint4*)&xs[r][kg * 4];
                acc[r] = sdot4(xv.x, wv.x, acc[r]);
                acc[r] = sdot4(xv.y, wv.y, acc[r]);
                acc[r] = sdot4(xv.z, wv.z, acc[r]);
                acc[r] = sdot4(xv.w, wv.w, acc[r]);
            }
        }
        float bias = fb2[j];
        #pragma unroll
        for (int r = 0; r < 8; r++) {
            float pv = fmaf(seff, (float)acc[r], bias);
            pb[r * 84 + j] = pv;
            vmax = fmaxf(vmax, pv); vnmax = fmaxf(vnmax, -pv);
        }
    }
    __syncthreads();
    {
        const float4* pb4 = (const float4*)pb;
        float4* d4 = (float4*)(p4 + row0 * 84);
        for (int i = tid; i < 168; i += 128) d4[i] = pb4[i];
    }
    block2AtomicMax2(vmax, vnmax, wsu + 7, wsu + 8);
}

// ---------------- fc3: [B,84]->[B,10], dot4, 1 row/thread ----------------
__global__ __launch_bounds__(256) void fc3_kernel(const float* __restrict__ fb3,
                                                  float* __restrict__ out,
                                                  float* __restrict__ wsf) {
    __shared__ unsigned int wsm[240];
    __shared__ float bs[10];
    __shared__ __align__(16) float pb[2560];
    unsigned int* wsu = (unsigned int*)wsf;
    const float* p4 = wsf + OFF_P4;
    int tid = threadIdx.x;
    for (int i = tid; i < 240; i += 256) wsm[i] = wsu[OFF_FQ3 + i];
    if (tid < 10) bs[tid] = fb3[tid];
    __syncthreads();
    float s1, s2;
    get_qrelu_scales(wsu, 7, s1, s2);
    float seff = s2 * wsf[13];
    size_t row = (size_t)blockIdx.x * 256 + tid;
    unsigned int xr[24];
    const float4* src = (const float4*)(p4 + row * 84);
    #pragma unroll
    for (int k = 0; k < 21; k++) {
        float4 v = src[k];
        int c0 = qrelu_code(v.x, s1, s2), c1 = qrelu_code(v.y, s1, s2);
        int c2 = qrelu_code(v.z, s1, s2), c3 = qrelu_code(v.w, s1, s2);
        xr[k] = c0 | (c1 << 8) | (c2 << 16) | ((unsigned)c3 << 24);
    }
    xr[21] = 0; xr[22] = 0; xr[23] = 0;
    #pragma unroll
    for (int j = 0; j < 10; j++) {
        int acc = 0;
        #pragma unroll
        for (int k = 0; k < 24; k++) acc = sdot4(xr[k], wsm[j * 24 + k], acc);
        pb[tid * 10 + j] = fmaf(seff, (float)acc, bs[j]);
    }
    __syncthreads();
    {
        const float4* pb4 = (const float4*)pb;
        float4* d4 = (float4*)(out + (size_t)blockIdx.x * 2560);
        for (int i = tid; i < 640; i += 256) d4[i] = pb4[i];
    }
}

extern "C" void kernel_launch(void* const* d_in, const int* in_sizes, int n_in,
                              void* d_out, int out_size, void* d_ws, size_t ws_size,
                              hipStream_t stream) {
    const float* input = (const float*)d_in[0];
    const float* w1  = (const float*)d_in[1];
    const float* b1  = (const float*)d_in[2];
    const float* w2  = (const float*)d_in[3];
    const float* b2  = (const float*)d_in[4];
    const float* fw1 = (const float*)d_in[5];
    const float* fb1 = (const float*)d_in[6];
    const float* fw2 = (const float*)d_in[7];
    const float* fb2 = (const float*)d_in[8];
    const float* fw3 = (const float*)d_in[9];
    const float* fb3 = (const float*)d_in[10];
    float* ws  = (float*)d_ws;
    float* out = (float*)d_out;

    prep_kernel<<<6, 256, 0, stream>>>(w1, w2, fw1, fw2, fw3, ws);
    absmax_kernel<<<2048, 256, 0, stream>>>((const float4*)input,
                                            (int)((size_t)BATCH * 3072 / 4),
                                            (unsigned int*)ws);
    conv1_kernel<<<(BATCH + 2) / 3, 256, 0, stream>>>(input, b1, ws);
    conv2_kernel<<<(BATCH + 2) / 3, 256, 0, stream>>>(b2, ws);
    fc1_kernel<<<BATCH / 8, 128, 0, stream>>>(fb1, ws);
    fc2_kernel<<<BATCH / 8, 128, 0, stream>>>(fb2, ws);
    fc3_kernel<<<BATCH / 256, 256, 0, stream>>>(fb3, out, ws);
}

// Round 10
// 581.805 us; speedup vs baseline: 1.6964x; 1.3092x over previous
//
#include <hip/hip_runtime.h>
#include <math.h>

#define BATCH 16384
#define EPSQ 1e-8f

// ---------------- ws layout (32-bit units) ----------------
// scal keys: [0] absmax_in, [1,2] conv1 max/negmax, [3,4] conv2, [5,6] fc1, [7,8] fc2
// floats: [9] s_w1 [10] s_w2 [11] s_w3 [12] s_w4 [13] s_w5
#define OFF_SCAL 0
#define OFF_WPK1 16        // 180 u32
#define OFF_WPK2 196       // 960 u32
#define OFF_FQ1  1156      // 12000 u32
#define OFF_FQ2  13156     // 2688 u32
#define OFF_FQ3  15844     // 240 u32
#define OFF_A    16384
// region A (18,874,368 u32) time-multiplexed:
#define OFF_QIN   OFF_A                 // [B][3][32][48] i8 codes (75.5MB) — quant1->conv1
#define OFF_QC2   OFF_A                 // [B][6][14][16] i8 codes (22MB)  — quant2->conv2
#define OFF_ISUM2 (OFF_A + 6000000)     // [B][400] i16 — conv2->quant3
#define OFF_QC3   (OFF_A + 10000000)    // [B][100] u32 — quant3->fc1
#define OFF_P3    (OFF_A + 12000000)    // [B][120] f32 — fc1->fc2
#define OFF_P4    (OFF_A + 14000000)    // [B][84]  f32 — fc2->fc3
#define OFF_ISUM1 (OFF_A + 18874368)    // [B][1176] i16 (38.5MB) — conv1->quant2
// total ~28.5M u32 = 114 MB

__device__ inline int sdot4(unsigned int a, unsigned int b, int c) {
    return __builtin_amdgcn_sdot4((int)a, (int)b, c, false);
}

// order-preserving float<->uint map
__device__ inline unsigned int fkey(float f) {
    unsigned int u = __float_as_uint(f);
    return (u & 0x80000000u) ? ~u : (u | 0x80000000u);
}
__device__ inline float fdec(unsigned int k) {
    unsigned int u = (k & 0x80000000u) ? (k ^ 0x80000000u) : ~k;
    return __uint_as_float(u);
}
#define KEY_ZERO   0x80000000u
#define KEY_NEGINF 0x007FFFFFu

__device__ inline float waveMax(float v) {
    #pragma unroll
    for (int off = 32; off > 0; off >>= 1)
        v = fmaxf(v, __shfl_down(v, off, 64));
    return v;
}

__device__ inline void blockAtomicMax2(float vmax, float vnmax,
                                       unsigned int* gmax, unsigned int* gnmax) {
    __shared__ float sm[4], sn[4];
    float a = waveMax(vmax), b = waveMax(vnmax);
    int tid = threadIdx.x;
    if ((tid & 63) == 0) { sm[tid >> 6] = a; sn[tid >> 6] = b; }
    __syncthreads();
    if (tid == 0) {
        atomicMax(gmax, fkey(fmaxf(fmaxf(sm[0], sm[1]), fmaxf(sm[2], sm[3]))));
        atomicMax(gnmax, fkey(fmaxf(fmaxf(sn[0], sn[1]), fmaxf(sn[2], sn[3]))));
    }
}

__device__ inline void block2AtomicMax2(float vmax, float vnmax,
                                        unsigned int* gmax, unsigned int* gnmax) {
    __shared__ float sm[2], sn[2];
    float a = waveMax(vmax), b = waveMax(vnmax);
    int tid = threadIdx.x;
    if ((tid & 63) == 0) { sm[tid >> 6] = a; sn[tid >> 6] = b; }
    __syncthreads();
    if (tid == 0) {
        atomicMax(gmax, fkey(fmaxf(sm[0], sm[1])));
        atomicMax(gnmax, fkey(fmaxf(sn[0], sn[1])));
    }
}

__device__ inline float fq_elem(float x, float s) {
    float q = fminf(fmaxf(rintf(x / s), -128.0f), 127.0f);
    return q * s;
}
__device__ inline int qrelu_code(float x, float s1, float s2) {
    float q = fq_elem(x, s1);
    q = fmaxf(q, 0.0f);
    return (int)fminf(fmaxf(rintf(q / s2), -128.0f), 127.0f);
}
__device__ inline void get_qrelu_scales(const unsigned int* scalu, int slot,
                                        float& s1, float& s2) {
    float maxa = fdec(scalu[slot]), negm = fdec(scalu[slot + 1]);
    float absm = fmaxf(maxa, negm);
    s1 = fmaxf(absm / 127.0f, EPSQ);
    float qm = fminf(fmaxf(rintf(maxa / s1), -128.0f), 127.0f) * s1;
    s2 = fmaxf(fmaxf(qm, 0.0f) / 127.0f, EPSQ);
}

__device__ inline unsigned int sgn8(float w) { return (w >= 0.0f) ? 0x01u : 0xFFu; }

__device__ inline unsigned int u32at(const unsigned int* wv, int wi, int k) {
    return (k == 0) ? wv[wi]
        : __builtin_amdgcn_perm(wv[wi + 1], wv[wi], 0x03020100u + 0x01010101u * (unsigned)k);
}

// ---------------- prep ----------------
__global__ __launch_bounds__(256) void prep_kernel(const float* __restrict__ w1,
        const float* __restrict__ w2, const float* __restrict__ fw1,
        const float* __restrict__ fw2, const float* __restrict__ fw3,
        float* __restrict__ wsf) {
    int blk = blockIdx.x, tid = threadIdx.x;
    unsigned int* wsu = (unsigned int*)wsf;
    if (blk == 0) {
        if (tid == 0) wsu[0] = KEY_ZERO;
        else if (tid <= 8) wsu[tid] = KEY_NEGINF;
        return;
    }
    const float* src = nullptr; int N = 0;
    if (blk == 1)      { src = w1;  N = 450; }
    else if (blk == 2) { src = w2;  N = 2400; }
    else if (blk == 3) { src = fw1; N = 48000; }
    else if (blk == 4) { src = fw2; N = 10080; }
    else               { src = fw3; N = 840; }
    __shared__ float red[256];
    float partial = 0.0f;
    for (int i = tid; i < N; i += 256) partial += fabsf(src[i]);
    red[tid] = partial;
    __syncthreads();
    for (int s = 128; s > 0; s >>= 1) {
        if (tid < s) red[tid] += red[tid + s];
        __syncthreads();
    }
    if (tid == 0) wsf[8 + blk] = red[0] / (float)N;

    if (blk == 1) {
        for (int t = tid; t < 90; t += 256) {
            const float* wp = w1 + t * 5;
            wsu[OFF_WPK1 + 2*t] = sgn8(wp[0]) | (sgn8(wp[1])<<8) | (sgn8(wp[2])<<16) | (sgn8(wp[3])<<24);
            wsu[OFF_WPK1 + 2*t + 1] = sgn8(wp[4]) << 24;
        }
    } else if (blk == 2) {
        for (int t = tid; t < 480; t += 256) {
            const float* wp = w2 + t * 5;
            wsu[OFF_WPK2 + 2*t] = sgn8(wp[0]) | (sgn8(wp[1])<<8) | (sgn8(wp[2])<<16) | (sgn8(wp[3])<<24);
            wsu[OFF_WPK2 + 2*t + 1] = sgn8(wp[4]) << 24;
        }
    } else if (blk == 3) {
        for (int i = tid; i < 12000; i += 256) {
            int j = i / 100, k = i % 100;
            const float* wp = fw1 + j * 400 + k * 4;
            wsu[OFF_FQ1 + i] = sgn8(wp[0]) | (sgn8(wp[1])<<8) | (sgn8(wp[2])<<16) | (sgn8(wp[3])<<24);
        }
    } else if (blk == 4) {
        for (int i = tid; i < 2688; i += 256) {
            int j = i >> 5, k = i & 31;
            unsigned int u = 0;
            if (k < 30) {
                const float* wp = fw2 + j * 120 + k * 4;
                u = sgn8(wp[0]) | (sgn8(wp[1])<<8) | (sgn8(wp[2])<<16) | (sgn8(wp[3])<<24);
            }
            wsu[OFF_FQ2 + i] = u;
        }
    } else {
        for (int i = tid; i < 240; i += 256) {
            int j = i / 24, k = i % 24;
            unsigned int u = 0;
            if (k < 21) {
                const float* wp = fw3 + j * 84 + k * 4;
                u = sgn8(wp[0]) | (sgn8(wp[1])<<8) | (sgn8(wp[2])<<16) | (sgn8(wp[3])<<24);
            }
            wsu[OFF_FQ3 + i] = u;
        }
    }
}

// ---------------- input abs-max ----------------
__global__ __launch_bounds__(256) void absmax_kernel(const float4* __restrict__ x, int n4,
                                                     unsigned int* __restrict__ gkey) {
    float m = 0.0f;
    int stride = gridDim.x * 256;
    for (int i = blockIdx.x * 256 + threadIdx.x; i < n4; i += stride) {
        float4 v = x[i];
        m = fmaxf(m, fmaxf(fmaxf(fabsf(v.x), fabsf(v.y)), fmaxf(fabsf(v.z), fabsf(v.w))));
    }
    __shared__ float sm[4];
    m = waveMax(m);
    int tid = threadIdx.x;
    if ((tid & 63) == 0) sm[tid >> 6] = m;
    __syncthreads();
    if (tid == 0)
        atomicMax(gkey, fkey(fmaxf(fmaxf(sm[0], sm[1]), fmaxf(sm[2], sm[3]))));
}

// ---------------- quant1: fp32 input -> padded i8 codes [B][3][32][48] ----------------
// unit = one output u32; row = 12 u32 (8 data + 4 pad)
__global__ __launch_bounds__(256) void quant1_kernel(const float4* __restrict__ x,
                                                     float* __restrict__ wsf) {
    unsigned int* wsu = (unsigned int*)wsf;
    float s0 = fmaxf(fdec(wsu[0]) / 127.0f, EPSQ);
    unsigned int* qin = wsu + OFF_QIN;
    int stride = gridDim.x * 256;
    const int total = BATCH * 96 * 12;   // 18,874,368
    for (int unit = blockIdx.x * 256 + threadIdx.x; unit < total; unit += stride) {
        int row_id = unit / 12, w = unit % 12;
        unsigned int u = 0;
        if (w < 8) {
            float4 v = x[row_id * 8 + w];
            int q0 = (int)fminf(fmaxf(rintf(v.x / s0), -128.f), 127.f);
            int q1 = (int)fminf(fmaxf(rintf(v.y / s0), -128.f), 127.f);
            int q2 = (int)fminf(fmaxf(rintf(v.z / s0), -128.f), 127.f);
            int q3 = (int)fminf(fmaxf(rintf(v.w / s0), -128.f), 127.f);
            u = (q0 & 255) | ((q1 & 255) << 8) | ((q2 & 255) << 16) | ((unsigned)(q3 & 255) << 24);
        }
        qin[unit] = u;
    }
}

// ---------------- conv1: 6 img/block, copy-staged codes, dot4, i16 isum out ------
#define C1_ROWP 48
#define C1_CIS  1536
#define C1_IMGS 4608

template<int PH>
__device__ __forceinline__ void c1_phase(const unsigned char* ib, const unsigned int* wcp,
                                         int* ip, int& gmax, int& gmin) {
    int a0[14], a1[14];
    #pragma unroll
    for (int i = 0; i < 14; i++) { a0[i] = 0; a1[i] = 0; }
    #pragma unroll 1
    for (int ci = 0; ci < 3; ci++) {
        uint4 A[6]; unsigned int Bv[6];
        const unsigned char* cb = ib + ci * C1_CIS;
        #pragma unroll
        for (int r = 0; r < 6; r++) {
            const unsigned char* rb = cb + r * C1_ROWP;
            if (PH == 0) {
                A[r]  = *(const uint4*)(rb);
                Bv[r] = *(const unsigned int*)(rb + 16);
            } else {
                Bv[r] = *(const unsigned int*)(rb + 12);
                A[r]  = *(const uint4*)(rb + 16);
            }
        }
        const unsigned int* wkp = wcp + ci * 10;
        unsigned int wk0[5], wk4[5];
        #pragma unroll
        for (int ky = 0; ky < 5; ky++) { wk0[ky] = wkp[2*ky]; wk4[ky] = wkp[2*ky+1]; }
        #pragma unroll
        for (int r6 = 0; r6 < 6; r6++) {
            unsigned int wq[5];
            if (PH == 0) {
                wq[0] = A[r6].x; wq[1] = A[r6].y; wq[2] = A[r6].z; wq[3] = A[r6].w; wq[4] = Bv[r6];
            } else {
                wq[0] = __builtin_amdgcn_perm(A[r6].x, Bv[r6],  0x05040302u);
                wq[1] = __builtin_amdgcn_perm(A[r6].y, A[r6].x, 0x05040302u);
                wq[2] = __builtin_amdgcn_perm(A[r6].z, A[r6].y, 0x05040302u);
                wq[3] = __builtin_amdgcn_perm(A[r6].w, A[r6].z, 0x05040302u);
                wq[4] = __builtin_amdgcn_perm(A[r6].w, A[r6].w, 0x00000302u);
            }
            unsigned int up[15];
            #pragma unroll
            for (int i = 0; i < 15; i++) up[i] = u32at(wq, i >> 2, i & 3);
            if (r6 <= 4) {
                unsigned int w0 = wk0[r6], w4 = wk4[r6];
                #pragma unroll
                for (int i = 0; i < 14; i++) {
                    a0[i] = sdot4(up[i], w0, a0[i]);
                    a0[i] = sdot4(up[i+1], w4, a0[i]);
                }
            }
            if (r6 >= 1) {
                unsigned int w0 = wk0[r6-1], w4 = wk4[r6-1];
                #pragma unroll
                for (int i = 0; i < 14; i++) {
                    a1[i] = sdot4(up[i], w0, a1[i]);
                    a1[i] = sdot4(up[i+1], w4, a1[i]);
                }
            }
        }
    }
    #pragma unroll
    for (int i = 0; i < 14; i++) {
        gmax = max(gmax, max(a0[i], a1[i]));
        gmin = min(gmin, min(a0[i], a1[i]));
    }
    #pragma unroll
    for (int p = 0; p < 7; p++)
        ip[p] = max(max(a0[2*p], a0[2*p+1]), max(a1[2*p], a1[2*p+1]));
}

__global__ __launch_bounds__(256) void conv1_kernel(const float* __restrict__ b1,
                                                    float* __restrict__ wsf) {
    __shared__ __align__(16) unsigned char xq[6 * C1_IMGS];   // 27648 B
    __shared__ unsigned int wpk[180];
    __shared__ float bsm[6];
    unsigned int* wsu = (unsigned int*)wsf;
    int tid = threadIdx.x;
    int b0 = blockIdx.x * 6;
    int nimg = min(6, BATCH - b0);
    float s0 = fmaxf(fdec(wsu[0]) / 127.0f, EPSQ);
    float seff = s0 * wsf[9];

    // stage pre-quantized codes: plain aligned copy (L3-resident)
    {
        const uint4* src = (const uint4*)((const unsigned char*)(wsu + OFF_QIN) + (size_t)b0 * C1_IMGS);
        uint4* dst = (uint4*)xq;
        for (int i = tid; i < nimg * 288; i += 256) dst[i] = src[i];
    }
    for (int i = tid; i < 180; i += 256) wpk[i] = wsu[OFF_WPK1 + i];
    if (tid < 6) bsm[tid] = b1[tid];
    __syncthreads();

    unsigned int* isum1 = wsu + OFF_ISUM1;
    float vmax = -INFINITY, vnmax = -INFINITY;
    int ntask = nimg * 84;
    for (int t = tid; t < ntask; t += 256) {
        int img = t / 84, r = t % 84;
        int c = r / 14, py = r % 14;
        const unsigned char* ib = &xq[img * C1_IMGS + (2 * py) * C1_ROWP];
        const unsigned int* wcp = &wpk[c * 30];
        int ip0[7], ip1[7];
        int gmax = -2000000000, gmin = 2000000000;
        c1_phase<0>(ib, wcp, ip0, gmax, gmin);
        c1_phase<1>(ib, wcp, ip1, gmax, gmin);
        float bias = bsm[c];
        vmax  = fmaxf(vmax,  fmaf(seff, (float)gmax, bias));
        vnmax = fmaxf(vnmax, -fmaf(seff, (float)gmin, bias));
        // 14 pooled i16 isums, 28B contiguous per task, dense across lanes
        unsigned int* dst = isum1 + 588 * (size_t)(b0 + img) + 7 * (c * 14 + py);
        #pragma unroll
        for (int p = 0; p < 7; p++) {
            int lo = (p < 7) ? ((p & 1) ? ip1[0] : 0) : 0; (void)lo;
        }
        int v14[14];
        #pragma unroll
        for (int p = 0; p < 7; p++) { v14[p] = ip0[p]; v14[7 + p] = ip1[p]; }
        #pragma unroll
        for (int p = 0; p < 7; p++)
            dst[p] = (v14[2*p] & 0xFFFF) | ((unsigned)(v14[2*p+1] & 0xFFFF) << 16);
    }
    blockAtomicMax2(vmax, vnmax, wsu + 1, wsu + 2);
}

// ---------------- quant2: isum1 i16 -> conv2 codes [B][6][14][16] ----------------
__global__ __launch_bounds__(256) void quant2_kernel(const float* __restrict__ b1,
                                                     float* __restrict__ wsf) {
    unsigned int* wsu = (unsigned int*)wsf;
    float s1, s2;
    get_qrelu_scales(wsu, 1, s1, s2);
    float s0 = fmaxf(fdec(wsu[0]) / 127.0f, EPSQ);
    float seff = s0 * wsf[9];
    float bv[6];
    #pragma unroll
    for (int c = 0; c < 6; c++) bv[c] = b1[c];
    const short* isum1 = (const short*)(wsu + OFF_ISUM1);
    unsigned int* qc2 = wsu + OFF_QC2;
    int stride = gridDim.x * 256;
    const int total = BATCH * 84 * 4;   // 5,505,024 (row=4 u32)
    for (int unit = blockIdx.x * 256 + threadIdx.x; unit < total; unit += stride) {
        int row_id = unit >> 2, w = unit & 3;       // row_id = (b*6+ci)*14+row
        int bci = row_id / 14, row = row_id % 14;
        int ci = bci % 6;
        float bias = bv[ci];
        unsigned int u = 0;
        const short* sp = isum1 + (size_t)bci * 196 + row * 14;
        #pragma unroll
        for (int k = 0; k < 4; k++) {
            int col = w * 4 + k;
            int code = 0;
            if (col < 14) {
                float pre = fmaf(seff, (float)sp[col], bias);
                code = qrelu_code(pre, s1, s2);
            }
            u |= ((unsigned)(code & 255)) << (8 * k);
        }
        qc2[unit] = u;
    }
}

// ---------------- conv2: 6 img/block, copy-staged codes, dot4, i16 isum out ------
#define C2_ROWP 16
#define C2_CIS  224
#define C2_IMGS 1344

__global__ __launch_bounds__(256) void conv2_kernel(const float* __restrict__ b2,
                                                    float* __restrict__ wsf) {
    __shared__ __align__(16) unsigned char act[6 * C2_IMGS];  // 8064 B
    __shared__ unsigned int wpk[960];
    __shared__ float bsm[16];
    unsigned int* wsu = (unsigned int*)wsf;
    int tid = threadIdx.x;
    int b0 = blockIdx.x * 6;
    int nimg = min(6, BATCH - b0);
    float s1, s2;
    get_qrelu_scales(wsu, 1, s1, s2);
    float seff = s2 * wsf[10];

    {
        const uint4* src = (const uint4*)((const unsigned char*)(wsu + OFF_QC2) + (size_t)b0 * C2_IMGS);
        uint4* dst = (uint4*)act;
        for (int i = tid; i < nimg * 84; i += 256) dst[i] = src[i];
    }
    for (int i = tid; i < 960; i += 256) wpk[i] = wsu[OFF_WPK2 + i];
    if (tid < 16) bsm[tid] = b2[tid];
    __syncthreads();

    short* isum2 = (short*)(wsu + OFF_ISUM2);
    float vmax = -INFINITY, vnmax = -INFINITY;
    int ntask = nimg * 80;
    for (int t = tid; t < ntask; t += 256) {
        int img = t / 80, r = t % 80;
        int c = r / 5, py = r % 5;
        const unsigned char* ib = &act[img * C2_IMGS + (2 * py) * C2_ROWP];
        int a0[10], a1[10];
        #pragma unroll
        for (int i = 0; i < 10; i++) { a0[i] = 0; a1[i] = 0; }
        #pragma unroll 1
        for (int cig = 0; cig < 3; cig++) {
            uint4 R[2][6];
            #pragma unroll
            for (int g = 0; g < 2; g++)
                #pragma unroll
                for (int r6 = 0; r6 < 6; r6++)
                    R[g][r6] = *(const uint4*)(ib + (2*cig + g) * C2_CIS + r6 * C2_ROWP);
            #pragma unroll
            for (int g = 0; g < 2; g++) {
                int ci = 2*cig + g;
                const unsigned int* wkp = &wpk[(c * 6 + ci) * 10];
                unsigned int wk0[5], wk4[5];
                #pragma unroll
                for (int ky = 0; ky < 5; ky++) { wk0[ky] = wkp[2*ky]; wk4[ky] = wkp[2*ky+1]; }
                #pragma unroll
                for (int r6 = 0; r6 < 6; r6++) {
                    unsigned int wv[4] = { R[g][r6].x, R[g][r6].y, R[g][r6].z, R[g][r6].w };
                    unsigned int up[11];
                    #pragma unroll
                    for (int i = 0; i < 11; i++) up[i] = u32at(wv, i >> 2, i & 3);
                    if (r6 <= 4) {
                        unsigned int w0 = wk0[r6], w4 = wk4[r6];
                        #pragma unroll
                        for (int i = 0; i < 10; i++) {
                            a0[i] = sdot4(up[i], w0, a0[i]);
                            a0[i] = sdot4(up[i+1], w4, a0[i]);
                        }
                    }
                    if (r6 >= 1) {
                        unsigned int w0 = wk0[r6-1], w4 = wk4[r6-1];
                        #pragma unroll
                        for (int i = 0; i < 10; i++) {
                            a1[i] = sdot4(up[i], w0, a1[i]);
                            a1[i] = sdot4(up[i+1], w4, a1[i]);
                        }
                    }
                }
            }
        }
        int gmax = -2000000000, gmin = 2000000000;
        #pragma unroll
        for (int i = 0; i < 10; i++) {
            gmax = max(gmax, max(a0[i], a1[i]));
            gmin = min(gmin, min(a0[i], a1[i]));
        }
        float bias = bsm[c];
        vmax  = fmaxf(vmax,  fmaf(seff, (float)gmax, bias));
        vnmax = fmaxf(vnmax, -fmaf(seff, (float)gmin, bias));
        short* dst = isum2 + (size_t)(b0 + img) * 400 + c * 25 + py * 5;
        #pragma unroll
        for (int p = 0; p < 5; p++)
            dst[p] = (short)max(max(a0[2*p], a0[2*p+1]), max(a1[2*p], a1[2*p+1]));
    }
    blockAtomicMax2(vmax, vnmax, wsu + 3, wsu + 4);
}

// ---------------- quant3: isum2 i16 -> fc1 codes [B][100] u32 ----------------
__global__ __launch_bounds__(256) void quant3_kernel(const float* __restrict__ b2,
                                                     float* __restrict__ wsf) {
    unsigned int* wsu = (unsigned int*)wsf;
    float s1, s2;
    get_qrelu_scales(wsu, 3, s1, s2);
    float sp1, sp2;
    get_qrelu_scales(wsu, 1, sp1, sp2);
    float seff = sp2 * wsf[10];
    __shared__ float bv[16];
    if (threadIdx.x < 16) bv[threadIdx.x] = b2[threadIdx.x];
    __syncthreads();
    const short* isum2 = (const short*)(wsu + OFF_ISUM2);
    unsigned int* qc3 = wsu + OFF_QC3;
    int stride = gridDim.x * 256;
    const int total = BATCH * 100;   // 1,638,400
    for (int unit = blockIdx.x * 256 + threadIdx.x; unit < total; unit += stride) {
        int b = unit / 100, w = unit % 100;
        const short* sp = isum2 + (size_t)b * 400 + w * 4;
        unsigned int u = 0;
        #pragma unroll
        for (int k = 0; k < 4; k++) {
            int p = w * 4 + k;
            float pre = fmaf(seff, (float)sp[k], bv[p / 25]);
            int code = qrelu_code(pre, s1, s2);
            u |= ((unsigned)(code & 255)) << (8 * k);
        }
        qc3[unit] = u;
    }
}

// ---------------- fc1: codes [B,100] -> p3 fp32 [B,120], 8 rows/block ----------------
__global__ __launch_bounds__(128) void fc1_kernel(const float* __restrict__ fb1,
                                                  float* __restrict__ wsf) {
    __shared__ unsigned int xs[8][100];
    __shared__ __align__(16) float pb[960];
    unsigned int* wsu = (unsigned int*)wsf;
    float* p3 = wsf + OFF_P3;
    int tid = threadIdx.x;
    size_t row0 = (size_t)blockIdx.x * 8;
    float s1, s2;
    get_qrelu_scales(wsu, 3, s1, s2);
    float seff = s2 * wsf[11];
    {
        const uint4* src = (const uint4*)(wsu + OFF_QC3 + row0 * 100);
        uint4* dst = (uint4*)xs;
        for (int i = tid; i < 200; i += 128) dst[i] = src[i];
    }
    __syncthreads();
    float vmax = -INFINITY, vnmax = -INFINITY;
    if (tid < 120) {
        int j = tid;
        int acc[8];
        #pragma unroll
        for (int r = 0; r < 8; r++) acc[r] = 0;
        const uint4* wrow = (const uint4*)&wsu[OFF_FQ1 + j * 100];
        for (int kg = 0; kg < 25; kg++) {
            uint4 wv = wrow[kg];
            #pragma unroll
            for (int r = 0; r < 8; r++) {
                uint4 xv = *(const uint4*)&xs[r][kg * 4];
                acc[r] = sdot4(xv.x, wv.x, acc[r]);
                acc[r] = sdot4(xv.y, wv.y, acc[r]);
                acc[r] = sdot4(xv.z, wv.z, acc[r]);
                acc[r] = sdot4(xv.w, wv.w, acc[r]);
            }
        }
        float bias = fb1[j];
        #pragma unroll
        for (int r = 0; r < 8; r++) {
            float pv = fmaf(seff, (float)acc[r], bias);
            pb[r * 120 + j] = pv;
            vmax = fmaxf(vmax, pv); vnmax = fmaxf(vnmax, -pv);
        }
    }
    __syncthreads();
    {
        const float4* pb4 = (const float4*)pb;
        float4* d4 = (float4*)(p3 + row0 * 120);
        for (int i = tid; i < 240; i += 128) d4[i] = pb4[i];
    }
    block2AtomicMax2(vmax, vnmax, wsu + 5, wsu + 6);
}

// ---------------- fc2: [B,120]->[B,84], 8 rows/block ----------------
__global__ __launch_bounds__(128) void fc2_kernel(const float* __restrict__ fb2,
                                                  float* __restrict__ wsf) {
    __shared__ unsigned int xs[8][32];
    __shared__ __align__(16) float pb[672];
    unsigned int* wsu = (unsigned int*)wsf;
    const float* p3 = wsf + OFF_P3;
    float* p4 = wsf + OFF_P4;
    int tid = threadIdx.x;
    size_t row0 = (size_t)blockIdx.x * 8;
    float s1, s2;
    get_qrelu_scales(wsu, 5, s1, s2);
    float seff = s2 * wsf[12];
    const float4* src = (const float4*)(p3 + row0 * 120);
    for (int i = tid; i < 240; i += 128) {
        float4 v = src[i];
        int c0 = qrelu_code(v.x, s1, s2), c1 = qrelu_code(v.y, s1, s2);
        int c2 = qrelu_code(v.z, s1, s2), c3 = qrelu_code(v.w, s1, s2);
        xs[i / 30][i % 30] = c0 | (c1 << 8) | (c2 << 16) | ((unsigned)c3 << 24);
    }
    if (tid < 16) xs[tid >> 1][30 + (tid & 1)] = 0;
    __syncthreads();
    float vmax = -INFINITY, vnmax = -INFINITY;
    if (tid < 84) {
        int j = tid;
        int acc[8];
        #pragma unroll
        for (int r = 0; r < 8; r++) acc[r] = 0;
        const uint4* wrow = (const uint4*)&wsu[OFF_FQ2 + j * 32];
        #pragma unroll
        for (int kg = 0; kg < 8; kg++) {
            uint4 wv = wrow[kg];
            #pragma unroll
            for (int r = 0; r < 8; r++) {
                uint4 xv = *(const uint4*)&xs[r][kg * 4];
                acc[r] = sdot4(xv.x, wv.x, acc[r]);
                acc[r] = sdot4(xv.y, wv.y, acc[r]);
                acc[r] = sdot4(xv.z, wv.z, acc[r]);
                acc[r] = sdot4(xv.w, wv.w, acc[r]);
            }
        }
        float bias = fb2[j];
        #pragma unroll
        for (int r = 0; r < 8; r++) {
            float pv = fmaf(seff, (float)acc[r], bias);
            pb[r * 84 + j] = pv;
            vmax = fmaxf(vmax, pv); vnmax = fmaxf(vnmax, -pv);
        }
    }
    __syncthreads();
    {
        const float4* pb4 = (const float4*)pb;
        float4* d4 = (float4*)(p4 + row0 * 84);
        for (int i = tid; i < 168; i += 128) d4[i] = pb4[i];
    }
    block2AtomicMax2(vmax, vnmax, wsu + 7, wsu + 8);
}

// ---------------- fc3: [B,84]->[B,10] ----------------
__global__ __launch_bounds__(256) void fc3_kernel(const float* __restrict__ fb3,
                                                  float* __restrict__ out,
                                                  float* __restrict__ wsf) {
    __shared__ unsigned int wsm[240];
    __shared__ float bs[10];
    __shared__ __align__(16) float pb[2560];
    unsigned int* wsu = (unsigned int*)wsf;
    const float* p4 = wsf + OFF_P4;
    int tid = threadIdx.x;
    for (int i = tid; i < 240; i += 256) wsm[i] = wsu[OFF_FQ3 + i];
    if (tid < 10) bs[tid] = fb3[tid];
    __syncthreads();
    float s1, s2;
    get_qrelu_scales(wsu, 7, s1, s2);
    float seff = s2 * wsf[13];
    size_t row = (size_t)blockIdx.x * 256 + tid;
    unsigned int xr[24];
    const float4* src = (const float4*)(p4 + row * 84);
    #pragma unroll
    for (int k = 0; k < 21; k++) {
        float4 v = src[k];
        int c0 = qrelu_code(v.x, s1, s2), c1 = qrelu_code(v.y, s1, s2);
        int c2 = qrelu_code(v.z, s1, s2), c3 = qrelu_code(v.w, s1, s2);
        xr[k] = c0 | (c1 << 8) | (c2 << 16) | ((unsigned)c3 << 24);
    }
    xr[21] = 0; xr[22] = 0; xr[23] = 0;
    #pragma unroll
    for (int j = 0; j < 10; j++) {
        int acc = 0;
        #pragma unroll
        for (int k = 0; k < 24; k++) acc = sdot4(xr[k], wsm[j * 24 + k], acc);
        pb[tid * 10 + j] = fmaf(seff, (float)acc, bs[j]);
    }
    __syncthreads();
    {
        const float4* pb4 = (const float4*)pb;
        float4* d4 = (float4*)(out + (size_t)blockIdx.x * 2560);
        for (int i = tid; i < 640; i += 256) d4[i] = pb4[i];
    }
}

extern "C" void kernel_launch(void* const* d_in, const int* in_sizes, int n_in,
                              void* d_out, int out_size, void* d_ws, size_t ws_size,
                              hipStream_t stream) {
    const float* input = (const float*)d_in[0];
    const float* w1  = (const float*)d_in[1];
    const float* b1  = (const float*)d_in[2];
    const float* w2  = (const float*)d_in[3];
    const float* b2  = (const float*)d_in[4];
    const float* fw1 = (const float*)d_in[5];
    const float* fb1 = (const float*)d_in[6];
    const float* fw2 = (const float*)d_in[7];
    const float* fb2 = (const float*)d_in[8];
    const float* fw3 = (const float*)d_in[9];
    const float* fb3 = (const float*)d_in[10];
    float* ws  = (float*)d_ws;
    float* out = (float*)d_out;

    prep_kernel<<<6, 256, 0, stream>>>(w1, w2, fw1, fw2, fw3, ws);
    absmax_kernel<<<2048, 256, 0, stream>>>((const float4*)input,
                                            (int)((size_t)BATCH * 3072 / 4),
                                            (unsigned int*)ws);
    quant1_kernel<<<8192, 256, 0, stream>>>((const float4*)input, ws);
    conv1_kernel<<<(BATCH + 5) / 6, 256, 0, stream>>>(b1, ws);
    quant2_kernel<<<4096, 256, 0, stream>>>(b1, ws);
    conv2_kernel<<<(BATCH + 5) / 6, 256, 0, stream>>>(b2, ws);
    quant3_kernel<<<2048, 256, 0, stream>>>(b2, ws);
    fc1_kernel<<<BATCH / 8, 128, 0, stream>>>(fb1, ws);
    fc2_kernel<<<BATCH / 8, 128, 0, stream>>>(fb2, ws);
    fc3_kernel<<<BATCH / 256, 256, 0, stream>>>(fb3, out, ws);
}

// Round 11
// 524.387 us; speedup vs baseline: 1.8821x; 1.1095x over previous
//
#include <hip/hip_runtime.h>
#include <math.h>

#define BATCH 16384
#define EPSQ 1e-8f

// ---------------- ws layout (32-bit units) ----------------
// scal keys: [0] absmax_in, [1,2] conv1 max/negmax, [3,4] conv2, [5,6] fc1, [7,8] fc2
// floats: [9] s_w1 [10] s_w2 [11] s_w3 [12] s_w4 [13] s_w5
#define OFF_SCAL 0
#define OFF_WPK1 16        // 180 u32
#define OFF_WPK2 196       // 960 u32
#define OFF_FQ1  1156      // 12000 u32
#define OFF_FQ2  13156     // 2688 u32
#define OFF_FQ3  15844     // 240 u32
#define OFF_A    16384
// region A time-multiplexed:
#define OFF_QIN   OFF_A                 // [B][3][32slots][48] i8 (75.5MB) quant1->conv1
#define OFF_QC2   OFF_A                 // [B][6][16slots][16] i8 (25.2MB) quant2->conv2
#define OFF_ISUM2 (OFF_A + 6400000)     // [B][400] i16 conv2->quant3
#define OFF_QC3   (OFF_A + 10000000)    // [B][100] u32 quant3->fc1
#define OFF_P3    (OFF_A + 12000000)    // [B][120] f32 fc1->fc2
#define OFF_P4    (OFF_A + 14000000)    // [B][84]  f32 fc2->fc3
#define OFF_ISUM1 (OFF_A + 18874368)    // [B][1176] i16 (38.5MB) conv1->quant2

__device__ inline int sdot4(unsigned int a, unsigned int b, int c) {
    return __builtin_amdgcn_sdot4((int)a, (int)b, c, false);
}

__device__ inline unsigned int fkey(float f) {
    unsigned int u = __float_as_uint(f);
    return (u & 0x80000000u) ? ~u : (u | 0x80000000u);
}
__device__ inline float fdec(unsigned int k) {
    unsigned int u = (k & 0x80000000u) ? (k ^ 0x80000000u) : ~k;
    return __uint_as_float(u);
}
#define KEY_ZERO   0x80000000u
#define KEY_NEGINF 0x007FFFFFu

__device__ inline float waveMax(float v) {
    #pragma unroll
    for (int off = 32; off > 0; off >>= 1)
        v = fmaxf(v, __shfl_down(v, off, 64));
    return v;
}

__device__ inline void blockAtomicMax2(float vmax, float vnmax,
                                       unsigned int* gmax, unsigned int* gnmax) {
    __shared__ float sm[4], sn[4];
    float a = waveMax(vmax), b = waveMax(vnmax);
    int tid = threadIdx.x;
    if ((tid & 63) == 0) { sm[tid >> 6] = a; sn[tid >> 6] = b; }
    __syncthreads();
    if (tid == 0) {
        atomicMax(gmax, fkey(fmaxf(fmaxf(sm[0], sm[1]), fmaxf(sm[2], sm[3]))));
        atomicMax(gnmax, fkey(fmaxf(fmaxf(sn[0], sn[1]), fmaxf(sn[2], sn[3]))));
    }
}

__device__ inline float fq_elem(float x, float s) {
    float q = fminf(fmaxf(rintf(x / s), -128.0f), 127.0f);
    return q * s;
}
__device__ inline int qrelu_code(float x, float s1, float s2) {
    float q = fq_elem(x, s1);
    q = fmaxf(q, 0.0f);
    return (int)fminf(fmaxf(rintf(q / s2), -128.0f), 127.0f);
}
__device__ inline void get_qrelu_scales(const unsigned int* scalu, int slot,
                                        float& s1, float& s2) {
    float maxa = fdec(scalu[slot]), negm = fdec(scalu[slot + 1]);
    float absm = fmaxf(maxa, negm);
    s1 = fmaxf(absm / 127.0f, EPSQ);
    float qm = fminf(fmaxf(rintf(maxa / s1), -128.0f), 127.0f) * s1;
    s2 = fmaxf(fmaxf(qm, 0.0f) / 127.0f, EPSQ);
}

__device__ inline unsigned int sgn8(float w) { return (w >= 0.0f) ? 0x01u : 0xFFu; }

__device__ inline unsigned int u32at(const unsigned int* wv, int wi, int k) {
    return (k == 0) ? wv[wi]
        : __builtin_amdgcn_perm(wv[wi + 1], wv[wi], 0x03020100u + 0x01010101u * (unsigned)k);
}

// ---------------- prep ----------------
__global__ __launch_bounds__(256) void prep_kernel(const float* __restrict__ w1,
        const float* __restrict__ w2, const float* __restrict__ fw1,
        const float* __restrict__ fw2, const float* __restrict__ fw3,
        float* __restrict__ wsf) {
    int blk = blockIdx.x, tid = threadIdx.x;
    unsigned int* wsu = (unsigned int*)wsf;
    if (blk == 0) {
        if (tid == 0) wsu[0] = KEY_ZERO;
        else if (tid <= 8) wsu[tid] = KEY_NEGINF;
        return;
    }
    const float* src = nullptr; int N = 0;
    if (blk == 1)      { src = w1;  N = 450; }
    else if (blk == 2) { src = w2;  N = 2400; }
    else if (blk == 3) { src = fw1; N = 48000; }
    else if (blk == 4) { src = fw2; N = 10080; }
    else               { src = fw3; N = 840; }
    __shared__ float red[256];
    float partial = 0.0f;
    for (int i = tid; i < N; i += 256) partial += fabsf(src[i]);
    red[tid] = partial;
    __syncthreads();
    for (int s = 128; s > 0; s >>= 1) {
        if (tid < s) red[tid] += red[tid + s];
        __syncthreads();
    }
    if (tid == 0) wsf[8 + blk] = red[0] / (float)N;

    if (blk == 1) {
        for (int t = tid; t < 90; t += 256) {
            const float* wp = w1 + t * 5;
            wsu[OFF_WPK1 + 2*t] = sgn8(wp[0]) | (sgn8(wp[1])<<8) | (sgn8(wp[2])<<16) | (sgn8(wp[3])<<24);
            wsu[OFF_WPK1 + 2*t + 1] = sgn8(wp[4]) << 24;
        }
    } else if (blk == 2) {
        for (int t = tid; t < 480; t += 256) {
            const float* wp = w2 + t * 5;
            wsu[OFF_WPK2 + 2*t] = sgn8(wp[0]) | (sgn8(wp[1])<<8) | (sgn8(wp[2])<<16) | (sgn8(wp[3])<<24);
            wsu[OFF_WPK2 + 2*t + 1] = sgn8(wp[4]) << 24;
        }
    } else if (blk == 3) {
        for (int i = tid; i < 12000; i += 256) {
            int j = i / 100, k = i % 100;
            const float* wp = fw1 + j * 400 + k * 4;
            wsu[OFF_FQ1 + i] = sgn8(wp[0]) | (sgn8(wp[1])<<8) | (sgn8(wp[2])<<16) | (sgn8(wp[3])<<24);
        }
    } else if (blk == 4) {
        for (int i = tid; i < 2688; i += 256) {
            int j = i >> 5, k = i & 31;
            unsigned int u = 0;
            if (k < 30) {
                const float* wp = fw2 + j * 120 + k * 4;
                u = sgn8(wp[0]) | (sgn8(wp[1])<<8) | (sgn8(wp[2])<<16) | (sgn8(wp[3])<<24);
            }
            wsu[OFF_FQ2 + i] = u;
        }
    } else {
        for (int i = tid; i < 240; i += 256) {
            int j = i / 24, k = i % 24;
            unsigned int u = 0;
            if (k < 21) {
                const float* wp = fw3 + j * 84 + k * 4;
                u = sgn8(wp[0]) | (sgn8(wp[1])<<8) | (sgn8(wp[2])<<16) | (sgn8(wp[3])<<24);
            }
            wsu[OFF_FQ3 + i] = u;
        }
    }
}

// ---------------- input abs-max ----------------
__global__ __launch_bounds__(256) void absmax_kernel(const float4* __restrict__ x, int n4,
                                                     unsigned int* __restrict__ gkey) {
    float m = 0.0f;
    int stride = gridDim.x * 256;
    for (int i = blockIdx.x * 256 + threadIdx.x; i < n4; i += stride) {
        float4 v = x[i];
        m = fmaxf(m, fmaxf(fmaxf(fabsf(v.x), fabsf(v.y)), fmaxf(fabsf(v.z), fabsf(v.w))));
    }
    __shared__ float sm[4];
    m = waveMax(m);
    int tid = threadIdx.x;
    if ((tid & 63) == 0) sm[tid >> 6] = m;
    __syncthreads();
    if (tid == 0)
        atomicMax(gkey, fkey(fmaxf(fmaxf(sm[0], sm[1]), fmaxf(sm[2], sm[3]))));
}

// ---------------- quant1: fp32 -> i8 codes, ROW-INTERLEAVED [B][3][slot(32)][48] ----
// slot(row) = (row>>1) + ((row&1)<<4): even rows 0..15, odd rows 16..31
__global__ __launch_bounds__(256) void quant1_kernel(const float4* __restrict__ x,
                                                     float* __restrict__ wsf) {
    unsigned int* wsu = (unsigned int*)wsf;
    float s0 = fmaxf(fdec(wsu[0]) / 127.0f, EPSQ);
    unsigned int* qin = wsu + OFF_QIN;
    int stride = gridDim.x * 256;
    const int total = BATCH * 96 * 12;
    for (int unit = blockIdx.x * 256 + threadIdx.x; unit < total; unit += stride) {
        int row_id = unit / 12, w = unit % 12;   // row_id = (b*3+ci)*32 + row
        int plane = row_id >> 5, row = row_id & 31;
        int slot = (row >> 1) + ((row & 1) << 4);
        unsigned int u = 0;
        if (w < 8) {
            float4 v = x[row_id * 8 + w];
            int q0 = (int)fminf(fmaxf(rintf(v.x / s0), -128.f), 127.f);
            int q1 = (int)fminf(fmaxf(rintf(v.y / s0), -128.f), 127.f);
            int q2 = (int)fminf(fmaxf(rintf(v.z / s0), -128.f), 127.f);
            int q3 = (int)fminf(fmaxf(rintf(v.w / s0), -128.f), 127.f);
            u = (q0 & 255) | ((q1 & 255) << 8) | ((q2 & 255) << 16) | ((unsigned)(q3 & 255) << 24);
        }
        qin[(plane * 32 + slot) * 12 + w] = u;
    }
}

// ---------------- conv1: 6 img/block, interleaved rows, dot4, i16 isum out ------
#define C1_ROWP 48
#define C1_CIS  1536
#define C1_IMGS 4608

// ib = &xq[img*C1_IMGS + py*C1_ROWP]; conv row r (0..5) at slot off:
//   ((r&1)<<4 slots) + (r>>1) rows beyond py
template<int PH>
__device__ __forceinline__ void c1_phase(const unsigned char* ib, const unsigned int* wcp,
                                         int* ip, int& gmax, int& gmin) {
    int a0[14], a1[14];
    #pragma unroll
    for (int i = 0; i < 14; i++) { a0[i] = 0; a1[i] = 0; }
    #pragma unroll 1
    for (int ci = 0; ci < 3; ci++) {
        uint4 A[6]; unsigned int Bv[6];
        const unsigned char* cb = ib + ci * C1_CIS;
        #pragma unroll
        for (int r = 0; r < 6; r++) {
            const unsigned char* rb = cb + (((r & 1) << 4) + (r >> 1)) * C1_ROWP;
            if (PH == 0) {
                A[r]  = *(const uint4*)(rb);
                Bv[r] = *(const unsigned int*)(rb + 16);
            } else {
                Bv[r] = *(const unsigned int*)(rb + 12);
                A[r]  = *(const uint4*)(rb + 16);
            }
        }
        const unsigned int* wkp = wcp + ci * 10;
        unsigned int wk0[5], wk4[5];
        #pragma unroll
        for (int ky = 0; ky < 5; ky++) { wk0[ky] = wkp[2*ky]; wk4[ky] = wkp[2*ky+1]; }
        #pragma unroll
        for (int r6 = 0; r6 < 6; r6++) {
            unsigned int wq[5];
            if (PH == 0) {
                wq[0] = A[r6].x; wq[1] = A[r6].y; wq[2] = A[r6].z; wq[3] = A[r6].w; wq[4] = Bv[r6];
            } else {
                wq[0] = __builtin_amdgcn_perm(A[r6].x, Bv[r6],  0x05040302u);
                wq[1] = __builtin_amdgcn_perm(A[r6].y, A[r6].x, 0x05040302u);
                wq[2] = __builtin_amdgcn_perm(A[r6].z, A[r6].y, 0x05040302u);
                wq[3] = __builtin_amdgcn_perm(A[r6].w, A[r6].z, 0x05040302u);
                wq[4] = __builtin_amdgcn_perm(A[r6].w, A[r6].w, 0x00000302u);
            }
            unsigned int up[15];
            #pragma unroll
            for (int i = 0; i < 15; i++) up[i] = u32at(wq, i >> 2, i & 3);
            if (r6 <= 4) {
                unsigned int w0 = wk0[r6], w4 = wk4[r6];
                #pragma unroll
                for (int i = 0; i < 14; i++) {
                    a0[i] = sdot4(up[i], w0, a0[i]);
                    a0[i] = sdot4(up[i+1], w4, a0[i]);
                }
            }
            if (r6 >= 1) {
                unsigned int w0 = wk0[r6-1], w4 = wk4[r6-1];
                #pragma unroll
                for (int i = 0; i < 14; i++) {
                    a1[i] = sdot4(up[i], w0, a1[i]);
                    a1[i] = sdot4(up[i+1], w4, a1[i]);
                }
            }
        }
    }
    #pragma unroll
    for (int i = 0; i < 14; i++) {
        gmax = max(gmax, max(a0[i], a1[i]));
        gmin = min(gmin, min(a0[i], a1[i]));
    }
    #pragma unroll
    for (int p = 0; p < 7; p++)
        ip[p] = max(max(a0[2*p], a0[2*p+1]), max(a1[2*p], a1[2*p+1]));
}

__global__ __launch_bounds__(256) void conv1_kernel(const float* __restrict__ b1,
                                                    float* __restrict__ wsf) {
    __shared__ __align__(16) unsigned char xq[6 * C1_IMGS];
    __shared__ unsigned int wpk[180];
    __shared__ float bsm[6];
    unsigned int* wsu = (unsigned int*)wsf;
    int tid = threadIdx.x;
    int b0 = blockIdx.x * 6;
    int nimg = min(6, BATCH - b0);
    float s0 = fmaxf(fdec(wsu[0]) / 127.0f, EPSQ);
    float seff = s0 * wsf[9];

    {
        const uint4* src = (const uint4*)((const unsigned char*)(wsu + OFF_QIN) + (size_t)b0 * C1_IMGS);
        uint4* dst = (uint4*)xq;
        for (int i = tid; i < nimg * 288; i += 256) dst[i] = src[i];
    }
    for (int i = tid; i < 180; i += 256) wpk[i] = wsu[OFF_WPK1 + i];
    if (tid < 6) bsm[tid] = b1[tid];
    __syncthreads();

    unsigned int* isum1 = wsu + OFF_ISUM1;
    float vmax = -INFINITY, vnmax = -INFINITY;
    int ntask = nimg * 84;
    for (int t = tid; t < ntask; t += 256) {
        int img = t / 84, r = t % 84;
        int c = r / 14, py = r % 14;
        const unsigned char* ib = &xq[img * C1_IMGS + py * C1_ROWP];
        const unsigned int* wcp = &wpk[c * 30];
        int ip0[7], ip1[7];
        int gmax = -2000000000, gmin = 2000000000;
        c1_phase<0>(ib, wcp, ip0, gmax, gmin);
        c1_phase<1>(ib, wcp, ip1, gmax, gmin);
        float bias = bsm[c];
        vmax  = fmaxf(vmax,  fmaf(seff, (float)gmax, bias));
        vnmax = fmaxf(vnmax, -fmaf(seff, (float)gmin, bias));
        unsigned int* dst = isum1 + 588 * (size_t)(b0 + img) + 7 * (c * 14 + py);
        int v14[14];
        #pragma unroll
        for (int p = 0; p < 7; p++) { v14[p] = ip0[p]; v14[7 + p] = ip1[p]; }
        #pragma unroll
        for (int p = 0; p < 7; p++)
            dst[p] = (v14[2*p] & 0xFFFF) | ((unsigned)(v14[2*p+1] & 0xFFFF) << 16);
    }
    blockAtomicMax2(vmax, vnmax, wsu + 1, wsu + 2);
}

// ---------------- quant2: isum1 -> conv2 codes, interleaved [B][6][slot(16)][16] ----
// slot(row) = (row>>1) + ((row&1)<<3): even rows 0..6, odd rows 8..14
__global__ __launch_bounds__(256) void quant2_kernel(const float* __restrict__ b1,
                                                     float* __restrict__ wsf) {
    unsigned int* wsu = (unsigned int*)wsf;
    float s1, s2;
    get_qrelu_scales(wsu, 1, s1, s2);
    float s0 = fmaxf(fdec(wsu[0]) / 127.0f, EPSQ);
    float seff = s0 * wsf[9];
    float bv[6];
    #pragma unroll
    for (int c = 0; c < 6; c++) bv[c] = b1[c];
    const short* isum1 = (const short*)(wsu + OFF_ISUM1);
    unsigned int* qc2 = wsu + OFF_QC2;
    int stride = gridDim.x * 256;
    const int total = BATCH * 84 * 4;
    for (int unit = blockIdx.x * 256 + threadIdx.x; unit < total; unit += stride) {
        int row_id = unit >> 2, w = unit & 3;
        int bci = row_id / 14, row = row_id % 14;
        int ci = bci % 6;
        int slot = (row >> 1) + ((row & 1) << 3);
        float bias = bv[ci];
        unsigned int u = 0;
        const short* sp = isum1 + (size_t)bci * 196 + row * 14;
        #pragma unroll
        for (int k = 0; k < 4; k++) {
            int col = w * 4 + k;
            int code = 0;
            if (col < 14) {
                float pre = fmaf(seff, (float)sp[col], bias);
                code = qrelu_code(pre, s1, s2);
            }
            u |= ((unsigned)(code & 255)) << (8 * k);
        }
        qc2[((size_t)bci * 16 + slot) * 4 + w] = u;
    }
}

// ---------------- conv2: 6 img/block, interleaved rows, dot4, i16 isum out ------
#define C2_ROWP 16
#define C2_CIS  256
#define C2_IMGS 1536

__global__ __launch_bounds__(256) void conv2_kernel(const float* __restrict__ b2,
                                                    float* __restrict__ wsf) {
    __shared__ __align__(16) unsigned char act[6 * C2_IMGS];  // 9216 B
    __shared__ unsigned int wpk[960];
    __shared__ float bsm[16];
    unsigned int* wsu = (unsigned int*)wsf;
    int tid = threadIdx.x;
    int b0 = blockIdx.x * 6;
    int nimg = min(6, BATCH - b0);
    float s1, s2;
    get_qrelu_scales(wsu, 1, s1, s2);
    float seff = s2 * wsf[10];

    {
        const uint4* src = (const uint4*)((const unsigned char*)(wsu + OFF_QC2) + (size_t)b0 * C2_IMGS);
        uint4* dst = (uint4*)act;
        for (int i = tid; i < nimg * 96; i += 256) dst[i] = src[i];
    }
    for (int i = tid; i < 960; i += 256) wpk[i] = wsu[OFF_WPK2 + i];
    if (tid < 16) bsm[tid] = b2[tid];
    __syncthreads();

    short* isum2 = (short*)(wsu + OFF_ISUM2);
    float vmax = -INFINITY, vnmax = -INFINITY;
    int ntask = nimg * 80;
    for (int t = tid; t < ntask; t += 256) {
        int img = t / 80, r = t % 80;
        int c = r / 5, py = r % 5;
        const unsigned char* ib = &act[img * C2_IMGS + py * C2_ROWP];
        int a0[10], a1[10];
        #pragma unroll
        for (int i = 0; i < 10; i++) { a0[i] = 0; a1[i] = 0; }
        #pragma unroll 1
        for (int cig = 0; cig < 3; cig++) {
            uint4 R[2][6];
            #pragma unroll
            for (int g = 0; g < 2; g++)
                #pragma unroll
                for (int r6 = 0; r6 < 6; r6++)
                    R[g][r6] = *(const uint4*)(ib + (2*cig + g) * C2_CIS
                                + (((r6 & 1) << 3) + (r6 >> 1)) * C2_ROWP);
            #pragma unroll
            for (int g = 0; g < 2; g++) {
                int ci = 2*cig + g;
                const unsigned int* wkp = &wpk[(c * 6 + ci) * 10];
                unsigned int wk0[5], wk4[5];
                #pragma unroll
                for (int ky = 0; ky < 5; ky++) { wk0[ky] = wkp[2*ky]; wk4[ky] = wkp[2*ky+1]; }
                #pragma unroll
                for (int r6 = 0; r6 < 6; r6++) {
                    unsigned int wv[4] = { R[g][r6].x, R[g][r6].y, R[g][r6].z, R[g][r6].w };
                    unsigned int up[11];
                    #pragma unroll
                    for (int i = 0; i < 11; i++) up[i] = u32at(wv, i >> 2, i & 3);
                    if (r6 <= 4) {
                        unsigned int w0 = wk0[r6], w4 = wk4[r6];
                        #pragma unroll
                        for (int i = 0; i < 10; i++) {
                            a0[i] = sdot4(up[i], w0, a0[i]);
                            a0[i] = sdot4(up[i+1], w4, a0[i]);
                        }
                    }
                    if (r6 >= 1) {
                        unsigned int w0 = wk0[r6-1], w4 = wk4[r6-1];
                        #pragma unroll
                        for (int i = 0; i < 10; i++) {
                            a1[i] = sdot4(up[i], w0, a1[i]);
                            a1[i] = sdot4(up[i+1], w4, a1[i]);
                        }
                    }
                }
            }
        }
        int gmax = -2000000000, gmin = 2000000000;
        #pragma unroll
        for (int i = 0; i < 10; i++) {
            gmax = max(gmax, max(a0[i], a1[i]));
            gmin = min(gmin, min(a0[i], a1[i]));
        }
        float bias = bsm[c];
        vmax  = fmaxf(vmax,  fmaf(seff, (float)gmax, bias));
        vnmax = fmaxf(vnmax, -fmaf(seff, (float)gmin, bias));
        short* dst = isum2 + (size_t)(b0 + img) * 400 + c * 25 + py * 5;
        #pragma unroll
        for (int p = 0; p < 5; p++)
            dst[p] = (short)max(max(a0[2*p], a0[2*p+1]), max(a1[2*p], a1[2*p+1]));
    }
    blockAtomicMax2(vmax, vnmax, wsu + 3, wsu + 4);
}

// ---------------- quant3: isum2 i16 -> fc1 codes [B][100] u32 ----------------
__global__ __launch_bounds__(256) void quant3_kernel(const float* __restrict__ b2,
                                                     float* __restrict__ wsf) {
    unsigned int* wsu = (unsigned int*)wsf;
    float s1, s2;
    get_qrelu_scales(wsu, 3, s1, s2);
    float sp1, sp2;
    get_qrelu_scales(wsu, 1, sp1, sp2);
    float seff = sp2 * wsf[10];
    __shared__ float bv[16];
    if (threadIdx.x < 16) bv[threadIdx.x] = b2[threadIdx.x];
    __syncthreads();
    const short* isum2 = (const short*)(wsu + OFF_ISUM2);
    unsigned int* qc3 = wsu + OFF_QC3;
    int stride = gridDim.x * 256;
    const int total = BATCH * 100;
    for (int unit = blockIdx.x * 256 + threadIdx.x; unit < total; unit += stride) {
        int b = unit / 100, w = unit % 100;
        const short* sp = isum2 + (size_t)b * 400 + w * 4;
        unsigned int u = 0;
        #pragma unroll
        for (int k = 0; k < 4; k++) {
            int p = w * 4 + k;
            float pre = fmaf(seff, (float)sp[k], bv[p / 25]);
            int code = qrelu_code(pre, s1, s2);
            u |= ((unsigned)(code & 255)) << (8 * k);
        }
        qc3[unit] = u;
    }
}

// ---------------- fc1: 256 threads, 16 rows/block (1024 blocks) ----------------
__global__ __launch_bounds__(256) void fc1_kernel(const float* __restrict__ fb1,
                                                  float* __restrict__ wsf) {
    __shared__ unsigned int xs[16][100];
    __shared__ __align__(16) float pb[1920];
    unsigned int* wsu = (unsigned int*)wsf;
    float* p3 = wsf + OFF_P3;
    int tid = threadIdx.x;
    size_t row0 = (size_t)blockIdx.x * 16;
    float s1, s2;
    get_qrelu_scales(wsu, 3, s1, s2);
    float seff = s2 * wsf[11];
    {
        const uint4* src = (const uint4*)(wsu + OFF_QC3 + row0 * 100);
        uint4* dst = (uint4*)xs;
        for (int i = tid; i < 400; i += 256) dst[i] = src[i];
    }
    __syncthreads();
    float vmax = -INFINITY, vnmax = -INFINITY;
    if (tid < 240) {
        int g = tid / 120, j = tid % 120;
        int acc[8];
        #pragma unroll
        for (int r = 0; r < 8; r++) acc[r] = 0;
        const uint4* wrow = (const uint4*)&wsu[OFF_FQ1 + j * 100];
        for (int kg = 0; kg < 25; kg++) {
            uint4 wv = wrow[kg];
            #pragma unroll
            for (int r = 0; r < 8; r++) {
                uint4 xv = *(const uint4*)&xs[g * 8 + r][kg * 4];
                acc[r] = sdot4(xv.x, wv.x, acc[r]);
                acc[r] = sdot4(xv.y, wv.y, acc[r]);
                acc[r] = sdot4(xv.z, wv.z, acc[r]);
                acc[r] = sdot4(xv.w, wv.w, acc[r]);
            }
        }
        float bias = fb1[j];
        #pragma unroll
        for (int r = 0; r < 8; r++) {
            float pv = fmaf(seff, (float)acc[r], bias);
            pb[(g * 8 + r) * 120 + j] = pv;
            vmax = fmaxf(vmax, pv); vnmax = fmaxf(vnmax, -pv);
        }
    }
    __syncthreads();
    {
        const float4* pb4 = (const float4*)pb;
        float4* d4 = (float4*)(p3 + row0 * 120);
        for (int i = tid; i < 480; i += 256) d4[i] = pb4[i];
    }
    blockAtomicMax2(vmax, vnmax, wsu + 5, wsu + 6);
}

// ---------------- fc2: 256 threads, 24 rows/block (683 blocks) ----------------
__global__ __launch_bounds__(256) void fc2_kernel(const float* __restrict__ fb2,
                                                  float* __restrict__ wsf) {
    __shared__ unsigned int xs[24][32];
    __shared__ __align__(16) float pb[2016];
    unsigned int* wsu = (unsigned int*)wsf;
    const float* p3 = wsf + OFF_P3;
    float* p4 = wsf + OFF_P4;
    int tid = threadIdx.x;
    size_t row0 = (size_t)blockIdx.x * 24;
    int nrow = min(24, (int)(BATCH - row0));
    float s1, s2;
    get_qrelu_scales(wsu, 5, s1, s2);
    float seff = s2 * wsf[12];
    const float4* src = (const float4*)(p3 + row0 * 120);
    for (int i = tid; i < nrow * 30; i += 256) {
        float4 v = src[i];
        int c0 = qrelu_code(v.x, s1, s2), c1 = qrelu_code(v.y, s1, s2);
        int c2 = qrelu_code(v.z, s1, s2), c3 = qrelu_code(v.w, s1, s2);
        xs[i / 30][i % 30] = c0 | (c1 << 8) | (c2 << 16) | ((unsigned)c3 << 24);
    }
    if (tid < 24) { xs[tid][30] = 0; xs[tid][31] = 0; }
    __syncthreads();
    float vmax = -INFINITY, vnmax = -INFINITY;
    if (tid < 252) {
        int g = tid / 84, j = tid % 84;
        int acc[8];
        #pragma unroll
        for (int r = 0; r < 8; r++) acc[r] = 0;
        const uint4* wrow = (const uint4*)&wsu[OFF_FQ2 + j * 32];
        #pragma unroll
        for (int kg = 0; kg < 8; kg++) {
            uint4 wv = wrow[kg];
            #pragma unroll
            for (int r = 0; r < 8; r++) {
                uint4 xv = *(const uint4*)&xs[g * 8 + r][kg * 4];
                acc[r] = sdot4(xv.x, wv.x, acc[r]);
                acc[r] = sdot4(xv.y, wv.y, acc[r]);
                acc[r] = sdot4(xv.z, wv.z, acc[r]);
                acc[r] = sdot4(xv.w, wv.w, acc[r]);
            }
        }
        float bias = fb2[j];
        #pragma unroll
        for (int r = 0; r < 8; r++) {
            int lr = g * 8 + r;
            if (lr < nrow) {
                float pv = fmaf(seff, (float)acc[r], bias);
                pb[lr * 84 + j] = pv;
                vmax = fmaxf(vmax, pv); vnmax = fmaxf(vnmax, -pv);
            }
        }
    }
    __syncthreads();
    {
        const float4* pb4 = (const float4*)pb;
        float4* d4 = (float4*)(p4 + row0 * 84);
        for (int i = tid; i < nrow * 21; i += 256) d4[i] = pb4[i];
    }
    blockAtomicMax2(vmax, vnmax, wsu + 7, wsu + 8);
}

// ---------------- fc3: [B,84]->[B,10] ----------------
__global__ __launch_bounds__(256) void fc3_kernel(const float* __restrict__ fb3,
                                                  float* __restrict__ out,
                                                  float* __restrict__ wsf) {
    __shared__ unsigned int wsm[240];
    __shared__ float bs[10];
    __shared__ __align__(16) float pb[2560];
    unsigned int* wsu = (unsigned int*)wsf;
    const float* p4 = wsf + OFF_P4;
    int tid = threadIdx.x;
    for (int i = tid; i < 240; i += 256) wsm[i] = wsu[OFF_FQ3 + i];
    if (tid < 10) bs[tid] = fb3[tid];
    __syncthreads();
    float s1, s2;
    get_qrelu_scales(wsu, 7, s1, s2);
    float seff = s2 * wsf[13];
    size_t row = (size_t)blockIdx.x * 256 + tid;
    unsigned int xr[24];
    const float4* src = (const float4*)(p4 + row * 84);
    #pragma unroll
    for (int k = 0; k < 21; k++) {
        float4 v = src[k];
        int c0 = qrelu_code(v.x, s1, s2), c1 = qrelu_code(v.y, s1, s2);
        int c2 = qrelu_code(v.z, s1, s2), c3 = qrelu_code(v.w, s1, s2);
        xr[k] = c0 | (c1 << 8) | (c2 << 16) | ((unsigned)c3 << 24);
    }
    xr[21] = 0; xr[22] = 0; xr[23] = 0;
    #pragma unroll
    for (int j = 0; j < 10; j++) {
        int acc = 0;
        #pragma unroll
        for (int k = 0; k < 24; k++) acc = sdot4(xr[k], wsm[j * 24 + k], acc);
        pb[tid * 10 + j] = fmaf(seff, (float)acc, bs[j]);
    }
    __syncthreads();
    {
        const float4* pb4 = (const float4*)pb;
        float4* d4 = (float4*)(out + (size_t)blockIdx.x * 2560);
        for (int i = tid; i < 640; i += 256) d4[i] = pb4[i];
    }
}

extern "C" void kernel_launch(void* const* d_in, const int* in_sizes, int n_in,
                              void* d_out, int out_size, void* d_ws, size_t ws_size,
                              hipStream_t stream) {
    const float* input = (const float*)d_in[0];
    const float* w1  = (const float*)d_in[1];
    const float* b1  = (const float*)d_in[2];
    const float* w2  = (const float*)d_in[3];
    const float* b2  = (const float*)d_in[4];
    const float* fw1 = (const float*)d_in[5];
    const float* fb1 = (const float*)d_in[6];
    const float* fw2 = (const float*)d_in[7];
    const float* fb2 = (const float*)d_in[8];
    const float* fw3 = (const float*)d_in[9];
    const float* fb3 = (const float*)d_in[10];
    float* ws  = (float*)d_ws;
    float* out = (float*)d_out;

    prep_kernel<<<6, 256, 0, stream>>>(w1, w2, fw1, fw2, fw3, ws);
    absmax_kernel<<<2048, 256, 0, stream>>>((const float4*)input,
                                            (int)((size_t)BATCH * 3072 / 4),
                                            (unsigned int*)ws);
    quant1_kernel<<<8192, 256, 0, stream>>>((const float4*)input, ws);
    conv1_kernel<<<(BATCH + 5) / 6, 256, 0, stream>>>(b1, ws);
    quant2_kernel<<<4096, 256, 0, stream>>>(b1, ws);
    conv2_kernel<<<(BATCH + 5) / 6, 256, 0, stream>>>(b2, ws);
    quant3_kernel<<<2048, 256, 0, stream>>>(b2, ws);
    fc1_kernel<<<BATCH / 16, 256, 0, stream>>>(fb1, ws);
    fc2_kernel<<<(BATCH + 23) / 24, 256, 0, stream>>>(fb2, ws);
    fc3_kernel<<<BATCH / 256, 256, 0, stream>>>(fb3, out, ws);
}

// Round 12
// 473.954 us; speedup vs baseline: 2.0824x; 1.1064x over previous
//
#include <hip/hip_runtime.h>
#include <math.h>

#define BATCH 16384
#define EPSQ 1e-8f

// ---------------- ws layout (32-bit units) ----------------
// scal keys: [0] absmax_in, [1,2] conv1 max/negmax, [3,4] conv2, [5,6] fc1, [7,8] fc2
// floats: [9] s_w1 [10] s_w2 [11] s_w3 [12] s_w4 [13] s_w5
#define OFF_SCAL 0
#define OFF_WPK1 16        // 180 u32
#define OFF_WPK2 196       // 960 u32
#define OFF_FQ1  1156      // 12000 u32
#define OFF_FQ2  13156     // 2688 u32
#define OFF_FQ3  15844     // 240 u32
#define OFF_A    16384
// region A time-multiplexed:
#define OFF_QIN   OFF_A                 // [B][3][32slots][48] i8 (75.5MB) quant1->conv1
#define OFF_QC2   OFF_A                 // [B][6][16slots][16] i8 (25.2MB) quant2->conv2
#define OFF_ISUM2 (OFF_A + 6400000)     // [B][400] i16 conv2->quant3
#define OFF_QC3   (OFF_A + 10000000)    // [B][100] u32 quant3->fc1
#define OFF_P3    (OFF_A + 12000000)    // [B][120] f32 fc1->fc2
#define OFF_P4    (OFF_A + 14000000)    // [B][84]  f32 fc2->fc3
#define OFF_ISUM1 (OFF_A + 18874368)    // [B][1176] i16 (38.5MB) conv1->quant2

__device__ inline int sdot4(unsigned int a, unsigned int b, int c) {
    return __builtin_amdgcn_sdot4((int)a, (int)b, c, false);
}

__device__ inline unsigned int fkey(float f) {
    unsigned int u = __float_as_uint(f);
    return (u & 0x80000000u) ? ~u : (u | 0x80000000u);
}
__device__ inline float fdec(unsigned int k) {
    unsigned int u = (k & 0x80000000u) ? (k ^ 0x80000000u) : ~k;
    return __uint_as_float(u);
}
#define KEY_ZERO   0x80000000u
#define KEY_NEGINF 0x007FFFFFu

__device__ inline float waveMax(float v) {
    #pragma unroll
    for (int off = 32; off > 0; off >>= 1)
        v = fmaxf(v, __shfl_down(v, off, 64));
    return v;
}

__device__ inline void blockAtomicMax2(float vmax, float vnmax,
                                       unsigned int* gmax, unsigned int* gnmax) {
    __shared__ float sm[4], sn[4];
    float a = waveMax(vmax), b = waveMax(vnmax);
    int tid = threadIdx.x;
    if ((tid & 63) == 0) { sm[tid >> 6] = a; sn[tid >> 6] = b; }
    __syncthreads();
    if (tid == 0) {
        atomicMax(gmax, fkey(fmaxf(fmaxf(sm[0], sm[1]), fmaxf(sm[2], sm[3]))));
        atomicMax(gnmax, fkey(fmaxf(fmaxf(sn[0], sn[1]), fmaxf(sn[2], sn[3]))));
    }
}

__device__ inline float fq_elem(float x, float s) {
    float q = fminf(fmaxf(rintf(x / s), -128.0f), 127.0f);
    return q * s;
}
__device__ inline int qrelu_code(float x, float s1, float s2) {
    float q = fq_elem(x, s1);
    q = fmaxf(q, 0.0f);
    return (int)fminf(fmaxf(rintf(q / s2), -128.0f), 127.0f);
}
__device__ inline void get_qrelu_scales(const unsigned int* scalu, int slot,
                                        float& s1, float& s2) {
    float maxa = fdec(scalu[slot]), negm = fdec(scalu[slot + 1]);
    float absm = fmaxf(maxa, negm);
    s1 = fmaxf(absm / 127.0f, EPSQ);
    float qm = fminf(fmaxf(rintf(maxa / s1), -128.0f), 127.0f) * s1;
    s2 = fmaxf(fmaxf(qm, 0.0f) / 127.0f, EPSQ);
}

__device__ inline unsigned int sgn8(float w) { return (w >= 0.0f) ? 0x01u : 0xFFu; }

__device__ inline unsigned int u32at(const unsigned int* wv, int wi, int k) {
    return (k == 0) ? wv[wi]
        : __builtin_amdgcn_perm(wv[wi + 1], wv[wi], 0x03020100u + 0x01010101u * (unsigned)k);
}

// ---------------- prep ----------------
__global__ __launch_bounds__(256) void prep_kernel(const float* __restrict__ w1,
        const float* __restrict__ w2, const float* __restrict__ fw1,
        const float* __restrict__ fw2, const float* __restrict__ fw3,
        float* __restrict__ wsf) {
    int blk = blockIdx.x, tid = threadIdx.x;
    unsigned int* wsu = (unsigned int*)wsf;
    if (blk == 0) {
        if (tid == 0) wsu[0] = KEY_ZERO;
        else if (tid <= 8) wsu[tid] = KEY_NEGINF;
        return;
    }
    const float* src = nullptr; int N = 0;
    if (blk == 1)      { src = w1;  N = 450; }
    else if (blk == 2) { src = w2;  N = 2400; }
    else if (blk == 3) { src = fw1; N = 48000; }
    else if (blk == 4) { src = fw2; N = 10080; }
    else               { src = fw3; N = 840; }
    __shared__ float red[256];
    float partial = 0.0f;
    for (int i = tid; i < N; i += 256) partial += fabsf(src[i]);
    red[tid] = partial;
    __syncthreads();
    for (int s = 128; s > 0; s >>= 1) {
        if (tid < s) red[tid] += red[tid + s];
        __syncthreads();
    }
    if (tid == 0) wsf[8 + blk] = red[0] / (float)N;

    if (blk == 1) {
        for (int t = tid; t < 90; t += 256) {
            const float* wp = w1 + t * 5;
            wsu[OFF_WPK1 + 2*t] = sgn8(wp[0]) | (sgn8(wp[1])<<8) | (sgn8(wp[2])<<16) | (sgn8(wp[3])<<24);
            wsu[OFF_WPK1 + 2*t + 1] = sgn8(wp[4]) << 24;
        }
    } else if (blk == 2) {
        for (int t = tid; t < 480; t += 256) {
            const float* wp = w2 + t * 5;
            wsu[OFF_WPK2 + 2*t] = sgn8(wp[0]) | (sgn8(wp[1])<<8) | (sgn8(wp[2])<<16) | (sgn8(wp[3])<<24);
            wsu[OFF_WPK2 + 2*t + 1] = sgn8(wp[4]) << 24;
        }
    } else if (blk == 3) {
        for (int i = tid; i < 12000; i += 256) {
            int j = i / 100, k = i % 100;
            const float* wp = fw1 + j * 400 + k * 4;
            wsu[OFF_FQ1 + i] = sgn8(wp[0]) | (sgn8(wp[1])<<8) | (sgn8(wp[2])<<16) | (sgn8(wp[3])<<24);
        }
    } else if (blk == 4) {
        for (int i = tid; i < 2688; i += 256) {
            int j = i >> 5, k = i & 31;
            unsigned int u = 0;
            if (k < 30) {
                const float* wp = fw2 + j * 120 + k * 4;
                u = sgn8(wp[0]) | (sgn8(wp[1])<<8) | (sgn8(wp[2])<<16) | (sgn8(wp[3])<<24);
            }
            wsu[OFF_FQ2 + i] = u;
        }
    } else {
        for (int i = tid; i < 240; i += 256) {
            int j = i / 24, k = i % 24;
            unsigned int u = 0;
            if (k < 21) {
                const float* wp = fw3 + j * 84 + k * 4;
                u = sgn8(wp[0]) | (sgn8(wp[1])<<8) | (sgn8(wp[2])<<16) | (sgn8(wp[3])<<24);
            }
            wsu[OFF_FQ3 + i] = u;
        }
    }
}

// ---------------- input abs-max ----------------
__global__ __launch_bounds__(256) void absmax_kernel(const float4* __restrict__ x, int n4,
                                                     unsigned int* __restrict__ gkey) {
    float m = 0.0f;
    int stride = gridDim.x * 256;
    for (int i = blockIdx.x * 256 + threadIdx.x; i < n4; i += stride) {
        float4 v = x[i];
        m = fmaxf(m, fmaxf(fmaxf(fabsf(v.x), fabsf(v.y)), fmaxf(fabsf(v.z), fabsf(v.w))));
    }
    __shared__ float sm[4];
    m = waveMax(m);
    int tid = threadIdx.x;
    if ((tid & 63) == 0) sm[tid >> 6] = m;
    __syncthreads();
    if (tid == 0)
        atomicMax(gkey, fkey(fmaxf(fmaxf(sm[0], sm[1]), fmaxf(sm[2], sm[3]))));
}

// ---------------- quant1: fp32 -> i8 codes, row-interleaved [B][3][slot(32)][48] ----
__global__ __launch_bounds__(256) void quant1_kernel(const float4* __restrict__ x,
                                                     float* __restrict__ wsf) {
    unsigned int* wsu = (unsigned int*)wsf;
    float s0 = fmaxf(fdec(wsu[0]) / 127.0f, EPSQ);
    unsigned int* qin = wsu + OFF_QIN;
    int stride = gridDim.x * 256;
    const int total = BATCH * 96 * 12;
    for (int unit = blockIdx.x * 256 + threadIdx.x; unit < total; unit += stride) {
        int row_id = unit / 12, w = unit % 12;
        int plane = row_id >> 5, row = row_id & 31;
        int slot = (row >> 1) + ((row & 1) << 4);
        unsigned int u = 0;
        if (w < 8) {
            float4 v = x[row_id * 8 + w];
            int q0 = (int)fminf(fmaxf(rintf(v.x / s0), -128.f), 127.f);
            int q1 = (int)fminf(fmaxf(rintf(v.y / s0), -128.f), 127.f);
            int q2 = (int)fminf(fmaxf(rintf(v.z / s0), -128.f), 127.f);
            int q3 = (int)fminf(fmaxf(rintf(v.w / s0), -128.f), 127.f);
            u = (q0 & 255) | ((q1 & 255) << 8) | ((q2 & 255) << 16) | ((unsigned)(q3 & 255) << 24);
        }
        qin[(plane * 32 + slot) * 12 + w] = u;
    }
}

// ---------------- conv1: 8 img/block, interleaved rows, dot4, i16 isum out ------
#define C1_ROWP 48
#define C1_CIS  1536
#define C1_IMGS 4608
#define C1_NIMG 8

template<int PH>
__device__ __forceinline__ void c1_phase(const unsigned char* ib, const unsigned int* wcp,
                                         int* ip, int& gmax, int& gmin) {
    int a0[14], a1[14];
    #pragma unroll
    for (int i = 0; i < 14; i++) { a0[i] = 0; a1[i] = 0; }
    #pragma unroll 1
    for (int ci = 0; ci < 3; ci++) {
        uint4 A[6]; unsigned int Bv[6];
        const unsigned char* cb = ib + ci * C1_CIS;
        #pragma unroll
        for (int r = 0; r < 6; r++) {
            const unsigned char* rb = cb + (((r & 1) << 4) + (r >> 1)) * C1_ROWP;
            if (PH == 0) {
                A[r]  = *(const uint4*)(rb);
                Bv[r] = *(const unsigned int*)(rb + 16);
            } else {
                Bv[r] = *(const unsigned int*)(rb + 12);
                A[r]  = *(const uint4*)(rb + 16);
            }
        }
        const unsigned int* wkp = wcp + ci * 10;
        unsigned int wk0[5], wk4[5];
        #pragma unroll
        for (int ky = 0; ky < 5; ky++) { wk0[ky] = wkp[2*ky]; wk4[ky] = wkp[2*ky+1]; }
        #pragma unroll
        for (int r6 = 0; r6 < 6; r6++) {
            unsigned int wq[5];
            if (PH == 0) {
                wq[0] = A[r6].x; wq[1] = A[r6].y; wq[2] = A[r6].z; wq[3] = A[r6].w; wq[4] = Bv[r6];
            } else {
                wq[0] = __builtin_amdgcn_perm(A[r6].x, Bv[r6],  0x05040302u);
                wq[1] = __builtin_amdgcn_perm(A[r6].y, A[r6].x, 0x05040302u);
                wq[2] = __builtin_amdgcn_perm(A[r6].z, A[r6].y, 0x05040302u);
                wq[3] = __builtin_amdgcn_perm(A[r6].w, A[r6].z, 0x05040302u);
                wq[4] = __builtin_amdgcn_perm(A[r6].w, A[r6].w, 0x00000302u);
            }
            unsigned int up[15];
            #pragma unroll
            for (int i = 0; i < 15; i++) up[i] = u32at(wq, i >> 2, i & 3);
            if (r6 <= 4) {
                unsigned int w0 = wk0[r6], w4 = wk4[r6];
                #pragma unroll
                for (int i = 0; i < 14; i++) {
                    a0[i] = sdot4(up[i], w0, a0[i]);
                    a0[i] = sdot4(up[i+1], w4, a0[i]);
                }
            }
            if (r6 >= 1) {
                unsigned int w0 = wk0[r6-1], w4 = wk4[r6-1];
                #pragma unroll
                for (int i = 0; i < 14; i++) {
                    a1[i] = sdot4(up[i], w0, a1[i]);
                    a1[i] = sdot4(up[i+1], w4, a1[i]);
                }
            }
        }
    }
    #pragma unroll
    for (int i = 0; i < 14; i++) {
        gmax = max(gmax, max(a0[i], a1[i]));
        gmin = min(gmin, min(a0[i], a1[i]));
    }
    #pragma unroll
    for (int p = 0; p < 7; p++)
        ip[p] = max(max(a0[2*p], a0[2*p+1]), max(a1[2*p], a1[2*p+1]));
}

__global__ __launch_bounds__(256) void conv1_kernel(const float* __restrict__ b1,
                                                    float* __restrict__ wsf) {
    __shared__ __align__(16) unsigned char xq[C1_NIMG * C1_IMGS];   // 36864 B
    __shared__ unsigned int wpk[180];
    __shared__ float bsm[6];
    unsigned int* wsu = (unsigned int*)wsf;
    int tid = threadIdx.x;
    int b0 = blockIdx.x * C1_NIMG;           // BATCH % 8 == 0
    float s0 = fmaxf(fdec(wsu[0]) / 127.0f, EPSQ);
    float seff = s0 * wsf[9];

    {
        const uint4* src = (const uint4*)((const unsigned char*)(wsu + OFF_QIN) + (size_t)b0 * C1_IMGS);
        uint4* dst = (uint4*)xq;
        for (int i = tid; i < C1_NIMG * 288; i += 256) dst[i] = src[i];
    }
    for (int i = tid; i < 180; i += 256) wpk[i] = wsu[OFF_WPK1 + i];
    if (tid < 6) bsm[tid] = b1[tid];
    __syncthreads();

    unsigned int* isum1 = wsu + OFF_ISUM1;
    float vmax = -INFINITY, vnmax = -INFINITY;
    const int ntask = C1_NIMG * 84;
    for (int t = tid; t < ntask; t += 256) {
        int img = t / 84, r = t % 84;
        int c = r / 14, py = r % 14;
        const unsigned char* ib = &xq[img * C1_IMGS + py * C1_ROWP];
        const unsigned int* wcp = &wpk[c * 30];
        int ip0[7], ip1[7];
        int gmax = -2000000000, gmin = 2000000000;
        c1_phase<0>(ib, wcp, ip0, gmax, gmin);
        c1_phase<1>(ib, wcp, ip1, gmax, gmin);
        float bias = bsm[c];
        vmax  = fmaxf(vmax,  fmaf(seff, (float)gmax, bias));
        vnmax = fmaxf(vnmax, -fmaf(seff, (float)gmin, bias));
        unsigned int* dst = isum1 + 588 * (size_t)(b0 + img) + 7 * (c * 14 + py);
        int v14[14];
        #pragma unroll
        for (int p = 0; p < 7; p++) { v14[p] = ip0[p]; v14[7 + p] = ip1[p]; }
        #pragma unroll
        for (int p = 0; p < 7; p++)
            dst[p] = (v14[2*p] & 0xFFFF) | ((unsigned)(v14[2*p+1] & 0xFFFF) << 16);
    }
    blockAtomicMax2(vmax, vnmax, wsu + 1, wsu + 2);
}

// ---------------- quant2: isum1 -> conv2 codes, interleaved [B][6][slot(16)][16] ----
__global__ __launch_bounds__(256) void quant2_kernel(const float* __restrict__ b1,
                                                     float* __restrict__ wsf) {
    unsigned int* wsu = (unsigned int*)wsf;
    float s1, s2;
    get_qrelu_scales(wsu, 1, s1, s2);
    float s0 = fmaxf(fdec(wsu[0]) / 127.0f, EPSQ);
    float seff = s0 * wsf[9];
    float bv[6];
    #pragma unroll
    for (int c = 0; c < 6; c++) bv[c] = b1[c];
    const short* isum1 = (const short*)(wsu + OFF_ISUM1);
    unsigned int* qc2 = wsu + OFF_QC2;
    int stride = gridDim.x * 256;
    const int total = BATCH * 84 * 4;
    for (int unit = blockIdx.x * 256 + threadIdx.x; unit < total; unit += stride) {
        int row_id = unit >> 2, w = unit & 3;
        int bci = row_id / 14, row = row_id % 14;
        int ci = bci % 6;
        int slot = (row >> 1) + ((row & 1) << 3);
        float bias = bv[ci];
        unsigned int u = 0;
        const short* sp = isum1 + (size_t)bci * 196 + row * 14;
        #pragma unroll
        for (int k = 0; k < 4; k++) {
            int col = w * 4 + k;
            int code = 0;
            if (col < 14) {
                float pre = fmaf(seff, (float)sp[col], bias);
                code = qrelu_code(pre, s1, s2);
            }
            u |= ((unsigned)(code & 255)) << (8 * k);
        }
        qc2[((size_t)bci * 16 + slot) * 4 + w] = u;
    }
}

// ---------------- conv2: 12 img/block, interleaved rows, dot4, staged i16 out ------
#define C2_ROWP 16
#define C2_CIS  256
#define C2_IMGS 1536
#define C2_NIMG 12

__global__ __launch_bounds__(256) void conv2_kernel(const float* __restrict__ b2,
                                                    float* __restrict__ wsf) {
    __shared__ __align__(16) unsigned char act[C2_NIMG * C2_IMGS];  // 18432 B
    __shared__ unsigned int wpk[960];
    __shared__ float bsm[16];
    __shared__ __align__(16) short spb[C2_NIMG * 400];               // 9600 B
    unsigned int* wsu = (unsigned int*)wsf;
    int tid = threadIdx.x;
    int b0 = blockIdx.x * C2_NIMG;
    int nimg = min(C2_NIMG, BATCH - b0);
    float s1, s2;
    get_qrelu_scales(wsu, 1, s1, s2);
    float seff = s2 * wsf[10];

    {
        const uint4* src = (const uint4*)((const unsigned char*)(wsu + OFF_QC2) + (size_t)b0 * C2_IMGS);
        uint4* dst = (uint4*)act;
        for (int i = tid; i < nimg * 96; i += 256) dst[i] = src[i];
    }
    for (int i = tid; i < 960; i += 256) wpk[i] = wsu[OFF_WPK2 + i];
    if (tid < 16) bsm[tid] = b2[tid];
    __syncthreads();

    float vmax = -INFINITY, vnmax = -INFINITY;
    int ntask = nimg * 80;
    for (int t = tid; t < ntask; t += 256) {
        int img = t / 80, r = t % 80;
        int c = r / 5, py = r % 5;
        const unsigned char* ib = &act[img * C2_IMGS + py * C2_ROWP];
        int a0[10], a1[10];
        #pragma unroll
        for (int i = 0; i < 10; i++) { a0[i] = 0; a1[i] = 0; }
        #pragma unroll 1
        for (int cig = 0; cig < 3; cig++) {
            uint4 R[2][6];
            #pragma unroll
            for (int g = 0; g < 2; g++)
                #pragma unroll
                for (int r6 = 0; r6 < 6; r6++)
                    R[g][r6] = *(const uint4*)(ib + (2*cig + g) * C2_CIS
                                + (((r6 & 1) << 3) + (r6 >> 1)) * C2_ROWP);
            #pragma unroll
            for (int g = 0; g < 2; g++) {
                int ci = 2*cig + g;
                const unsigned int* wkp = &wpk[(c * 6 + ci) * 10];
                unsigned int wk0[5], wk4[5];
                #pragma unroll
                for (int ky = 0; ky < 5; ky++) { wk0[ky] = wkp[2*ky]; wk4[ky] = wkp[2*ky+1]; }
                #pragma unroll
                for (int r6 = 0; r6 < 6; r6++) {
                    unsigned int wv[4] = { R[g][r6].x, R[g][r6].y, R[g][r6].z, R[g][r6].w };
                    unsigned int up[11];
                    #pragma unroll
                    for (int i = 0; i < 11; i++) up[i] = u32at(wv, i >> 2, i & 3);
                    if (r6 <= 4) {
                        unsigned int w0 = wk0[r6], w4 = wk4[r6];
                        #pragma unroll
                        for (int i = 0; i < 10; i++) {
                            a0[i] = sdot4(up[i], w0, a0[i]);
                            a0[i] = sdot4(up[i+1], w4, a0[i]);
                        }
                    }
                    if (r6 >= 1) {
                        unsigned int w0 = wk0[r6-1], w4 = wk4[r6-1];
                        #pragma unroll
                        for (int i = 0; i < 10; i++) {
                            a1[i] = sdot4(up[i], w0, a1[i]);
                            a1[i] = sdot4(up[i+1], w4, a1[i]);
                        }
                    }
                }
            }
        }
        int gmax = -2000000000, gmin = 2000000000;
        #pragma unroll
        for (int i = 0; i < 10; i++) {
            gmax = max(gmax, max(a0[i], a1[i]));
            gmin = min(gmin, min(a0[i], a1[i]));
        }
        float bias = bsm[c];
        vmax  = fmaxf(vmax,  fmaf(seff, (float)gmax, bias));
        vnmax = fmaxf(vnmax, -fmaf(seff, (float)gmin, bias));
        short* dst = spb + img * 400 + c * 25 + py * 5;
        #pragma unroll
        for (int p = 0; p < 5; p++)
            dst[p] = (short)max(max(a0[2*p], a0[2*p+1]), max(a1[2*p], a1[2*p+1]));
    }
    __syncthreads();
    {
        const uint4* pb4 = (const uint4*)spb;
        uint4* d4 = (uint4*)((short*)(wsu + OFF_ISUM2) + (size_t)b0 * 400);
        for (int i = tid; i < nimg * 50; i += 256) d4[i] = pb4[i];
    }
    blockAtomicMax2(vmax, vnmax, wsu + 3, wsu + 4);
}

// ---------------- quant3: isum2 i16 -> fc1 codes [B][100] u32 ----------------
__global__ __launch_bounds__(256) void quant3_kernel(const float* __restrict__ b2,
                                                     float* __restrict__ wsf) {
    unsigned int* wsu = (unsigned int*)wsf;
    float s1, s2;
    get_qrelu_scales(wsu, 3, s1, s2);
    float sp1, sp2;
    get_qrelu_scales(wsu, 1, sp1, sp2);
    float seff = sp2 * wsf[10];
    __shared__ float bv[16];
    if (threadIdx.x < 16) bv[threadIdx.x] = b2[threadIdx.x];
    __syncthreads();
    const short* isum2 = (const short*)(wsu + OFF_ISUM2);
    unsigned int* qc3 = wsu + OFF_QC3;
    int stride = gridDim.x * 256;
    const int total = BATCH * 100;
    for (int unit = blockIdx.x * 256 + threadIdx.x; unit < total; unit += stride) {
        int b = unit / 100, w = unit % 100;
        const short* sp = isum2 + (size_t)b * 400 + w * 4;
        unsigned int u = 0;
        #pragma unroll
        for (int k = 0; k < 4; k++) {
            int p = w * 4 + k;
            float pre = fmaf(seff, (float)sp[k], bv[p / 25]);
            int code = qrelu_code(pre, s1, s2);
            u |= ((unsigned)(code & 255)) << (8 * k);
        }
        qc3[unit] = u;
    }
}

// ---------------- fc1: 256 threads, 32 rows/block (512 blocks) ----------------
__global__ __launch_bounds__(256) void fc1_kernel(const float* __restrict__ fb1,
                                                  float* __restrict__ wsf) {
    __shared__ unsigned int xs[32][100];                 // 12800 B
    __shared__ __align__(16) float pb[32 * 120];         // 15360 B
    unsigned int* wsu = (unsigned int*)wsf;
    float* p3 = wsf + OFF_P3;
    int tid = threadIdx.x;
    size_t row0 = (size_t)blockIdx.x * 32;               // BATCH % 32 == 0
    float s1, s2;
    get_qrelu_scales(wsu, 3, s1, s2);
    float seff = s2 * wsf[11];
    {
        const uint4* src = (const uint4*)(wsu + OFF_QC3 + row0 * 100);
        uint4* dst = (uint4*)xs;
        for (int i = tid; i < 800; i += 256) dst[i] = src[i];
    }
    __syncthreads();
    float vmax = -INFINITY, vnmax = -INFINITY;
    if (tid < 240) {
        int g = tid / 120, j = tid % 120;                // 16 rows per group
        int acc[16];
        #pragma unroll
        for (int r = 0; r < 16; r++) acc[r] = 0;
        const uint4* wrow = (const uint4*)&wsu[OFF_FQ1 + j * 100];
        for (int kg = 0; kg < 25; kg++) {
            uint4 wv = wrow[kg];
            #pragma unroll
            for (int r = 0; r < 16; r++) {
                uint4 xv = *(const uint4*)&xs[g * 16 + r][kg * 4];
                acc[r] = sdot4(xv.x, wv.x, acc[r]);
                acc[r] = sdot4(xv.y, wv.y, acc[r]);
                acc[r] = sdot4(xv.z, wv.z, acc[r]);
                acc[r] = sdot4(xv.w, wv.w, acc[r]);
            }
        }
        float bias = fb1[j];
        #pragma unroll
        for (int r = 0; r < 16; r++) {
            float pv = fmaf(seff, (float)acc[r], bias);
            pb[(g * 16 + r) * 120 + j] = pv;
            vmax = fmaxf(vmax, pv); vnmax = fmaxf(vnmax, -pv);
        }
    }
    __syncthreads();
    {
        const float4* pb4 = (const float4*)pb;
        float4* d4 = (float4*)(p3 + row0 * 120);
        for (int i = tid; i < 960; i += 256) d4[i] = pb4[i];
    }
    blockAtomicMax2(vmax, vnmax, wsu + 5, wsu + 6);
}

// ---------------- fc2: 256 threads, 48 rows/block (342 blocks) ----------------
__global__ __launch_bounds__(256) void fc2_kernel(const float* __restrict__ fb2,
                                                  float* __restrict__ wsf) {
    __shared__ unsigned int xs[48][32];                  // 6144 B
    __shared__ __align__(16) float pb[48 * 84];          // 16128 B
    unsigned int* wsu = (unsigned int*)wsf;
    const float* p3 = wsf + OFF_P3;
    float* p4 = wsf + OFF_P4;
    int tid = threadIdx.x;
    size_t row0 = (size_t)blockIdx.x * 48;
    int nrow = min(48, (int)(BATCH - row0));
    float s1, s2;
    get_qrelu_scales(wsu, 5, s1, s2);
    float seff = s2 * wsf[12];
    const float4* src = (const float4*)(p3 + row0 * 120);
    for (int i = tid; i < nrow * 30; i += 256) {
        float4 v = src[i];
        int c0 = qrelu_code(v.x, s1, s2), c1 = qrelu_code(v.y, s1, s2);
        int c2 = qrelu_code(v.z, s1, s2), c3 = qrelu_code(v.w, s1, s2);
        xs[i / 30][i % 30] = c0 | (c1 << 8) | (c2 << 16) | ((unsigned)c3 << 24);
    }
    if (tid < 48) { xs[tid][30] = 0; xs[tid][31] = 0; }
    __syncthreads();
    float vmax = -INFINITY, vnmax = -INFINITY;
    if (tid < 252) {
        int g = tid / 84, j = tid % 84;                  // 3 groups x 16 rows
        int acc[16];
        #pragma unroll
        for (int r = 0; r < 16; r++) acc[r] = 0;
        const uint4* wrow = (const uint4*)&wsu[OFF_FQ2 + j * 32];
        #pragma unroll
        for (int kg = 0; kg < 8; kg++) {
            uint4 wv = wrow[kg];
            #pragma unroll
            for (int r = 0; r < 16; r++) {
                uint4 xv = *(const uint4*)&xs[g * 16 + r][kg * 4];
                acc[r] = sdot4(xv.x, wv.x, acc[r]);
                acc[r] = sdot4(xv.y, wv.y, acc[r]);
                acc[r] = sdot4(xv.z, wv.z, acc[r]);
                acc[r] = sdot4(xv.w, wv.w, acc[r]);
            }
        }
        float bias = fb2[j];
        #pragma unroll
        for (int r = 0; r < 16; r++) {
            int lr = g * 16 + r;
            if (lr < nrow) {
                float pv = fmaf(seff, (float)acc[r], bias);
                pb[lr * 84 + j] = pv;
                vmax = fmaxf(vmax, pv); vnmax = fmaxf(vnmax, -pv);
            }
        }
    }
    __syncthreads();
    {
        const float4* pb4 = (const float4*)pb;
        float4* d4 = (float4*)(p4 + row0 * 84);
        for (int i = tid; i < nrow * 21; i += 256) d4[i] = pb4[i];
    }
    blockAtomicMax2(vmax, vnmax, wsu + 7, wsu + 8);
}

// ---------------- fc3: [B,84]->[B,10] ----------------
__global__ __launch_bounds__(256) void fc3_kernel(const float* __restrict__ fb3,
                                                  float* __restrict__ out,
                                                  float* __restrict__ wsf) {
    __shared__ unsigned int wsm[240];
    __shared__ float bs[10];
    __shared__ __align__(16) float pb[2560];
    unsigned int* wsu = (unsigned int*)wsf;
    const float* p4 = wsf + OFF_P4;
    int tid = threadIdx.x;
    for (int i = tid; i < 240; i += 256) wsm[i] = wsu[OFF_FQ3 + i];
    if (tid < 10) bs[tid] = fb3[tid];
    __syncthreads();
    float s1, s2;
    get_qrelu_scales(wsu, 7, s1, s2);
    float seff = s2 * wsf[13];
    size_t row = (size_t)blockIdx.x * 256 + tid;
    unsigned int xr[24];
    const float4* src = (const float4*)(p4 + row * 84);
    #pragma unroll
    for (int k = 0; k < 21; k++) {
        float4 v = src[k];
        int c0 = qrelu_code(v.x, s1, s2), c1 = qrelu_code(v.y, s1, s2);
        int c2 = qrelu_code(v.z, s1, s2), c3 = qrelu_code(v.w, s1, s2);
        xr[k] = c0 | (c1 << 8) | (c2 << 16) | ((unsigned)c3 << 24);
    }
    xr[21] = 0; xr[22] = 0; xr[23] = 0;
    #pragma unroll
    for (int j = 0; j < 10; j++) {
        int acc = 0;
        #pragma unroll
        for (int k = 0; k < 24; k++) acc = sdot4(xr[k], wsm[j * 24 + k], acc);
        pb[tid * 10 + j] = fmaf(seff, (float)acc, bs[j]);
    }
    __syncthreads();
    {
        const float4* pb4 = (const float4*)pb;
        float4* d4 = (float4*)(out + (size_t)blockIdx.x * 2560);
        for (int i = tid; i < 640; i += 256) d4[i] = pb4[i];
    }
}

extern "C" void kernel_launch(void* const* d_in, const int* in_sizes, int n_in,
                              void* d_out, int out_size, void* d_ws, size_t ws_size,
                              hipStream_t stream) {
    const float* input = (const float*)d_in[0];
    const float* w1  = (const float*)d_in[1];
    const float* b1  = (const float*)d_in[2];
    const float* w2  = (const float*)d_in[3];
    const float* b2  = (const float*)d_in[4];
    const float* fw1 = (const float*)d_in[5];
    const float* fb1 = (const float*)d_in[6];
    const float* fw2 = (const float*)d_in[7];
    const float* fb2 = (const float*)d_in[8];
    const float* fw3 = (const float*)d_in[9];
    const float* fb3 = (const float*)d_in[10];
    float* ws  = (float*)d_ws;
    float* out = (float*)d_out;

    prep_kernel<<<6, 256, 0, stream>>>(w1, w2, fw1, fw2, fw3, ws);
    absmax_kernel<<<2048, 256, 0, stream>>>((const float4*)input,
                                            (int)((size_t)BATCH * 3072 / 4),
                                            (unsigned int*)ws);
    quant1_kernel<<<8192, 256, 0, stream>>>((const float4*)input, ws);
    conv1_kernel<<<BATCH / C1_NIMG, 256, 0, stream>>>(b1, ws);
    quant2_kernel<<<4096, 256, 0, stream>>>(b1, ws);
    conv2_kernel<<<(BATCH + C2_NIMG - 1) / C2_NIMG, 256, 0, stream>>>(b2, ws);
    quant3_kernel<<<2048, 256, 0, stream>>>(b2, ws);
    fc1_kernel<<<BATCH / 32, 256, 0, stream>>>(fb1, ws);
    fc2_kernel<<<(BATCH + 47) / 48, 256, 0, stream>>>(fb2, ws);
    fc3_kernel<<<BATCH / 256, 256, 0, stream>>>(fb3, out, ws);
}

// Round 13
// 467.605 us; speedup vs baseline: 2.1107x; 1.0136x over previous
//
#include <hip/hip_runtime.h>
#include <math.h>

#define BATCH 16384
#define EPSQ 1e-8f

// ---------------- ws layout (32-bit units) ----------------
// scal keys: [0] absmax_in, [1,2] conv1 max/negmax, [3,4] conv2, [5,6] fc1, [7,8] fc2
// floats: [9] s_w1 [10] s_w2 [11] s_w3 [12] s_w4 [13] s_w5
#define OFF_SCAL 0
#define OFF_WPK1 16        // 180 u32
#define OFF_WPK2 196       // 960 u32
#define OFF_FQ1  1156      // 12000 u32
#define OFF_FQ2  13156     // 2688 u32
#define OFF_FQ3  15844     // 240 u32
#define OFF_A    16384
// region A time-multiplexed:
#define OFF_QIN   OFF_A                 // [B][3][32slots][48] i8 (75.5MB) quant1->conv1
#define OFF_QC2   OFF_A                 // [B][6][16slots][16] i8 (25.2MB) quant2->conv2
#define OFF_ISUM2 (OFF_A + 6400000)     // [B][400] i16 conv2->quant3
#define OFF_QC3   (OFF_A + 10000000)    // [B][100] u32 quant3->fc1
#define OFF_P3    (OFF_A + 12000000)    // [B][120] f32 fc1->fc2
#define OFF_P4    (OFF_A + 14000000)    // [B][84]  f32 fc2->fc3
#define OFF_ISUM1 (OFF_A + 18874368)    // [B][1176] i16 (38.5MB) conv1->quant2

__device__ inline int sdot4(unsigned int a, unsigned int b, int c) {
    return __builtin_amdgcn_sdot4((int)a, (int)b, c, false);
}

__device__ inline unsigned int fkey(float f) {
    unsigned int u = __float_as_uint(f);
    return (u & 0x80000000u) ? ~u : (u | 0x80000000u);
}
__device__ inline float fdec(unsigned int k) {
    unsigned int u = (k & 0x80000000u) ? (k ^ 0x80000000u) : ~k;
    return __uint_as_float(u);
}
#define KEY_ZERO   0x80000000u
#define KEY_NEGINF 0x007FFFFFu

__device__ inline float waveMax(float v) {
    #pragma unroll
    for (int off = 32; off > 0; off >>= 1)
        v = fmaxf(v, __shfl_down(v, off, 64));
    return v;
}

__device__ inline void blockAtomicMax2(float vmax, float vnmax,
                                       unsigned int* gmax, unsigned int* gnmax) {
    __shared__ float sm[4], sn[4];
    float a = waveMax(vmax), b = waveMax(vnmax);
    int tid = threadIdx.x;
    if ((tid & 63) == 0) { sm[tid >> 6] = a; sn[tid >> 6] = b; }
    __syncthreads();
    if (tid == 0) {
        atomicMax(gmax, fkey(fmaxf(fmaxf(sm[0], sm[1]), fmaxf(sm[2], sm[3]))));
        atomicMax(gnmax, fkey(fmaxf(fmaxf(sn[0], sn[1]), fmaxf(sn[2], sn[3]))));
    }
}

__device__ inline float fq_elem(float x, float s) {
    float q = fminf(fmaxf(rintf(x / s), -128.0f), 127.0f);
    return q * s;
}
__device__ inline int qrelu_code(float x, float s1, float s2) {
    float q = fq_elem(x, s1);
    q = fmaxf(q, 0.0f);
    return (int)fminf(fmaxf(rintf(q / s2), -128.0f), 127.0f);
}
__device__ inline void get_qrelu_scales(const unsigned int* scalu, int slot,
                                        float& s1, float& s2) {
    float maxa = fdec(scalu[slot]), negm = fdec(scalu[slot + 1]);
    float absm = fmaxf(maxa, negm);
    s1 = fmaxf(absm / 127.0f, EPSQ);
    float qm = fminf(fmaxf(rintf(maxa / s1), -128.0f), 127.0f) * s1;
    s2 = fmaxf(fmaxf(qm, 0.0f) / 127.0f, EPSQ);
}

__device__ inline unsigned int sgn8(float w) { return (w >= 0.0f) ? 0x01u : 0xFFu; }

__device__ inline unsigned int u32at(const unsigned int* wv, int wi, int k) {
    return (k == 0) ? wv[wi]
        : __builtin_amdgcn_perm(wv[wi + 1], wv[wi], 0x03020100u + 0x01010101u * (unsigned)k);
}

// ---------------- prep ----------------
__global__ __launch_bounds__(256) void prep_kernel(const float* __restrict__ w1,
        const float* __restrict__ w2, const float* __restrict__ fw1,
        const float* __restrict__ fw2, const float* __restrict__ fw3,
        float* __restrict__ wsf) {
    int blk = blockIdx.x, tid = threadIdx.x;
    unsigned int* wsu = (unsigned int*)wsf;
    if (blk == 0) {
        if (tid == 0) wsu[0] = KEY_ZERO;
        else if (tid <= 8) wsu[tid] = KEY_NEGINF;
        return;
    }
    const float* src = nullptr; int N = 0;
    if (blk == 1)      { src = w1;  N = 450; }
    else if (blk == 2) { src = w2;  N = 2400; }
    else if (blk == 3) { src = fw1; N = 48000; }
    else if (blk == 4) { src = fw2; N = 10080; }
    else               { src = fw3; N = 840; }
    __shared__ float red[256];
    float partial = 0.0f;
    for (int i = tid; i < N; i += 256) partial += fabsf(src[i]);
    red[tid] = partial;
    __syncthreads();
    for (int s = 128; s > 0; s >>= 1) {
        if (tid < s) red[tid] += red[tid + s];
        __syncthreads();
    }
    if (tid == 0) wsf[8 + blk] = red[0] / (float)N;

    if (blk == 1) {
        for (int t = tid; t < 90; t += 256) {
            const float* wp = w1 + t * 5;
            wsu[OFF_WPK1 + 2*t] = sgn8(wp[0]) | (sgn8(wp[1])<<8) | (sgn8(wp[2])<<16) | (sgn8(wp[3])<<24);
            wsu[OFF_WPK1 + 2*t + 1] = sgn8(wp[4]) << 24;
        }
    } else if (blk == 2) {
        for (int t = tid; t < 480; t += 256) {
            const float* wp = w2 + t * 5;
            wsu[OFF_WPK2 + 2*t] = sgn8(wp[0]) | (sgn8(wp[1])<<8) | (sgn8(wp[2])<<16) | (sgn8(wp[3])<<24);
            wsu[OFF_WPK2 + 2*t + 1] = sgn8(wp[4]) << 24;
        }
    } else if (blk == 3) {
        for (int i = tid; i < 12000; i += 256) {
            int j = i / 100, k = i % 100;
            const float* wp = fw1 + j * 400 + k * 4;
            wsu[OFF_FQ1 + i] = sgn8(wp[0]) | (sgn8(wp[1])<<8) | (sgn8(wp[2])<<16) | (sgn8(wp[3])<<24);
        }
    } else if (blk == 4) {
        for (int i = tid; i < 2688; i += 256) {
            int j = i >> 5, k = i & 31;
            unsigned int u = 0;
            if (k < 30) {
                const float* wp = fw2 + j * 120 + k * 4;
                u = sgn8(wp[0]) | (sgn8(wp[1])<<8) | (sgn8(wp[2])<<16) | (sgn8(wp[3])<<24);
            }
            wsu[OFF_FQ2 + i] = u;
        }
    } else {
        for (int i = tid; i < 240; i += 256) {
            int j = i / 24, k = i % 24;
            unsigned int u = 0;
            if (k < 21) {
                const float* wp = fw3 + j * 84 + k * 4;
                u = sgn8(wp[0]) | (sgn8(wp[1])<<8) | (sgn8(wp[2])<<16) | (sgn8(wp[3])<<24);
            }
            wsu[OFF_FQ3 + i] = u;
        }
    }
}

// ---------------- input abs-max ----------------
__global__ __launch_bounds__(256) void absmax_kernel(const float4* __restrict__ x, int n4,
                                                     unsigned int* __restrict__ gkey) {
    float m = 0.0f;
    int stride = gridDim.x * 256;
    for (int i = blockIdx.x * 256 + threadIdx.x; i < n4; i += stride) {
        float4 v = x[i];
        m = fmaxf(m, fmaxf(fmaxf(fabsf(v.x), fabsf(v.y)), fmaxf(fabsf(v.z), fabsf(v.w))));
    }
    __shared__ float sm[4];
    m = waveMax(m);
    int tid = threadIdx.x;
    if ((tid & 63) == 0) sm[tid >> 6] = m;
    __syncthreads();
    if (tid == 0)
        atomicMax(gkey, fkey(fmaxf(fmaxf(sm[0], sm[1]), fmaxf(sm[2], sm[3]))));
}

// ---------------- quant1: fp32 -> i8 codes, row-interleaved [B][3][slot(32)][48] ----
__global__ __launch_bounds__(256) void quant1_kernel(const float4* __restrict__ x,
                                                     float* __restrict__ wsf) {
    unsigned int* wsu = (unsigned int*)wsf;
    float s0 = fmaxf(fdec(wsu[0]) / 127.0f, EPSQ);
    unsigned int* qin = wsu + OFF_QIN;
    int stride = gridDim.x * 256;
    const int total = BATCH * 96 * 12;
    for (int unit = blockIdx.x * 256 + threadIdx.x; unit < total; unit += stride) {
        int row_id = unit / 12, w = unit % 12;
        int plane = row_id >> 5, row = row_id & 31;
        int slot = (row >> 1) + ((row & 1) << 4);
        unsigned int u = 0;
        if (w < 8) {
            float4 v = x[row_id * 8 + w];
            int q0 = (int)fminf(fmaxf(rintf(v.x / s0), -128.f), 127.f);
            int q1 = (int)fminf(fmaxf(rintf(v.y / s0), -128.f), 127.f);
            int q2 = (int)fminf(fmaxf(rintf(v.z / s0), -128.f), 127.f);
            int q3 = (int)fminf(fmaxf(rintf(v.w / s0), -128.f), 127.f);
            u = (q0 & 255) | ((q1 & 255) << 8) | ((q2 & 255) << 16) | ((unsigned)(q3 & 255) << 24);
        }
        qin[(plane * 32 + slot) * 12 + w] = u;
    }
}

// ---------------- conv1: 12 img/block, interleaved rows, dot4, i16 isum out ------
#define C1_ROWP 48
#define C1_CIS  1536
#define C1_IMGS 4608
#define C1_NIMG 12

// PH=0: outputs x=0..13, window bytes 0..19  -> wv={A(0..15),Bv(16..19)}, OFS=0
// PH=1: outputs x=14..27, window bytes 14..31 -> wv={Bv(12..15),A(16..31)}, OFS=2
template<int PH>
__device__ __forceinline__ void c1_phase(const unsigned char* ib, const unsigned int* wcp,
                                         int* ip, int& gmax, int& gmin) {
    int a0[14], a1[14];
    #pragma unroll
    for (int i = 0; i < 14; i++) { a0[i] = 0; a1[i] = 0; }
    #pragma unroll 1
    for (int ci = 0; ci < 3; ci++) {
        uint4 A[6]; unsigned int Bv[6];
        const unsigned char* cb = ib + ci * C1_CIS;
        #pragma unroll
        for (int r = 0; r < 6; r++) {
            const unsigned char* rb = cb + (((r & 1) << 4) + (r >> 1)) * C1_ROWP;
            if (PH == 0) {
                A[r]  = *(const uint4*)(rb);
                Bv[r] = *(const unsigned int*)(rb + 16);
            } else {
                Bv[r] = *(const unsigned int*)(rb + 12);
                A[r]  = *(const uint4*)(rb + 16);
            }
        }
        const unsigned int* wkp = wcp + ci * 10;
        unsigned int wk0[5], wk4[5];
        #pragma unroll
        for (int ky = 0; ky < 5; ky++) { wk0[ky] = wkp[2*ky]; wk4[ky] = wkp[2*ky+1]; }
        #pragma unroll
        for (int r6 = 0; r6 < 6; r6++) {
            unsigned int wv[5];
            if (PH == 0) {
                wv[0] = A[r6].x; wv[1] = A[r6].y; wv[2] = A[r6].z; wv[3] = A[r6].w; wv[4] = Bv[r6];
            } else {
                wv[0] = Bv[r6]; wv[1] = A[r6].x; wv[2] = A[r6].y; wv[3] = A[r6].z; wv[4] = A[r6].w;
            }
            const int OFS = (PH == 0) ? 0 : 2;
            unsigned int up[15];
            #pragma unroll
            for (int i = 0; i < 15; i++) {
                int e = OFS + i;
                up[i] = u32at(wv, e >> 2, e & 3);
            }
            if (r6 <= 4) {
                unsigned int w0 = wk0[r6], w4 = wk4[r6];
                #pragma unroll
                for (int i = 0; i < 14; i++) {
                    a0[i] = sdot4(up[i], w0, a0[i]);
                    a0[i] = sdot4(up[i+1], w4, a0[i]);
                }
            }
            if (r6 >= 1) {
                unsigned int w0 = wk0[r6-1], w4 = wk4[r6-1];
                #pragma unroll
                for (int i = 0; i < 14; i++) {
                    a1[i] = sdot4(up[i], w0, a1[i]);
                    a1[i] = sdot4(up[i+1], w4, a1[i]);
                }
            }
        }
    }
    #pragma unroll
    for (int i = 0; i < 14; i++) {
        gmax = max(gmax, max(a0[i], a1[i]));
        gmin = min(gmin, min(a0[i], a1[i]));
    }
    #pragma unroll
    for (int p = 0; p < 7; p++)
        ip[p] = max(max(a0[2*p], a0[2*p+1]), max(a1[2*p], a1[2*p+1]));
}

__global__ __launch_bounds__(256) void conv1_kernel(const float* __restrict__ b1,
                                                    float* __restrict__ wsf) {
    __shared__ __align__(16) unsigned char xq[C1_NIMG * C1_IMGS];   // 55296 B
    __shared__ unsigned int wpk[180];
    __shared__ float bsm[6];
    unsigned int* wsu = (unsigned int*)wsf;
    int tid = threadIdx.x;
    int b0 = blockIdx.x * C1_NIMG;
    int nimg = min(C1_NIMG, BATCH - b0);
    float s0 = fmaxf(fdec(wsu[0]) / 127.0f, EPSQ);
    float seff = s0 * wsf[9];

    {
        const uint4* src = (const uint4*)((const unsigned char*)(wsu + OFF_QIN) + (size_t)b0 * C1_IMGS);
        uint4* dst = (uint4*)xq;
        for (int i = tid; i < nimg * 288; i += 256) dst[i] = src[i];
    }
    for (int i = tid; i < 180; i += 256) wpk[i] = wsu[OFF_WPK1 + i];
    if (tid < 6) bsm[tid] = b1[tid];
    __syncthreads();

    unsigned int* isum1 = wsu + OFF_ISUM1;
    float vmax = -INFINITY, vnmax = -INFINITY;
    int ntask = nimg * 84;   // 1008 = 252*4 when full
    for (int t = tid; t < ntask; t += 252) {
        if (tid >= 252) break;
        int img = t / 84, r = t % 84;
        int c = r / 14, py = r % 14;
        const unsigned char* ib = &xq[img * C1_IMGS + py * C1_ROWP];
        const unsigned int* wcp = &wpk[c * 30];
        int ip0[7], ip1[7];
        int gmax = -2000000000, gmin = 2000000000;
        c1_phase<0>(ib, wcp, ip0, gmax, gmin);
        c1_phase<1>(ib, wcp, ip1, gmax, gmin);
        float bias = bsm[c];
        vmax  = fmaxf(vmax,  fmaf(seff, (float)gmax, bias));
        vnmax = fmaxf(vnmax, -fmaf(seff, (float)gmin, bias));
        unsigned int* dst = isum1 + 588 * (size_t)(b0 + img) + 7 * (c * 14 + py);
        int v14[14];
        #pragma unroll
        for (int p = 0; p < 7; p++) { v14[p] = ip0[p]; v14[7 + p] = ip1[p]; }
        #pragma unroll
        for (int p = 0; p < 7; p++)
            dst[p] = (v14[2*p] & 0xFFFF) | ((unsigned)(v14[2*p+1] & 0xFFFF) << 16);
    }
    blockAtomicMax2(vmax, vnmax, wsu + 1, wsu + 2);
}

// ---------------- quant2: isum1 -> conv2 codes, interleaved [B][6][slot(16)][16] ----
__global__ __launch_bounds__(256) void quant2_kernel(const float* __restrict__ b1,
                                                     float* __restrict__ wsf) {
    unsigned int* wsu = (unsigned int*)wsf;
    float s1, s2;
    get_qrelu_scales(wsu, 1, s1, s2);
    float s0 = fmaxf(fdec(wsu[0]) / 127.0f, EPSQ);
    float seff = s0 * wsf[9];
    float bv[6];
    #pragma unroll
    for (int c = 0; c < 6; c++) bv[c] = b1[c];
    const short* isum1 = (const short*)(wsu + OFF_ISUM1);
    unsigned int* qc2 = wsu + OFF_QC2;
    int stride = gridDim.x * 256;
    const int total = BATCH * 84 * 4;
    for (int unit = blockIdx.x * 256 + threadIdx.x; unit < total; unit += stride) {
        int row_id = unit >> 2, w = unit & 3;
        int bci = row_id / 14, row = row_id % 14;
        int ci = bci % 6;
        int slot = (row >> 1) + ((row & 1) << 3);
        float bias = bv[ci];
        unsigned int u = 0;
        const short* sp = isum1 + (size_t)bci * 196 + row * 14;
        #pragma unroll
        for (int k = 0; k < 4; k++) {
            int col = w * 4 + k;
            int code = 0;
            if (col < 14) {
                float pre = fmaf(seff, (float)sp[col], bias);
                code = qrelu_code(pre, s1, s2);
            }
            u |= ((unsigned)(code & 255)) << (8 * k);
        }
        qc2[((size_t)bci * 16 + slot) * 4 + w] = u;
    }
}

// ---------------- conv2: 16 img/block, interleaved rows, dot4, staged i16 out ------
#define C2_ROWP 16
#define C2_CIS  256
#define C2_IMGS 1536
#define C2_NIMG 16

__global__ __launch_bounds__(256) void conv2_kernel(const float* __restrict__ b2,
                                                    float* __restrict__ wsf) {
    __shared__ __align__(16) unsigned char act[C2_NIMG * C2_IMGS];  // 24576 B
    __shared__ unsigned int wpk[960];
    __shared__ float bsm[16];
    __shared__ __align__(16) short spb[C2_NIMG * 400];               // 12800 B
    unsigned int* wsu = (unsigned int*)wsf;
    int tid = threadIdx.x;
    int b0 = blockIdx.x * C2_NIMG;           // BATCH % 16 == 0
    float s1, s2;
    get_qrelu_scales(wsu, 1, s1, s2);
    float seff = s2 * wsf[10];

    {
        const uint4* src = (const uint4*)((const unsigned char*)(wsu + OFF_QC2) + (size_t)b0 * C2_IMGS);
        uint4* dst = (uint4*)act;
        for (int i = tid; i < C2_NIMG * 96; i += 256) dst[i] = src[i];
    }
    for (int i = tid; i < 960; i += 256) wpk[i] = wsu[OFF_WPK2 + i];
    if (tid < 16) bsm[tid] = b2[tid];
    __syncthreads();

    float vmax = -INFINITY, vnmax = -INFINITY;
    const int ntask = C2_NIMG * 80;          // 1280 = 5*256 exact
    for (int t = tid; t < ntask; t += 256) {
        int img = t / 80, r = t % 80;
        int c = r / 5, py = r % 5;
        const unsigned char* ib = &act[img * C2_IMGS + py * C2_ROWP];
        int a0[10], a1[10];
        #pragma unroll
        for (int i = 0; i < 10; i++) { a0[i] = 0; a1[i] = 0; }
        #pragma unroll 1
        for (int cig = 0; cig < 3; cig++) {
            uint4 R[2][6];
            #pragma unroll
            for (int g = 0; g < 2; g++)
                #pragma unroll
                for (int r6 = 0; r6 < 6; r6++)
                    R[g][r6] = *(const uint4*)(ib + (2*cig + g) * C2_CIS
                                + (((r6 & 1) << 3) + (r6 >> 1)) * C2_ROWP);
            #pragma unroll
            for (int g = 0; g < 2; g++) {
                int ci = 2*cig + g;
                const unsigned int* wkp = &wpk[(c * 6 + ci) * 10];
                unsigned int wk0[5], wk4[5];
                #pragma unroll
                for (int ky = 0; ky < 5; ky++) { wk0[ky] = wkp[2*ky]; wk4[ky] = wkp[2*ky+1]; }
                #pragma unroll
                for (int r6 = 0; r6 < 6; r6++) {
                    unsigned int wv[4] = { R[g][r6].x, R[g][r6].y, R[g][r6].z, R[g][r6].w };
                    unsigned int up[11];
                    #pragma unroll
                    for (int i = 0; i < 11; i++) up[i] = u32at(wv, i >> 2, i & 3);
                    if (r6 <= 4) {
                        unsigned int w0 = wk0[r6], w4 = wk4[r6];
                        #pragma unroll
                        for (int i = 0; i < 10; i++) {
                            a0[i] = sdot4(up[i], w0, a0[i]);
                            a0[i] = sdot4(up[i+1], w4, a0[i]);
                        }
                    }
                    if (r6 >= 1) {
                        unsigned int w0 = wk0[r6-1], w4 = wk4[r6-1];
                        #pragma unroll
                        for (int i = 0; i < 10; i++) {
                            a1[i] = sdot4(up[i], w0, a1[i]);
                            a1[i] = sdot4(up[i+1], w4, a1[i]);
                        }
                    }
                }
            }
        }
        int gmax = -2000000000, gmin = 2000000000;
        #pragma unroll
        for (int i = 0; i < 10; i++) {
            gmax = max(gmax, max(a0[i], a1[i]));
            gmin = min(gmin, min(a0[i], a1[i]));
        }
        float bias = bsm[c];
        vmax  = fmaxf(vmax,  fmaf(seff, (float)gmax, bias));
        vnmax = fmaxf(vnmax, -fmaf(seff, (float)gmin, bias));
        short* dst = spb + img * 400 + c * 25 + py * 5;
        #pragma unroll
        for (int p = 0; p < 5; p++)
            dst[p] = (short)max(max(a0[2*p], a0[2*p+1]), max(a1[2*p], a1[2*p+1]));
    }
    __syncthreads();
    {
        const uint4* pb4 = (const uint4*)spb;
        uint4* d4 = (uint4*)((short*)(wsu + OFF_ISUM2) + (size_t)b0 * 400);
        for (int i = tid; i < C2_NIMG * 50; i += 256) d4[i] = pb4[i];
    }
    blockAtomicMax2(vmax, vnmax, wsu + 3, wsu + 4);
}

// ---------------- quant3: isum2 i16 -> fc1 codes [B][100] u32 ----------------
__global__ __launch_bounds__(256) void quant3_kernel(const float* __restrict__ b2,
                                                     float* __restrict__ wsf) {
    unsigned int* wsu = (unsigned int*)wsf;
    float s1, s2;
    get_qrelu_scales(wsu, 3, s1, s2);
    float sp1, sp2;
    get_qrelu_scales(wsu, 1, sp1, sp2);
    float seff = sp2 * wsf[10];
    __shared__ float bv[16];
    if (threadIdx.x < 16) bv[threadIdx.x] = b2[threadIdx.x];
    __syncthreads();
    const short* isum2 = (const short*)(wsu + OFF_ISUM2);
    unsigned int* qc3 = wsu + OFF_QC3;
    int stride = gridDim.x * 256;
    const int total = BATCH * 100;
    for (int unit = blockIdx.x * 256 + threadIdx.x; unit < total; unit += stride) {
        int b = unit / 100, w = unit % 100;
        const short* sp = isum2 + (size_t)b * 400 + w * 4;
        unsigned int u = 0;
        #pragma unroll
        for (int k = 0; k < 4; k++) {
            int p = w * 4 + k;
            float pre = fmaf(seff, (float)sp[k], bv[p / 25]);
            int code = qrelu_code(pre, s1, s2);
            u |= ((unsigned)(code & 255)) << (8 * k);
        }
        qc3[unit] = u;
    }
}

// ---------------- fc1: 256 threads, 32 rows/block (512 blocks) ----------------
__global__ __launch_bounds__(256) void fc1_kernel(const float* __restrict__ fb1,
                                                  float* __restrict__ wsf) {
    __shared__ unsigned int xs[32][100];
    __shared__ __align__(16) float pb[32 * 120];
    unsigned int* wsu = (unsigned int*)wsf;
    float* p3 = wsf + OFF_P3;
    int tid = threadIdx.x;
    size_t row0 = (size_t)blockIdx.x * 32;
    float s1, s2;
    get_qrelu_scales(wsu, 3, s1, s2);
    float seff = s2 * wsf[11];
    {
        const uint4* src = (const uint4*)(wsu + OFF_QC3 + row0 * 100);
        uint4* dst = (uint4*)xs;
        for (int i = tid; i < 800; i += 256) dst[i] = src[i];
    }
    __syncthreads();
    float vmax = -INFINITY, vnmax = -INFINITY;
    if (tid < 240) {
        int g = tid / 120, j = tid % 120;
        int acc[16];
        #pragma unroll
        for (int r = 0; r < 16; r++) acc[r] = 0;
        const uint4* wrow = (const uint4*)&wsu[OFF_FQ1 + j * 100];
        for (int kg = 0; kg < 25; kg++) {
            uint4 wv = wrow[kg];
            #pragma unroll
            for (int r = 0; r < 16; r++) {
                uint4 xv = *(const uint4*)&xs[g * 16 + r][kg * 4];
                acc[r] = sdot4(xv.x, wv.x, acc[r]);
                acc[r] = sdot4(xv.y, wv.y, acc[r]);
                acc[r] = sdot4(xv.z, wv.z, acc[r]);
                acc[r] = sdot4(xv.w, wv.w, acc[r]);
            }
        }
        float bias = fb1[j];
        #pragma unroll
        for (int r = 0; r < 16; r++) {
            float pv = fmaf(seff, (float)acc[r], bias);
            pb[(g * 16 + r) * 120 + j] = pv;
            vmax = fmaxf(vmax, pv); vnmax = fmaxf(vnmax, -pv);
        }
    }
    __syncthreads();
    {
        const float4* pb4 = (const float4*)pb;
        float4* d4 = (float4*)(p3 + row0 * 120);
        for (int i = tid; i < 960; i += 256) d4[i] = pb4[i];
    }
    blockAtomicMax2(vmax, vnmax, wsu + 5, wsu + 6);
}

// ---------------- fc2: 256 threads, 48 rows/block (342 blocks) ----------------
__global__ __launch_bounds__(256) void fc2_kernel(const float* __restrict__ fb2,
                                                  float* __restrict__ wsf) {
    __shared__ unsigned int xs[48][32];
    __shared__ __align__(16) float pb[48 * 84];
    unsigned int* wsu = (unsigned int*)wsf;
    const float* p3 = wsf + OFF_P3;
    float* p4 = wsf + OFF_P4;
    int tid = threadIdx.x;
    size_t row0 = (size_t)blockIdx.x * 48;
    int nrow = min(48, (int)(BATCH - row0));
    float s1, s2;
    get_qrelu_scales(wsu, 5, s1, s2);
    float seff = s2 * wsf[12];
    const float4* src = (const float4*)(p3 + row0 * 120);
    for (int i = tid; i < nrow * 30; i += 256) {
        float4 v = src[i];
        int c0 = qrelu_code(v.x, s1, s2), c1 = qrelu_code(v.y, s1, s2);
        int c2 = qrelu_code(v.z, s1, s2), c3 = qrelu_code(v.w, s1, s2);
        xs[i / 30][i % 30] = c0 | (c1 << 8) | (c2 << 16) | ((unsigned)c3 << 24);
    }
    if (tid < 48) { xs[tid][30] = 0; xs[tid][31] = 0; }
    __syncthreads();
    float vmax = -INFINITY, vnmax = -INFINITY;
    if (tid < 252) {
        int g = tid / 84, j = tid % 84;
        int acc[16];
        #pragma unroll
        for (int r = 0; r < 16; r++) acc[r] = 0;
        const uint4* wrow = (const uint4*)&wsu[OFF_FQ2 + j * 32];
        #pragma unroll
        for (int kg = 0; kg < 8; kg++) {
            uint4 wv = wrow[kg];
            #pragma unroll
            for (int r = 0; r < 16; r++) {
                uint4 xv = *(const uint4*)&xs[g * 16 + r][kg * 4];
                acc[r] = sdot4(xv.x, wv.x, acc[r]);
                acc[r] = sdot4(xv.y, wv.y, acc[r]);
                acc[r] = sdot4(xv.z, wv.z, acc[r]);
                acc[r] = sdot4(xv.w, wv.w, acc[r]);
            }
        }
        float bias = fb2[j];
        #pragma unroll
        for (int r = 0; r < 16; r++) {
            int lr = g * 16 + r;
            if (lr < nrow) {
                float pv = fmaf(seff, (float)acc[r], bias);
                pb[lr * 84 + j] = pv;
                vmax = fmaxf(vmax, pv); vnmax = fmaxf(vnmax, -pv);
            }
        }
    }
    __syncthreads();
    {
        const float4* pb4 = (const float4*)pb;
        float4* d4 = (float4*)(p4 + row0 * 84);
        for (int i = tid; i < nrow * 21; i += 256) d4[i] = pb4[i];
    }
    blockAtomicMax2(vmax, vnmax, wsu + 7, wsu + 8);
}

// ---------------- fc3: [B,84]->[B,10] ----------------
__global__ __launch_bounds__(256) void fc3_kernel(const float* __restrict__ fb3,
                                                  float* __restrict__ out,
                                                  float* __restrict__ wsf) {
    __shared__ unsigned int wsm[240];
    __shared__ float bs[10];
    __shared__ __align__(16) float pb[2560];
    unsigned int* wsu = (unsigned int*)wsf;
    const float* p4 = wsf + OFF_P4;
    int tid = threadIdx.x;
    for (int i = tid; i < 240; i += 256) wsm[i] = wsu[OFF_FQ3 + i];
    if (tid < 10) bs[tid] = fb3[tid];
    __syncthreads();
    float s1, s2;
    get_qrelu_scales(wsu, 7, s1, s2);
    float seff = s2 * wsf[13];
    size_t row = (size_t)blockIdx.x * 256 + tid;
    unsigned int xr[24];
    const float4* src = (const float4*)(p4 + row * 84);
    #pragma unroll
    for (int k = 0; k < 21; k++) {
        float4 v = src[k];
        int c0 = qrelu_code(v.x, s1, s2), c1 = qrelu_code(v.y, s1, s2);
        int c2 = qrelu_code(v.z, s1, s2), c3 = qrelu_code(v.w, s1, s2);
        xr[k] = c0 | (c1 << 8) | (c2 << 16) | ((unsigned)c3 << 24);
    }
    xr[21] = 0; xr[22] = 0; xr[23] = 0;
    #pragma unroll
    for (int j = 0; j < 10; j++) {
        int acc = 0;
        #pragma unroll
        for (int k = 0; k < 24; k++) acc = sdot4(xr[k], wsm[j * 24 + k], acc);
        pb[tid * 10 + j] = fmaf(seff, (float)acc, bs[j]);
    }
    __syncthreads();
    {
        const float4* pb4 = (const float4*)pb;
        float4* d4 = (float4*)(out + (size_t)blockIdx.x * 2560);
        for (int i = tid; i < 640; i += 256) d4[i] = pb4[i];
    }
}

extern "C" void kernel_launch(void* const* d_in, const int* in_sizes, int n_in,
                              void* d_out, int out_size, void* d_ws, size_t ws_size,
                              hipStream_t stream) {
    const float* input = (const float*)d_in[0];
    const float* w1  = (const float*)d_in[1];
    const float* b1  = (const float*)d_in[2];
    const float* w2  = (const float*)d_in[3];
    const float* b2  = (const float*)d_in[4];
    const float* fw1 = (const float*)d_in[5];
    const float* fb1 = (const float*)d_in[6];
    const float* fw2 = (const float*)d_in[7];
    const float* fb2 = (const float*)d_in[8];
    const float* fw3 = (const float*)d_in[9];
    const float* fb3 = (const float*)d_in[10];
    float* ws  = (float*)d_ws;
    float* out = (float*)d_out;

    prep_kernel<<<6, 256, 0, stream>>>(w1, w2, fw1, fw2, fw3, ws);
    absmax_kernel<<<2048, 256, 0, stream>>>((const float4*)input,
                                            (int)((size_t)BATCH * 3072 / 4),
                                            (unsigned int*)ws);
    quant1_kernel<<<8192, 256, 0, stream>>>((const float4*)input, ws);
    conv1_kernel<<<(BATCH + C1_NIMG - 1) / C1_NIMG, 256, 0, stream>>>(b1, ws);
    quant2_kernel<<<4096, 256, 0, stream>>>(b1, ws);
    conv2_kernel<<<BATCH / C2_NIMG, 256, 0, stream>>>(b2, ws);
    quant3_kernel<<<2048, 256, 0, stream>>>(b2, ws);
    fc1_kernel<<<BATCH / 32, 256, 0, stream>>>(fb1, ws);
    fc2_kernel<<<(BATCH + 47) / 48, 256, 0, stream>>>(fb2, ws);
    fc3_kernel<<<BATCH / 256, 256, 0, stream>>>(fb3, out, ws);
}

// Round 15
// 464.107 us; speedup vs baseline: 2.1266x; 1.0075x over previous
//
#include <hip/hip_runtime.h>
#include <math.h>

#define BATCH 16384
#define EPSQ 1e-8f

// ---------------- ws layout (32-bit units) ----------------
#define OFF_SCAL 0
#define OFF_WPK1 16        // 180 u32
#define OFF_WPK2 196       // 960 u32
#define OFF_FQ1  1156      // 12000 u32
#define OFF_FQ2  13156     // 2688 u32
#define OFF_FQ3  15844     // 240 u32
#define OFF_A    16384
#define OFF_QIN   OFF_A                 // [B][3][32slots][48] i8 quant1->conv1
#define OFF_QC2   OFF_A                 // [B][6][16slots][16] i8 quant2->conv2
#define OFF_ISUM2 (OFF_A + 6400000)     // [B][400] i16 conv2->quant3
#define OFF_QC3   (OFF_A + 10000000)    // [B][100] u32 quant3->fc1
#define OFF_P3    (OFF_A + 12000000)    // [B][120] f32 fc1->fc2
#define OFF_P4    (OFF_A + 14000000)    // [B][84]  f32 fc2->fc3
#define OFF_ISUM1 (OFF_A + 18874368)    // [B][1176] i16 conv1->quant2

__device__ inline int sdot4(unsigned int a, unsigned int b, int c) {
    return __builtin_amdgcn_sdot4((int)a, (int)b, c, false);
}

__device__ inline unsigned int fkey(float f) {
    unsigned int u = __float_as_uint(f);
    return (u & 0x80000000u) ? ~u : (u | 0x80000000u);
}
__device__ inline float fdec(unsigned int k) {
    unsigned int u = (k & 0x80000000u) ? (k ^ 0x80000000u) : ~k;
    return __uint_as_float(u);
}
#define KEY_ZERO   0x80000000u
#define KEY_NEGINF 0x007FFFFFu

__device__ inline float waveMax(float v) {
    #pragma unroll
    for (int off = 32; off > 0; off >>= 1)
        v = fmaxf(v, __shfl_down(v, off, 64));
    return v;
}

__device__ inline void blockAtomicMax2(float vmax, float vnmax,
                                       unsigned int* gmax, unsigned int* gnmax) {
    __shared__ float sm[4], sn[4];
    float a = waveMax(vmax), b = waveMax(vnmax);
    int tid = threadIdx.x;
    if ((tid & 63) == 0) { sm[tid >> 6] = a; sn[tid >> 6] = b; }
    __syncthreads();
    if (tid == 0) {
        atomicMax(gmax, fkey(fmaxf(fmaxf(sm[0], sm[1]), fmaxf(sm[2], sm[3]))));
        atomicMax(gnmax, fkey(fmaxf(fmaxf(sn[0], sn[1]), fmaxf(sn[2], sn[3]))));
    }
}

__device__ inline float fq_elem(float x, float s) {
    float q = fminf(fmaxf(rintf(x / s), -128.0f), 127.0f);
    return q * s;
}
__device__ inline int qrelu_code(float x, float s1, float s2) {
    float q = fq_elem(x, s1);
    q = fmaxf(q, 0.0f);
    return (int)fminf(fmaxf(rintf(q / s2), -128.0f), 127.0f);
}
__device__ inline void get_qrelu_scales(const unsigned int* scalu, int slot,
                                        float& s1, float& s2) {
    float maxa = fdec(scalu[slot]), negm = fdec(scalu[slot + 1]);
    float absm = fmaxf(maxa, negm);
    s1 = fmaxf(absm / 127.0f, EPSQ);
    float qm = fminf(fmaxf(rintf(maxa / s1), -128.0f), 127.0f) * s1;
    s2 = fmaxf(fmaxf(qm, 0.0f) / 127.0f, EPSQ);
}

__device__ inline unsigned int sgn8(float w) { return (w >= 0.0f) ? 0x01u : 0xFFu; }

__device__ inline unsigned int u32at(const unsigned int* wv, int wi, int k) {
    return (k == 0) ? wv[wi]
        : __builtin_amdgcn_perm(wv[wi + 1], wv[wi], 0x03020100u + 0x01010101u * (unsigned)k);
}

// ---------------- prep ----------------
__global__ __launch_bounds__(256) void prep_kernel(const float* __restrict__ w1,
        const float* __restrict__ w2, const float* __restrict__ fw1,
        const float* __restrict__ fw2, const float* __restrict__ fw3,
        float* __restrict__ wsf) {
    int blk = blockIdx.x, tid = threadIdx.x;
    unsigned int* wsu = (unsigned int*)wsf;
    if (blk == 0) {
        if (tid == 0) wsu[0] = KEY_ZERO;
        else if (tid <= 8) wsu[tid] = KEY_NEGINF;
        return;
    }
    const float* src = nullptr; int N = 0;
    if (blk == 1)      { src = w1;  N = 450; }
    else if (blk == 2) { src = w2;  N = 2400; }
    else if (blk == 3) { src = fw1; N = 48000; }
    else if (blk == 4) { src = fw2; N = 10080; }
    else               { src = fw3; N = 840; }
    __shared__ float red[256];
    float partial = 0.0f;
    for (int i = tid; i < N; i += 256) partial += fabsf(src[i]);
    red[tid] = partial;
    __syncthreads();
    for (int s = 128; s > 0; s >>= 1) {
        if (tid < s) red[tid] += red[tid + s];
        __syncthreads();
    }
    if (tid == 0) wsf[8 + blk] = red[0] / (float)N;

    if (blk == 1) {
        for (int t = tid; t < 90; t += 256) {
            const float* wp = w1 + t * 5;
            wsu[OFF_WPK1 + 2*t] = sgn8(wp[0]) | (sgn8(wp[1])<<8) | (sgn8(wp[2])<<16) | (sgn8(wp[3])<<24);
            wsu[OFF_WPK1 + 2*t + 1] = sgn8(wp[4]) << 24;
        }
    } else if (blk == 2) {
        for (int t = tid; t < 480; t += 256) {
            const float* wp = w2 + t * 5;
            wsu[OFF_WPK2 + 2*t] = sgn8(wp[0]) | (sgn8(wp[1])<<8) | (sgn8(wp[2])<<16) | (sgn8(wp[3])<<24);
            wsu[OFF_WPK2 + 2*t + 1] = sgn8(wp[4]) << 24;
        }
    } else if (blk == 3) {
        for (int i = tid; i < 12000; i += 256) {
            int j = i / 100, k = i % 100;
            const float* wp = fw1 + j * 400 + k * 4;
            wsu[OFF_FQ1 + i] = sgn8(wp[0]) | (sgn8(wp[1])<<8) | (sgn8(wp[2])<<16) | (sgn8(wp[3])<<24);
        }
    } else if (blk == 4) {
        for (int i = tid; i < 2688; i += 256) {
            int j = i >> 5, k = i & 31;
            unsigned int u = 0;
            if (k < 30) {
                const float* wp = fw2 + j * 120 + k * 4;
                u = sgn8(wp[0]) | (sgn8(wp[1])<<8) | (sgn8(wp[2])<<16) | (sgn8(wp[3])<<24);
            }
            wsu[OFF_FQ2 + i] = u;
        }
    } else {
        for (int i = tid; i < 240; i += 256) {
            int j = i / 24, k = i % 24;
            unsigned int u = 0;
            if (k < 21) {
                const float* wp = fw3 + j * 84 + k * 4;
                u = sgn8(wp[0]) | (sgn8(wp[1])<<8) | (sgn8(wp[2])<<16) | (sgn8(wp[3])<<24);
            }
            wsu[OFF_FQ3 + i] = u;
        }
    }
}

// ---------------- input abs-max ----------------
__global__ __launch_bounds__(256) void absmax_kernel(const float4* __restrict__ x, int n4,
                                                     unsigned int* __restrict__ gkey) {
    float m = 0.0f;
    int stride = gridDim.x * 256;
    for (int i = blockIdx.x * 256 + threadIdx.x; i < n4; i += stride) {
        float4 v = x[i];
        m = fmaxf(m, fmaxf(fmaxf(fabsf(v.x), fabsf(v.y)), fmaxf(fabsf(v.z), fabsf(v.w))));
    }
    __shared__ float sm[4];
    m = waveMax(m);
    int tid = threadIdx.x;
    if ((tid & 63) == 0) sm[tid >> 6] = m;
    __syncthreads();
    if (tid == 0)
        atomicMax(gkey, fkey(fmaxf(fmaxf(sm[0], sm[1]), fmaxf(sm[2], sm[3]))));
}

// ---------------- quant1: fp32 -> i8 codes, row-interleaved [B][3][slot(32)][48] ----
__global__ __launch_bounds__(256) void quant1_kernel(const float4* __restrict__ x,
                                                     float* __restrict__ wsf) {
    unsigned int* wsu = (unsigned int*)wsf;
    float s0 = fmaxf(fdec(wsu[0]) / 127.0f, EPSQ);
    unsigned int* qin = wsu + OFF_QIN;
    int stride = gridDim.x * 256;
    const int total = BATCH * 96 * 12;
    for (int unit = blockIdx.x * 256 + threadIdx.x; unit < total; unit += stride) {
        int row_id = unit / 12, w = unit % 12;
        int plane = row_id >> 5, row = row_id & 31;
        int slot = (row >> 1) + ((row & 1) << 4);
        unsigned int u = 0;
        if (w < 8) {
            float4 v = x[row_id * 8 + w];
            int q0 = (int)fminf(fmaxf(rintf(v.x / s0), -128.f), 127.f);
            int q1 = (int)fminf(fmaxf(rintf(v.y / s0), -128.f), 127.f);
            int q2 = (int)fminf(fmaxf(rintf(v.z / s0), -128.f), 127.f);
            int q3 = (int)fminf(fmaxf(rintf(v.w / s0), -128.f), 127.f);
            u = (q0 & 255) | ((q1 & 255) << 8) | ((q2 & 255) << 16) | ((unsigned)(q3 & 255) << 24);
        }
        qin[(plane * 32 + slot) * 12 + w] = u;
    }
}

// ---------------- conv1: 9 img/block, thread = (img, c-triple, py), dot4 ------
#define C1_ROWP 48
#define C1_CIS  1536
#define C1_IMGS 4608
#define C1_NIMG 9

// one x-phase computing 3 output channels; per-channel extremes in gmax[3]/gmin[3]
template<int PH>
__device__ __forceinline__ void c1_phase3(const unsigned char* ib, const unsigned int* wcp,
                                          int ip[3][7], int gmax[3], int gmin[3]) {
    int a0[3][14], a1[3][14];
    #pragma unroll
    for (int cc = 0; cc < 3; cc++)
        #pragma unroll
        for (int i = 0; i < 14; i++) { a0[cc][i] = 0; a1[cc][i] = 0; }
    #pragma unroll 1
    for (int ci = 0; ci < 3; ci++) {
        uint4 A[6]; unsigned int Bv[6];
        const unsigned char* cb = ib + ci * C1_CIS;
        #pragma unroll
        for (int r = 0; r < 6; r++) {
            const unsigned char* rb = cb + (((r & 1) << 4) + (r >> 1)) * C1_ROWP;
            if (PH == 0) {
                A[r]  = *(const uint4*)(rb);
                Bv[r] = *(const unsigned int*)(rb + 16);
            } else {
                Bv[r] = *(const unsigned int*)(rb + 12);
                A[r]  = *(const uint4*)(rb + 16);
            }
        }
        #pragma unroll
        for (int r6 = 0; r6 < 6; r6++) {
            unsigned int wv[5];
            if (PH == 0) {
                wv[0] = A[r6].x; wv[1] = A[r6].y; wv[2] = A[r6].z; wv[3] = A[r6].w; wv[4] = Bv[r6];
            } else {
                wv[0] = Bv[r6]; wv[1] = A[r6].x; wv[2] = A[r6].y; wv[3] = A[r6].z; wv[4] = A[r6].w;
            }
            const int OFS = (PH == 0) ? 0 : 2;
            unsigned int up[15];
            #pragma unroll
            for (int i = 0; i < 15; i++) {
                int e = OFS + i;
                up[i] = u32at(wv, e >> 2, e & 3);
            }
            #pragma unroll
            for (int cc = 0; cc < 3; cc++) {
                const unsigned int* wkp = wcp + cc * 30 + ci * 10;
                if (r6 <= 4) {
                    unsigned int w0 = wkp[2 * r6], w4 = wkp[2 * r6 + 1];
                    #pragma unroll
                    for (int i = 0; i < 14; i++) {
                        a0[cc][i] = sdot4(up[i], w0, a0[cc][i]);
                        a0[cc][i] = sdot4(up[i + 1], w4, a0[cc][i]);
                    }
                }
                if (r6 >= 1) {
                    unsigned int w0 = wkp[2 * (r6 - 1)], w4 = wkp[2 * (r6 - 1) + 1];
                    #pragma unroll
                    for (int i = 0; i < 14; i++) {
                        a1[cc][i] = sdot4(up[i], w0, a1[cc][i]);
                        a1[cc][i] = sdot4(up[i + 1], w4, a1[cc][i]);
                    }
                }
            }
        }
    }
    #pragma unroll
    for (int cc = 0; cc < 3; cc++) {
        #pragma unroll
        for (int i = 0; i < 14; i++) {
            gmax[cc] = max(gmax[cc], max(a0[cc][i], a1[cc][i]));
            gmin[cc] = min(gmin[cc], min(a0[cc][i], a1[cc][i]));
        }
        #pragma unroll
        for (int p = 0; p < 7; p++)
            ip[cc][p] = max(max(a0[cc][2*p], a0[cc][2*p+1]), max(a1[cc][2*p], a1[cc][2*p+1]));
    }
}

__global__ __launch_bounds__(256) void conv1_kernel(const float* __restrict__ b1,
                                                    float* __restrict__ wsf) {
    __shared__ __align__(16) unsigned char xq[C1_NIMG * C1_IMGS];   // 41472 B
    __shared__ unsigned int wpk[180];
    __shared__ float bsm[6];
    unsigned int* wsu = (unsigned int*)wsf;
    int tid = threadIdx.x;
    int b0 = blockIdx.x * C1_NIMG;
    int nimg = min(C1_NIMG, BATCH - b0);
    float s0 = fmaxf(fdec(wsu[0]) / 127.0f, EPSQ);
    float seff = s0 * wsf[9];

    {
        const uint4* src = (const uint4*)((const unsigned char*)(wsu + OFF_QIN) + (size_t)b0 * C1_IMGS);
        uint4* dst = (uint4*)xq;
        for (int i = tid; i < nimg * 288; i += 256) dst[i] = src[i];
    }
    for (int i = tid; i < 180; i += 256) wpk[i] = wsu[OFF_WPK1 + i];
    if (tid < 6) bsm[tid] = b1[tid];
    __syncthreads();

    unsigned int* isum1 = wsu + OFF_ISUM1;
    float vmax = -INFINITY, vnmax = -INFINITY;
    int ntask = nimg * 28;   // (img, chalf, py): <= 252
    if (tid < ntask) {
        int img = tid / 28, rem = tid % 28;
        int chalf = rem / 14, py = rem % 14;
        int c0 = chalf * 3;
        const unsigned char* ib = &xq[img * C1_IMGS + py * C1_ROWP];
        const unsigned int* wcp = &wpk[c0 * 30];
        int ip0[3][7], ip1[3][7];
        int gmax[3] = {-2000000000, -2000000000, -2000000000};
        int gmin[3] = { 2000000000,  2000000000,  2000000000};
        c1_phase3<0>(ib, wcp, ip0, gmax, gmin);
        c1_phase3<1>(ib, wcp, ip1, gmax, gmin);
        #pragma unroll
        for (int cc = 0; cc < 3; cc++) {
            float bias = bsm[c0 + cc];
            vmax  = fmaxf(vmax,  fmaf(seff, (float)gmax[cc], bias));
            vnmax = fmaxf(vnmax, -fmaf(seff, (float)gmin[cc], bias));
            unsigned int* dst = isum1 + 588 * (size_t)(b0 + img) + 7 * ((c0 + cc) * 14 + py);
            int v14[14];
            #pragma unroll
            for (int p = 0; p < 7; p++) { v14[p] = ip0[cc][p]; v14[7 + p] = ip1[cc][p]; }
            #pragma unroll
            for (int p = 0; p < 7; p++)
                dst[p] = (v14[2*p] & 0xFFFF) | ((unsigned)(v14[2*p+1] & 0xFFFF) << 16);
        }
    }
    blockAtomicMax2(vmax, vnmax, wsu + 1, wsu + 2);
}

// ---------------- quant2 ----------------
__global__ __launch_bounds__(256) void quant2_kernel(const float* __restrict__ b1,
                                                     float* __restrict__ wsf) {
    unsigned int* wsu = (unsigned int*)wsf;
    float s1, s2;
    get_qrelu_scales(wsu, 1, s1, s2);
    float s0 = fmaxf(fdec(wsu[0]) / 127.0f, EPSQ);
    float seff = s0 * wsf[9];
    float bv[6];
    #pragma unroll
    for (int c = 0; c < 6; c++) bv[c] = b1[c];
    const short* isum1 = (const short*)(wsu + OFF_ISUM1);
    unsigned int* qc2 = wsu + OFF_QC2;
    int stride = gridDim.x * 256;
    const int total = BATCH * 84 * 4;
    for (int unit = blockIdx.x * 256 + threadIdx.x; unit < total; unit += stride) {
        int row_id = unit >> 2, w = unit & 3;
        int bci = row_id / 14, row = row_id % 14;
        int ci = bci % 6;
        int slot = (row >> 1) + ((row & 1) << 3);
        float bias = bv[ci];
        unsigned int u = 0;
        const short* sp = isum1 + (size_t)bci * 196 + row * 14;
        #pragma unroll
        for (int k = 0; k < 4; k++) {
            int col = w * 4 + k;
            int code = 0;
            if (col < 14) {
                float pre = fmaf(seff, (float)sp[col], bias);
                code = qrelu_code(pre, s1, s2);
            }
            u |= ((unsigned)(code & 255)) << (8 * k);
        }
        qc2[((size_t)bci * 16 + slot) * 4 + w] = u;
    }
}

// ---------------- conv2: 12 img/block, thread = (img, c-quad, py), dot4 ------
#define C2_ROWP 16
#define C2_CIS  256
#define C2_IMGS 1536
#define C2_NIMG 12

__global__ __launch_bounds__(256) void conv2_kernel(const float* __restrict__ b2,
                                                    float* __restrict__ wsf) {
    __shared__ __align__(16) unsigned char act[C2_NIMG * C2_IMGS];  // 18432 B
    __shared__ unsigned int wpk[960];
    __shared__ float bsm[16];
    __shared__ __align__(16) short spb[C2_NIMG * 400];               // 9600 B
    unsigned int* wsu = (unsigned int*)wsf;
    int tid = threadIdx.x;
    int b0 = blockIdx.x * C2_NIMG;
    int nimg = min(C2_NIMG, BATCH - b0);
    float s1, s2;
    get_qrelu_scales(wsu, 1, s1, s2);
    float seff = s2 * wsf[10];

    {
        const uint4* src = (const uint4*)((const unsigned char*)(wsu + OFF_QC2) + (size_t)b0 * C2_IMGS);
        uint4* dst = (uint4*)act;
        for (int i = tid; i < nimg * 96; i += 256) dst[i] = src[i];
    }
    for (int i = tid; i < 960; i += 256) wpk[i] = wsu[OFF_WPK2 + i];
    if (tid < 16) bsm[tid] = b2[tid];
    __syncthreads();

    float vmax = -INFINITY, vnmax = -INFINITY;
    int ntask = nimg * 20;   // (img, cq, py): <= 240
    if (tid < ntask) {
        int img = tid / 20, rem = tid % 20;
        int cq = rem / 5, py = rem % 5;
        int c0 = cq * 4;
        const unsigned char* ib = &act[img * C2_IMGS + py * C2_ROWP];
        int a0[4][10], a1[4][10];
        #pragma unroll
        for (int cc = 0; cc < 4; cc++)
            #pragma unroll
            for (int i = 0; i < 10; i++) { a0[cc][i] = 0; a1[cc][i] = 0; }
        #pragma unroll 1
        for (int ci = 0; ci < 6; ci++) {
            uint4 R[6];
            #pragma unroll
            for (int r6 = 0; r6 < 6; r6++)
                R[r6] = *(const uint4*)(ib + ci * C2_CIS + (((r6 & 1) << 3) + (r6 >> 1)) * C2_ROWP);
            #pragma unroll
            for (int r6 = 0; r6 < 6; r6++) {
                unsigned int wv[4] = { R[r6].x, R[r6].y, R[r6].z, R[r6].w };
                unsigned int up[11];
                #pragma unroll
                for (int i = 0; i < 11; i++) up[i] = u32at(wv, i >> 2, i & 3);
                #pragma unroll
                for (int cc = 0; cc < 4; cc++) {
                    const unsigned int* wkp = &wpk[((c0 + cc) * 6 + ci) * 10];
                    if (r6 <= 4) {
                        unsigned int w0 = wkp[2 * r6], w4 = wkp[2 * r6 + 1];
                        #pragma unroll
                        for (int i = 0; i < 10; i++) {
                            a0[cc][i] = sdot4(up[i], w0, a0[cc][i]);
                            a0[cc][i] = sdot4(up[i + 1], w4, a0[cc][i]);
                        }
                    }
                    if (r6 >= 1) {
                        unsigned int w0 = wkp[2 * (r6 - 1)], w4 = wkp[2 * (r6 - 1) + 1];
                        #pragma unroll
                        for (int i = 0; i < 10; i++) {
                            a1[cc][i] = sdot4(up[i], w0, a1[cc][i]);
                            a1[cc][i] = sdot4(up[i + 1], w4, a1[cc][i]);
                        }
                    }
                }
            }
        }
        #pragma unroll
        for (int cc = 0; cc < 4; cc++) {
            int gmax = -2000000000, gmin = 2000000000;
            #pragma unroll
            for (int i = 0; i < 10; i++) {
                gmax = max(gmax, max(a0[cc][i], a1[cc][i]));
                gmin = min(gmin, min(a0[cc][i], a1[cc][i]));
            }
            float bias = bsm[c0 + cc];
            vmax  = fmaxf(vmax,  fmaf(seff, (float)gmax, bias));
            vnmax = fmaxf(vnmax, -fmaf(seff, (float)gmin, bias));
            short* dst = spb + img * 400 + (c0 + cc) * 25 + py * 5;
            #pragma unroll
            for (int p = 0; p < 5; p++)
                dst[p] = (short)max(max(a0[cc][2*p], a0[cc][2*p+1]),
                                    max(a1[cc][2*p], a1[cc][2*p+1]));
        }
    }
    __syncthreads();
    {
        const uint4* pb4 = (const uint4*)spb;
        uint4* d4 = (uint4*)((short*)(wsu + OFF_ISUM2) + (size_t)b0 * 400);
        for (int i = tid; i < nimg * 50; i += 256) d4[i] = pb4[i];
    }
    blockAtomicMax2(vmax, vnmax, wsu + 3, wsu + 4);
}

// ---------------- quant3 ----------------
__global__ __launch_bounds__(256) void quant3_kernel(const float* __restrict__ b2,
                                                     float* __restrict__ wsf) {
    unsigned int* wsu = (unsigned int*)wsf;
    float s1, s2;
    get_qrelu_scales(wsu, 3, s1, s2);
    float sp1, sp2;
    get_qrelu_scales(wsu, 1, sp1, sp2);
    float seff = sp2 * wsf[10];
    __shared__ float bv[16];
    if (threadIdx.x < 16) bv[threadIdx.x] = b2[threadIdx.x];
    __syncthreads();
    const short* isum2 = (const short*)(wsu + OFF_ISUM2);
    unsigned int* qc3 = wsu + OFF_QC3;
    int stride = gridDim.x * 256;
    const int total = BATCH * 100;
    for (int unit = blockIdx.x * 256 + threadIdx.x; unit < total; unit += stride) {
        int b = unit / 100, w = unit % 100;
        const short* sp = isum2 + (size_t)b * 400 + w * 4;
        unsigned int u = 0;
        #pragma unroll
        for (int k = 0; k < 4; k++) {
            int p = w * 4 + k;
            float pre = fmaf(seff, (float)sp[k], bv[p / 25]);
            int code = qrelu_code(pre, s1, s2);
            u |= ((unsigned)(code & 255)) << (8 * k);
        }
        qc3[unit] = u;
    }
}

// ---------------- fc1: 256 threads, 32 rows/block (512 blocks) ----------------
__global__ __launch_bounds__(256) void fc1_kernel(const float* __restrict__ fb1,
                                                  float* __restrict__ wsf) {
    __shared__ unsigned int xs[32][100];
    __shared__ __align__(16) float pb[32 * 120];
    unsigned int* wsu = (unsigned int*)wsf;
    float* p3 = wsf + OFF_P3;
    int tid = threadIdx.x;
    size_t row0 = (size_t)blockIdx.x * 32;
    float s1, s2;
    get_qrelu_scales(wsu, 3, s1, s2);
    float seff = s2 * wsf[11];
    {
        const uint4* src = (const uint4*)(wsu + OFF_QC3 + row0 * 100);
        uint4* dst = (uint4*)xs;
        for (int i = tid; i < 800; i += 256) dst[i] = src[i];
    }
    __syncthreads();
    float vmax = -INFINITY, vnmax = -INFINITY;
    if (tid < 240) {
        int g = tid / 120, j = tid % 120;
        int acc[16];
        #pragma unroll
        for (int r = 0; r < 16; r++) acc[r] = 0;
        const uint4* wrow = (const uint4*)&wsu[OFF_FQ1 + j * 100];
        for (int kg = 0; kg < 25; kg++) {
            uint4 wv = wrow[kg];
            #pragma unroll
            for (int r = 0; r < 16; r++) {
                uint4 xv = *(const uint4*)&xs[g * 16 + r][kg * 4];
                acc[r] = sdot4(xv.x, wv.x, acc[r]);
                acc[r] = sdot4(xv.y, wv.y, acc[r]);
                acc[r] = sdot4(xv.z, wv.z, acc[r]);
                acc[r] = sdot4(xv.w, wv.w, acc[r]);
            }
        }
        float bias = fb1[j];
        #pragma unroll
        for (int r = 0; r < 16; r++) {
            float pv = fmaf(seff, (float)acc[r], bias);
            pb[(g * 16 + r) * 120 + j] = pv;
            vmax = fmaxf(vmax, pv); vnmax = fmaxf(vnmax, -pv);
        }
    }
    __syncthreads();
    {
        const float4* pb4 = (const float4*)pb;
        float4* d4 = (float4*)(p3 + row0 * 120);
        for (int i = tid; i < 960; i += 256) d4[i] = pb4[i];
    }
    blockAtomicMax2(vmax, vnmax, wsu + 5, wsu + 6);
}

// ---------------- fc2: 256 threads, 48 rows/block ----------------
__global__ __launch_bounds__(256) void fc2_kernel(const float* __restrict__ fb2,
                                                  float* __restrict__ wsf) {
    __shared__ unsigned int xs[48][32];
    __shared__ __align__(16) float pb[48 * 84];
    unsigned int* wsu = (unsigned int*)wsf;
    const float* p3 = wsf + OFF_P3;
    float* p4 = wsf + OFF_P4;
    int tid = threadIdx.x;
    size_t row0 = (size_t)blockIdx.x * 48;
    int nrow = min(48, (int)(BATCH - row0));
    float s1, s2;
    get_qrelu_scales(wsu, 5, s1, s2);
    float seff = s2 * wsf[12];
    const float4* src = (const float4*)(p3 + row0 * 120);
    for (int i = tid; i < nrow * 30; i += 256) {
        float4 v = src[i];
        int c0 = qrelu_code(v.x, s1, s2), c1 = qrelu_code(v.y, s1, s2);
        int c2 = qrelu_code(v.z, s1, s2), c3 = qrelu_code(v.w, s1, s2);
        xs[i / 30][i % 30] = c0 | (c1 << 8) | (c2 << 16) | ((unsigned)c3 << 24);
    }
    if (tid < 48) { xs[tid][30] = 0; xs[tid][31] = 0; }
    __syncthreads();
    float vmax = -INFINITY, vnmax = -INFINITY;
    if (tid < 252) {
        int g = tid / 84, j = tid % 84;
        int acc[16];
        #pragma unroll
        for (int r = 0; r < 16; r++) acc[r] = 0;
        const uint4* wrow = (const uint4*)&wsu[OFF_FQ2 + j * 32];
        #pragma unroll
        for (int kg = 0; kg < 8; kg++) {
            uint4 wv = wrow[kg];
            #pragma unroll
            for (int r = 0; r < 16; r++) {
                uint4 xv = *(const uint4*)&xs[g * 16 + r][kg * 4];
                acc[r] = sdot4(xv.x, wv.x, acc[r]);
                acc[r] = sdot4(xv.y, wv.y, acc[r]);
                acc[r] = sdot4(xv.z, wv.z, acc[r]);
                acc[r] = sdot4(xv.w, wv.w, acc[r]);
            }
        }
        float bias = fb2[j];
        #pragma unroll
        for (int r = 0; r < 16; r++) {
            int lr = g * 16 + r;
            if (lr < nrow) {
                float pv = fmaf(seff, (float)acc[r], bias);
                pb[lr * 84 + j] = pv;
                vmax = fmaxf(vmax, pv); vnmax = fmaxf(vnmax, -pv);
            }
        }
    }
    __syncthreads();
    {
        const float4* pb4 = (const float4*)pb;
        float4* d4 = (float4*)(p4 + row0 * 84);
        for (int i = tid; i < nrow * 21; i += 256) d4[i] = pb4[i];
    }
    blockAtomicMax2(vmax, vnmax, wsu + 7, wsu + 8);
}

// ---------------- fc3 ----------------
__global__ __launch_bounds__(256) void fc3_kernel(const float* __restrict__ fb3,
                                                  float* __restrict__ out,
                                                  float* __restrict__ wsf) {
    __shared__ unsigned int wsm[240];
    __shared__ float bs[10];
    __shared__ __align__(16) float pb[2560];
    unsigned int* wsu = (unsigned int*)wsf;
    const float* p4 = wsf + OFF_P4;
    int tid = threadIdx.x;
    for (int i = tid; i < 240; i += 256) wsm[i] = wsu[OFF_FQ3 + i];
    if (tid < 10) bs[tid] = fb3[tid];
    __syncthreads();
    float s1, s2;
    get_qrelu_scales(wsu, 7, s1, s2);
    float seff = s2 * wsf[13];
    size_t row = (size_t)blockIdx.x * 256 + tid;
    unsigned int xr[24];
    const float4* src = (const float4*)(p4 + row * 84);
    #pragma unroll
    for (int k = 0; k < 21; k++) {
        float4 v = src[k];
        int c0 = qrelu_code(v.x, s1, s2), c1 = qrelu_code(v.y, s1, s2);
        int c2 = qrelu_code(v.z, s1, s2), c3 = qrelu_code(v.w, s1, s2);
        xr[k] = c0 | (c1 << 8) | (c2 << 16) | ((unsigned)c3 << 24);
    }
    xr[21] = 0; xr[22] = 0; xr[23] = 0;
    #pragma unroll
    for (int j = 0; j < 10; j++) {
        int acc = 0;
        #pragma unroll
        for (int k = 0; k < 24; k++) acc = sdot4(xr[k], wsm[j * 24 + k], acc);
        pb[tid * 10 + j] = fmaf(seff, (float)acc, bs[j]);
    }
    __syncthreads();
    {
        const float4* pb4 = (const float4*)pb;
        float4* d4 = (float4*)(out + (size_t)blockIdx.x * 2560);
        for (int i = tid; i < 640; i += 256) d4[i] = pb4[i];
    }
}

extern "C" void kernel_launch(void* const* d_in, const int* in_sizes, int n_in,
                              void* d_out, int out_size, void* d_ws, size_t ws_size,
                              hipStream_t stream) {
    const float* input = (const float*)d_in[0];
    const float* w1  = (const float*)d_in[1];
    const float* b1  = (const float*)d_in[2];
    const float* w2  = (const float*)d_in[3];
    const float* b2  = (const float*)d_in[4];
    const float* fw1 = (const float*)d_in[5];
    const float* fb1 = (const float*)d_in[6];
    const float* fw2 = (const float*)d_in[7];
    const float* fb2 = (const float*)d_in[8];
    const float* fw3 = (const float*)d_in[9];
    const float* fb3 = (const float*)d_in[10];
    float* ws  = (float*)d_ws;
    float* out = (float*)d_out;

    prep_kernel<<<6, 256, 0, stream>>>(w1, w2, fw1, fw2, fw3, ws);
    absmax_kernel<<<2048, 256, 0, stream>>>((const float4*)input,
                                            (int)((size_t)BATCH * 3072 / 4),
                                            (unsigned int*)ws);
    quant1_kernel<<<8192, 256, 0, stream>>>((const float4*)input, ws);
    conv1_kernel<<<(BATCH + C1_NIMG - 1) / C1_NIMG, 256, 0, stream>>>(b1, ws);
    quant2_kernel<<<4096, 256, 0, stream>>>(b1, ws);
    conv2_kernel<<<(BATCH + C2_NIMG - 1) / C2_NIMG, 256, 0, stream>>>(b2, ws);
    quant3_kernel<<<2048, 256, 0, stream>>>(b2, ws);
    fc1_kernel<<<BATCH / 32, 256, 0, stream>>>(fb1, ws);
    fc2_kernel<<<(BATCH + 47) / 48, 256, 0, stream>>>(fb2, ws);
    fc3_kernel<<<BATCH / 256, 256, 0, stream>>>(fb3, out, ws);
}